// Round 1
// baseline (4099.523 us; speedup 1.0000x reference)
//
#include <hip/hip_runtime.h>
#include <math.h>

// Problem constants (fixed by setup_inputs())
#define F_DIM 256
#define D_DIM 128
#define O_DIM 64
#define NS0   100000
#define ND0   25000
#define E0_N  500000
#define NS1   25000
#define ND1   5000
#define E1_N  100000

// ---------------------------------------------------------------------------
// Tiled fp32 GEMM: C[M,N] = A[M,K] @ B[K,N] + bias[N]
// Block tile BM x BN, 256 threads, each thread TM x TN outputs.
// K must be a multiple of BK; N == BN (full width per block).
// ---------------------------------------------------------------------------
template<int BM, int BN, int BK, int TM, int TN>
__global__ __launch_bounds__(256) void gemm_bias(
    const float* __restrict__ A, const float* __restrict__ B,
    const float* __restrict__ bias, float* __restrict__ C,
    int M, int K, int N)
{
    __shared__ float As[BK][BM];
    __shared__ float Bs[BK][BN];
    const int tid = threadIdx.x;
    const int row0 = blockIdx.x * BM;
    constexpr int TCOLS = BN / TN;            // threads per row of C-tile
    const int tcol = tid % TCOLS;
    const int trow = tid / TCOLS;
    float acc[TM][TN] = {};

    for (int k0 = 0; k0 < K; k0 += BK) {
        // A tile: BM x BK, transposed into As[k][m]. float4 loads.
        #pragma unroll
        for (int i = 0; i < (BM * BK) / (256 * 4); ++i) {
            int f  = tid + i * 256;
            int r  = f >> 3;                  // BK/4 == 8 quads per row
            int kq = f & 7;
            int g  = row0 + r;
            float4 v = make_float4(0.f, 0.f, 0.f, 0.f);
            if (g < M) v = *(const float4*)(A + (size_t)g * K + k0 + kq * 4);
            As[kq * 4 + 0][r] = v.x;
            As[kq * 4 + 1][r] = v.y;
            As[kq * 4 + 2][r] = v.z;
            As[kq * 4 + 3][r] = v.w;
        }
        // B tile: BK x BN, straight copy, float4.
        #pragma unroll
        for (int i = 0; i < (BK * BN) / (256 * 4); ++i) {
            int f  = tid + i * 256;
            int r  = f / (BN / 4);
            int nq = f % (BN / 4);
            float4 v = *(const float4*)(B + (size_t)(k0 + r) * N + nq * 4);
            *(float4*)(&Bs[r][nq * 4]) = v;
        }
        __syncthreads();
        #pragma unroll
        for (int k = 0; k < BK; ++k) {
            float a[TM], b[TN];
            #pragma unroll
            for (int i = 0; i < TM; ++i) a[i] = As[k][trow * TM + i];
            #pragma unroll
            for (int j = 0; j < TN; ++j) b[j] = Bs[k][tcol * TN + j];
            #pragma unroll
            for (int i = 0; i < TM; ++i)
                #pragma unroll
                for (int j = 0; j < TN; ++j)
                    acc[i][j] += a[i] * b[j];
        }
        __syncthreads();
    }
    #pragma unroll
    for (int i = 0; i < TM; ++i) {
        int g = row0 + trow * TM + i;
        if (g < M) {
            #pragma unroll
            for (int j = 0; j < TN; ++j) {
                int c = tcol * TN + j;
                C[(size_t)g * N + c] = acc[i][j] + bias[c];
            }
        }
    }
}

// ---------------------------------------------------------------------------
// Per-node projections: one wave (64 lanes) per node, 8 dots of length 128.
// Outputs: ps[n,2], qs[n] for all src nodes; pd[n,2], qd[n], alpha[n,2]
// (softmaxed) for dst nodes (n < n_dst).
// ---------------------------------------------------------------------------
__global__ __launch_bounds__(256) void node_proj(
    const float* __restrict__ z,
    const float* __restrict__ Wna,   // D x 2
    const float* __restrict__ We,    // 2D x 2
    const float* __restrict__ Wi,    // 2D x 1
    float* __restrict__ ps, float* __restrict__ qs,
    float* __restrict__ pd, float* __restrict__ qd,
    float* __restrict__ alpha,
    int n_src, int n_dst)
{
    __shared__ float w[8][D_DIM];
    for (int k = threadIdx.x; k < D_DIM; k += 256) {
        w[0][k] = We[k * 2 + 0];
        w[1][k] = We[k * 2 + 1];
        w[2][k] = Wi[k];
        w[3][k] = We[(D_DIM + k) * 2 + 0];
        w[4][k] = We[(D_DIM + k) * 2 + 1];
        w[5][k] = Wi[D_DIM + k];
        w[6][k] = Wna[k * 2 + 0];
        w[7][k] = Wna[k * 2 + 1];
    }
    __syncthreads();

    const int lane = threadIdx.x & 63;
    const int node = blockIdx.x * 4 + (threadIdx.x >> 6);
    if (node >= n_src) return;

    float2 zv = *(const float2*)(z + (size_t)node * D_DIM + lane * 2);
    float p[8];
    #pragma unroll
    for (int c = 0; c < 8; ++c)
        p[c] = zv.x * w[c][2 * lane] + zv.y * w[c][2 * lane + 1];
    #pragma unroll
    for (int off = 32; off > 0; off >>= 1)
        #pragma unroll
        for (int c = 0; c < 8; ++c)
            p[c] += __shfl_down(p[c], off);

    if (lane == 0) {
        ps[node * 2 + 0] = p[0];
        ps[node * 2 + 1] = p[1];
        qs[node]         = p[2];
        if (node < n_dst) {
            pd[node * 2 + 0] = p[3];
            pd[node * 2 + 1] = p[4];
            qd[node]         = p[5];
            float mx = fmaxf(p[6], p[7]);
            float a0 = expf(p[6] - mx), a1 = expf(p[7] - mx);
            float inv = 1.0f / (a0 + a1);
            alpha[node * 2 + 0] = a0 * inv;
            alpha[node * 2 + 1] = a1 * inv;
        }
    }
}

// ---------------------------------------------------------------------------
// Per-edge attention values: softmax over 2 logits (e-channel) + sigmoid
// (i-channel). One thread per edge index (edge sets share the same E).
// ---------------------------------------------------------------------------
__global__ void edge_logits(
    const float* __restrict__ ps, const float* __restrict__ pd,
    const float* __restrict__ qs, const float* __restrict__ qd,
    const int* __restrict__ es, const int* __restrict__ ed,
    const int* __restrict__ is_, const int* __restrict__ id_,
    float* __restrict__ ee, float* __restrict__ ei, int E)
{
    int e = blockIdx.x * blockDim.x + threadIdx.x;
    if (e >= E) return;
    int s = es[e], d = ed[e];
    float l0 = ps[s * 2 + 0] + pd[d * 2 + 0];
    float l1 = ps[s * 2 + 1] + pd[d * 2 + 1];
    float mx = fmaxf(l0, l1);
    float x0 = expf(l0 - mx), x1 = expf(l1 - mx);
    float inv = 1.0f / (x0 + x1);
    ee[e * 2 + 0] = x0 * inv;
    ee[e * 2 + 1] = x1 * inv;
    int si = is_[e], di = id_[e];
    float q = qs[si] + qd[di];
    ei[e] = 1.0f / (1.0f + expf(-q));
}

// ---------------------------------------------------------------------------
// Edge scatter (atomic): one wave per edge index e; lane handles 2 channels.
//   s_acc[ed]  += ee0[e] * wz[es]
//   eh_acc[ed] += ee1[e] * z[es]
//   deg[ed]    += 1
//   ih_acc[id] += ei[e] * z[is]
// ---------------------------------------------------------------------------
__global__ __launch_bounds__(256) void scatter(
    const float* __restrict__ wz, const float* __restrict__ z,
    const float* __restrict__ ee, const float* __restrict__ ei,
    const int* __restrict__ es, const int* __restrict__ ed,
    const int* __restrict__ is_, const int* __restrict__ id_,
    float* __restrict__ s_acc, float* __restrict__ eh_acc,
    float* __restrict__ ih_acc, float* __restrict__ deg, int E)
{
    const int e = blockIdx.x * 4 + (threadIdx.x >> 6);
    const int lane = threadIdx.x & 63;
    if (e >= E) return;

    int s = es[e], d = ed[e];
    float e0 = ee[e * 2 + 0];
    float e1 = ee[e * 2 + 1];
    float2 wzv = *(const float2*)(wz + (size_t)s * D_DIM + lane * 2);
    float2 zv  = *(const float2*)(z  + (size_t)s * D_DIM + lane * 2);
    size_t dbase = (size_t)d * D_DIM + lane * 2;
    atomicAdd(&s_acc[dbase + 0],  e0 * wzv.x);
    atomicAdd(&s_acc[dbase + 1],  e0 * wzv.y);
    atomicAdd(&eh_acc[dbase + 0], e1 * zv.x);
    atomicAdd(&eh_acc[dbase + 1], e1 * zv.y);
    if (lane == 0) atomicAdd(&deg[d], 1.0f);

    int si = is_[e], di = id_[e];
    float sg = ei[e];
    float2 zv2 = *(const float2*)(z + (size_t)si * D_DIM + lane * 2);
    size_t ibase = (size_t)di * D_DIM + lane * 2;
    atomicAdd(&ih_acc[ibase + 0], sg * zv2.x);
    atomicAdd(&ih_acc[ibase + 1], sg * zv2.y);
}

// ---------------------------------------------------------------------------
// Combine: z_out = 0.5*( relu(s/max(deg,1)) + relu(eh*ih) + (a0+a1)*z )
// ---------------------------------------------------------------------------
__global__ void combine(
    const float* __restrict__ s_acc, const float* __restrict__ eh_acc,
    const float* __restrict__ ih_acc, const float* __restrict__ deg,
    const float* __restrict__ alpha, const float* __restrict__ z,
    float* __restrict__ zout, int n_dst)
{
    int i = blockIdx.x * blockDim.x + threadIdx.x;
    if (i >= n_dst * D_DIM) return;
    int v = i >> 7;
    float dg = fmaxf(deg[v], 1.0f);
    float f = fmaxf(s_acc[i] / dg, 0.0f);
    float inter = fmaxf(eh_acc[i] * ih_acc[i], 0.0f);
    float a = alpha[v * 2 + 0] + alpha[v * 2 + 1];
    zout[i] = 0.5f * (f + inter + a * z[i]);
}

// ---------------------------------------------------------------------------
extern "C" void kernel_launch(void* const* d_in, const int* in_sizes, int n_in,
                              void* d_out, int out_size, void* d_ws, size_t ws_size,
                              hipStream_t stream)
{
    const float* feat = (const float*)d_in[0];
    const int* src0_cor = (const int*)d_in[1];
    const int* dst0_cor = (const int*)d_in[2];
    const int* src0_sim = (const int*)d_in[3];
    const int* dst0_sim = (const int*)d_in[4];
    const int* src1_cor = (const int*)d_in[5];
    const int* dst1_cor = (const int*)d_in[6];
    const int* src1_sim = (const int*)d_in[7];
    const int* dst1_sim = (const int*)d_in[8];
    // d_in[9], d_in[10]: n_dst0 / n_dst1 scalars (hard-coded)
    const float* Win  = (const float*)d_in[11];
    const float* b_in = (const float*)d_in[12];
    const float* na1  = (const float*)d_in[13];
    const float* ea1  = (const float*)d_in[14];
    const float* ia1  = (const float*)d_in[15];
    const float* W1   = (const float*)d_in[16];
    const float* b1   = (const float*)d_in[17];
    const float* na2  = (const float*)d_in[18];
    const float* ea2  = (const float*)d_in[19];
    const float* ia2  = (const float*)d_in[20];
    const float* W2   = (const float*)d_in[21];
    const float* b2   = (const float*)d_in[22];
    const float* Wout = (const float*)d_in[23];
    const float* bout = (const float*)d_in[24];

    // Workspace layout (floats), reused across the two modes (sequential).
    float* ws = (float*)d_ws;
    size_t off = 0;
    float* z0    = ws + off; off += (size_t)NS0 * D_DIM;   // 12.8M
    float* wz    = ws + off; off += (size_t)NS0 * D_DIM;   // 12.8M
    float* ps    = ws + off; off += (size_t)NS0 * 2;
    float* qs    = ws + off; off += (size_t)NS0;
    float* pd    = ws + off; off += (size_t)ND0 * 2;
    float* qd    = ws + off; off += (size_t)ND0;
    float* alpha = ws + off; off += (size_t)ND0 * 2;
    float* ee    = ws + off; off += (size_t)E0_N * 2;
    float* ei    = ws + off; off += (size_t)E0_N;
    float* s_acc = ws + off; off += (size_t)ND0 * D_DIM;
    float* eh_acc= ws + off; off += (size_t)ND0 * D_DIM;
    float* ih_acc= ws + off; off += (size_t)ND0 * D_DIM;
    float* deg   = ws + off; off += (size_t)ND0;
    float* z1    = ws + off; off += (size_t)NS1 * D_DIM;
    float* z2    = ws + off; off += (size_t)ND1 * D_DIM;
    (void)ws_size; (void)in_sizes; (void)n_in; (void)out_size;

    const size_t acc_bytes = ((size_t)3 * ND0 * D_DIM + ND0) * sizeof(float);

    for (int m = 0; m < 2; ++m) {
        const int *es0, *ed0, *is0, *id0, *es1, *ed1, *is1, *id1;
        if (m == 0) {
            es0 = src0_cor; ed0 = dst0_cor; is0 = src0_sim; id0 = dst0_sim;
            es1 = src1_cor; ed1 = dst1_cor; is1 = src1_sim; id1 = dst1_sim;
        } else {
            es0 = src0_sim; ed0 = dst0_sim; is0 = src0_cor; id0 = dst0_cor;
            es1 = src1_sim; ed1 = dst1_sim; is1 = src1_cor; id1 = dst1_cor;
        }

        // --- Layer 0: z0 = feat @ Win[m] + b_in[m]   (100000 x 256 x 128)
        gemm_bias<64, 128, 32, 8, 4><<<(NS0 + 63) / 64, 256, 0, stream>>>(
            feat, Win + (size_t)m * F_DIM * D_DIM, b_in + m * D_DIM, z0,
            NS0, F_DIM, D_DIM);

        // --- Layer 1 attention
        node_proj<<<(NS0 + 3) / 4, 256, 0, stream>>>(
            z0, na1 + m * D_DIM * 2, ea1 + m * 2 * D_DIM * 2, ia1 + m * 2 * D_DIM,
            ps, qs, pd, qd, alpha, NS0, ND0);
        edge_logits<<<(E0_N + 255) / 256, 256, 0, stream>>>(
            ps, pd, qs, qd, es0, ed0, is0, id0, ee, ei, E0_N);
        gemm_bias<64, 128, 32, 8, 4><<<(NS0 + 63) / 64, 256, 0, stream>>>(
            z0, W1 + (size_t)m * D_DIM * D_DIM, b1 + m * D_DIM, wz,
            NS0, D_DIM, D_DIM);
        hipMemsetAsync(s_acc, 0, acc_bytes, stream);
        scatter<<<(E0_N + 3) / 4, 256, 0, stream>>>(
            wz, z0, ee, ei, es0, ed0, is0, id0,
            s_acc, eh_acc, ih_acc, deg, E0_N);
        combine<<<(ND0 * D_DIM + 255) / 256, 256, 0, stream>>>(
            s_acc, eh_acc, ih_acc, deg, alpha, z0, z1, ND0);

        // --- Layer 2 attention
        node_proj<<<(NS1 + 3) / 4, 256, 0, stream>>>(
            z1, na2 + m * D_DIM * 2, ea2 + m * 2 * D_DIM * 2, ia2 + m * 2 * D_DIM,
            ps, qs, pd, qd, alpha, NS1, ND1);
        edge_logits<<<(E1_N + 255) / 256, 256, 0, stream>>>(
            ps, pd, qs, qd, es1, ed1, is1, id1, ee, ei, E1_N);
        gemm_bias<64, 128, 32, 8, 4><<<(NS1 + 63) / 64, 256, 0, stream>>>(
            z1, W2 + (size_t)m * D_DIM * D_DIM, b2 + m * D_DIM, wz,
            NS1, D_DIM, D_DIM);
        hipMemsetAsync(s_acc, 0, acc_bytes, stream);
        scatter<<<(E1_N + 3) / 4, 256, 0, stream>>>(
            wz, z1, ee, ei, es1, ed1, is1, id1,
            s_acc, eh_acc, ih_acc, deg, E1_N);
        combine<<<(ND1 * D_DIM + 255) / 256, 256, 0, stream>>>(
            s_acc, eh_acc, ih_acc, deg, alpha, z1, z2, ND1);

        // --- Output: out[m] = z2 @ Wout[m] + bout[m]   (5000 x 128 x 64)
        gemm_bias<64, 64, 32, 8, 2><<<(ND1 + 63) / 64, 256, 0, stream>>>(
            z2, Wout + (size_t)m * D_DIM * O_DIM, bout + m * O_DIM,
            (float*)d_out + (size_t)m * ND1 * O_DIM, ND1, D_DIM, O_DIM);
    }
}

// Round 2
// 1307.196 us; speedup vs baseline: 3.1361x; 3.1361x over previous
//
#include <hip/hip_runtime.h>
#include <math.h>

// Problem constants (fixed by setup_inputs())
#define F_DIM 256
#define D_DIM 128
#define O_DIM 64
#define NS0   100000
#define ND0   25000
#define E0_N  500000
#define NS1   25000
#define ND1   5000
#define E1_N  100000

// ---------------------------------------------------------------------------
// Tiled fp32 GEMM: C[M,N] = A[M,K] @ B[K,N] + bias[N]
// ---------------------------------------------------------------------------
template<int BM, int BN, int BK, int TM, int TN>
__global__ __launch_bounds__(256) void gemm_bias(
    const float* __restrict__ A, const float* __restrict__ B,
    const float* __restrict__ bias, float* __restrict__ C,
    int M, int K, int N)
{
    __shared__ float As[BK][BM];
    __shared__ float Bs[BK][BN];
    const int tid = threadIdx.x;
    const int row0 = blockIdx.x * BM;
    constexpr int TCOLS = BN / TN;
    const int tcol = tid % TCOLS;
    const int trow = tid / TCOLS;
    float acc[TM][TN] = {};

    for (int k0 = 0; k0 < K; k0 += BK) {
        #pragma unroll
        for (int i = 0; i < (BM * BK) / (256 * 4); ++i) {
            int f  = tid + i * 256;
            int r  = f >> 3;
            int kq = f & 7;
            int g  = row0 + r;
            float4 v = make_float4(0.f, 0.f, 0.f, 0.f);
            if (g < M) v = *(const float4*)(A + (size_t)g * K + k0 + kq * 4);
            As[kq * 4 + 0][r] = v.x;
            As[kq * 4 + 1][r] = v.y;
            As[kq * 4 + 2][r] = v.z;
            As[kq * 4 + 3][r] = v.w;
        }
        #pragma unroll
        for (int i = 0; i < (BK * BN) / (256 * 4); ++i) {
            int f  = tid + i * 256;
            int r  = f / (BN / 4);
            int nq = f % (BN / 4);
            float4 v = *(const float4*)(B + (size_t)(k0 + r) * N + nq * 4);
            *(float4*)(&Bs[r][nq * 4]) = v;
        }
        __syncthreads();
        #pragma unroll
        for (int k = 0; k < BK; ++k) {
            float a[TM], b[TN];
            #pragma unroll
            for (int i = 0; i < TM; ++i) a[i] = As[k][trow * TM + i];
            #pragma unroll
            for (int j = 0; j < TN; ++j) b[j] = Bs[k][tcol * TN + j];
            #pragma unroll
            for (int i = 0; i < TM; ++i)
                #pragma unroll
                for (int j = 0; j < TN; ++j)
                    acc[i][j] += a[i] * b[j];
        }
        __syncthreads();
    }
    #pragma unroll
    for (int i = 0; i < TM; ++i) {
        int g = row0 + trow * TM + i;
        if (g < M) {
            #pragma unroll
            for (int j = 0; j < TN; ++j) {
                int c = tcol * TN + j;
                C[(size_t)g * N + c] = acc[i][j] + bias[c];
            }
        }
    }
}

// ---------------------------------------------------------------------------
// CSR construction: histogram -> single-block exclusive scan -> rank perm.
// ---------------------------------------------------------------------------
__global__ void histo(const int* __restrict__ ed, int* __restrict__ cnt, int E)
{
    int e = blockIdx.x * 256 + threadIdx.x;
    if (e < E) atomicAdd(&cnt[ed[e]], 1);
}

__global__ __launch_bounds__(1024) void exscan(
    const int* __restrict__ cnt, int* __restrict__ row,
    int* __restrict__ head, int n)
{
    __shared__ int part[1024];
    const int t = threadIdx.x;
    const int chunk = (n + 1023) >> 10;
    const int start = t * chunk;
    int s = 0;
    for (int i = 0; i < chunk; ++i) {
        int idx = start + i;
        if (idx < n) s += cnt[idx];
    }
    part[t] = s;
    __syncthreads();
    for (int off = 1; off < 1024; off <<= 1) {
        int v = (t >= off) ? part[t - off] : 0;
        __syncthreads();
        part[t] += v;
        __syncthreads();
    }
    int run = (t == 0) ? 0 : part[t - 1];
    for (int i = 0; i < chunk; ++i) {
        int idx = start + i;
        if (idx < n) { row[idx] = run; head[idx] = run; run += cnt[idx]; }
    }
    if (t == 1023) row[n] = part[1023];
}

__global__ void build_csr(
    const int* __restrict__ es, const int* __restrict__ ed,
    int* __restrict__ head, int* __restrict__ pos, int* __restrict__ srcc, int E)
{
    int e = blockIdx.x * 256 + threadIdx.x;
    if (e >= E) return;
    int p = atomicAdd(&head[ed[e]], 1);
    pos[e] = p;
    srcc[p] = es[e];
}

// ---------------------------------------------------------------------------
// Per-node projections: one wave per node, 8 dots of length 128.
// ---------------------------------------------------------------------------
__global__ __launch_bounds__(256) void node_proj(
    const float* __restrict__ z,
    const float* __restrict__ Wna, const float* __restrict__ We,
    const float* __restrict__ Wi,
    float* __restrict__ ps, float* __restrict__ qs,
    float* __restrict__ pd, float* __restrict__ qd,
    float* __restrict__ alpha,
    int n_src, int n_dst)
{
    __shared__ float w[8][D_DIM];
    for (int k = threadIdx.x; k < D_DIM; k += 256) {
        w[0][k] = We[k * 2 + 0];
        w[1][k] = We[k * 2 + 1];
        w[2][k] = Wi[k];
        w[3][k] = We[(D_DIM + k) * 2 + 0];
        w[4][k] = We[(D_DIM + k) * 2 + 1];
        w[5][k] = Wi[D_DIM + k];
        w[6][k] = Wna[k * 2 + 0];
        w[7][k] = Wna[k * 2 + 1];
    }
    __syncthreads();

    const int lane = threadIdx.x & 63;
    const int node = blockIdx.x * 4 + (threadIdx.x >> 6);
    if (node >= n_src) return;

    float2 zv = *(const float2*)(z + (size_t)node * D_DIM + lane * 2);
    float p[8];
    #pragma unroll
    for (int c = 0; c < 8; ++c)
        p[c] = zv.x * w[c][2 * lane] + zv.y * w[c][2 * lane + 1];
    #pragma unroll
    for (int off = 32; off > 0; off >>= 1)
        #pragma unroll
        for (int c = 0; c < 8; ++c)
            p[c] += __shfl_down(p[c], off);

    if (lane == 0) {
        ps[node * 2 + 0] = p[0];
        ps[node * 2 + 1] = p[1];
        qs[node]         = p[2];
        if (node < n_dst) {
            pd[node * 2 + 0] = p[3];
            pd[node * 2 + 1] = p[4];
            qd[node]         = p[5];
            float mx = fmaxf(p[6], p[7]);
            float a0 = expf(p[6] - mx), a1 = expf(p[7] - mx);
            float inv = 1.0f / (a0 + a1);
            alpha[node * 2 + 0] = a0 * inv;
            alpha[node * 2 + 1] = a1 * inv;
        }
    }
}

// ---------------------------------------------------------------------------
// Per-edge attention values, written directly in CSR order via rank arrays.
// ---------------------------------------------------------------------------
__global__ void edge_logits_csr(
    const float* __restrict__ ps, const float* __restrict__ pd,
    const float* __restrict__ qs, const float* __restrict__ qd,
    const int* __restrict__ es, const int* __restrict__ ed,
    const int* __restrict__ is_, const int* __restrict__ id_,
    const int* __restrict__ pos_e, const int* __restrict__ pos_i,
    float* __restrict__ ee_csr, float* __restrict__ ei_csr, int E)
{
    int e = blockIdx.x * blockDim.x + threadIdx.x;
    if (e >= E) return;
    int s = es[e], d = ed[e];
    float l0 = ps[s * 2 + 0] + pd[d * 2 + 0];
    float l1 = ps[s * 2 + 1] + pd[d * 2 + 1];
    float mx = fmaxf(l0, l1);
    float x0 = expf(l0 - mx), x1 = expf(l1 - mx);
    float inv = 1.0f / (x0 + x1);
    int pe = pos_e[e];
    ee_csr[pe * 2 + 0] = x0 * inv;
    ee_csr[pe * 2 + 1] = x1 * inv;
    int si = is_[e], di = id_[e];
    float q = qs[si] + qd[di];
    ei_csr[pos_i[e]] = 1.0f / (1.0f + expf(-q));
}

// ---------------------------------------------------------------------------
// Gather + combine: one wave per dst node, register accumulation, no atomics.
//   z_out = 0.5*( relu(s/max(deg,1)) + relu(eh*ih) + (a0+a1)*z_dst )
// ---------------------------------------------------------------------------
__global__ __launch_bounds__(256) void gather_combine(
    const float* __restrict__ z, const float* __restrict__ wz,
    const float* __restrict__ ee_csr, const float* __restrict__ ei_csr,
    const int* __restrict__ erow, const int* __restrict__ esrc,
    const int* __restrict__ irow, const int* __restrict__ isrc,
    const float* __restrict__ alpha, float* __restrict__ zout, int n_dst)
{
    const int d = blockIdx.x * 4 + (threadIdx.x >> 6);
    const int lane = threadIdx.x & 63;
    if (d >= n_dst) return;

    float sx = 0.f, sy = 0.f, ehx = 0.f, ehy = 0.f, ihx = 0.f, ihy = 0.f;

    const int b0 = erow[d], b1 = erow[d + 1];
    for (int j = b0; j < b1; ++j) {
        int s = esrc[j];
        float e0 = ee_csr[j * 2 + 0];
        float e1 = ee_csr[j * 2 + 1];
        float2 wzv = *(const float2*)(wz + (size_t)s * D_DIM + lane * 2);
        float2 zv  = *(const float2*)(z  + (size_t)s * D_DIM + lane * 2);
        sx  += e0 * wzv.x; sy  += e0 * wzv.y;
        ehx += e1 * zv.x;  ehy += e1 * zv.y;
    }
    const int c0 = irow[d], c1 = irow[d + 1];
    for (int j = c0; j < c1; ++j) {
        int si = isrc[j];
        float sg = ei_csr[j];
        float2 zv = *(const float2*)(z + (size_t)si * D_DIM + lane * 2);
        ihx += sg * zv.x; ihy += sg * zv.y;
    }

    float inv = 1.0f / fmaxf((float)(b1 - b0), 1.0f);
    float fx = fmaxf(sx * inv, 0.f), fy = fmaxf(sy * inv, 0.f);
    float ix = fmaxf(ehx * ihx, 0.f), iy = fmaxf(ehy * ihy, 0.f);
    float a = alpha[d * 2 + 0] + alpha[d * 2 + 1];
    float2 zd = *(const float2*)(z + (size_t)d * D_DIM + lane * 2);
    float2 o;
    o.x = 0.5f * (fx + ix + a * zd.x);
    o.y = 0.5f * (fy + iy + a * zd.y);
    *(float2*)(zout + (size_t)d * D_DIM + lane * 2) = o;
}

// ---------------------------------------------------------------------------
extern "C" void kernel_launch(void* const* d_in, const int* in_sizes, int n_in,
                              void* d_out, int out_size, void* d_ws, size_t ws_size,
                              hipStream_t stream)
{
    const float* feat = (const float*)d_in[0];
    const int* src0_cor = (const int*)d_in[1];
    const int* dst0_cor = (const int*)d_in[2];
    const int* src0_sim = (const int*)d_in[3];
    const int* dst0_sim = (const int*)d_in[4];
    const int* src1_cor = (const int*)d_in[5];
    const int* dst1_cor = (const int*)d_in[6];
    const int* src1_sim = (const int*)d_in[7];
    const int* dst1_sim = (const int*)d_in[8];
    const float* Win  = (const float*)d_in[11];
    const float* b_in = (const float*)d_in[12];
    const float* na1  = (const float*)d_in[13];
    const float* ea1  = (const float*)d_in[14];
    const float* ia1  = (const float*)d_in[15];
    const float* W1   = (const float*)d_in[16];
    const float* b1   = (const float*)d_in[17];
    const float* na2  = (const float*)d_in[18];
    const float* ea2  = (const float*)d_in[19];
    const float* ia2  = (const float*)d_in[20];
    const float* W2   = (const float*)d_in[21];
    const float* b2   = (const float*)d_in[22];
    const float* Wout = (const float*)d_in[23];
    const float* bout = (const float*)d_in[24];
    (void)in_sizes; (void)n_in; (void)out_size; (void)ws_size;

    // ---- workspace layout (4-byte elements) ----
    char* wsb = (char*)d_ws;
    size_t off = 0;
    auto alloc_f = [&](size_t n) { float* p = (float*)(wsb + off); off += n * 4; return p; };
    auto alloc_i = [&](size_t n) { int*   p = (int*)  (wsb + off); off += n * 4; return p; };

    float* z0     = alloc_f((size_t)NS0 * D_DIM);
    float* wz     = alloc_f((size_t)NS0 * D_DIM);
    float* ps     = alloc_f((size_t)NS0 * 2);
    float* qs     = alloc_f(NS0);
    float* pd     = alloc_f((size_t)ND0 * 2);
    float* qd     = alloc_f(ND0);
    float* alpha  = alloc_f((size_t)ND0 * 2);
    float* ee_csr = alloc_f((size_t)E0_N * 2);
    float* ei_csr = alloc_f(E0_N);
    float* z1     = alloc_f((size_t)NS1 * D_DIM);
    float* z2     = alloc_f((size_t)ND1 * D_DIM);

    // CSR storage for the 4 edge lists
    int* pos_c0 = alloc_i(E0_N); int* src_c0 = alloc_i(E0_N);
    int* row_c0 = alloc_i(ND0 + 1); int* head_c0 = alloc_i(ND0);
    int* pos_s0 = alloc_i(E0_N); int* src_s0 = alloc_i(E0_N);
    int* row_s0 = alloc_i(ND0 + 1); int* head_s0 = alloc_i(ND0);
    int* pos_c1 = alloc_i(E1_N); int* src_c1 = alloc_i(E1_N);
    int* row_c1 = alloc_i(ND1 + 1); int* head_c1 = alloc_i(ND1);
    int* pos_s1 = alloc_i(E1_N); int* src_s1 = alloc_i(E1_N);
    int* row_s1 = alloc_i(ND1 + 1); int* head_s1 = alloc_i(ND1);
    int* cnt    = alloc_i(ND0);   // shared histogram scratch

    // ---- build the 4 CSRs (launch-invariant graph structure) ----
    auto make_csr = [&](const int* es, const int* ed, int n_dst, int E,
                        int* pos, int* srcc, int* row, int* head) {
        hipMemsetAsync(cnt, 0, (size_t)n_dst * 4, stream);
        histo<<<(E + 255) / 256, 256, 0, stream>>>(ed, cnt, E);
        exscan<<<1, 1024, 0, stream>>>(cnt, row, head, n_dst);
        build_csr<<<(E + 255) / 256, 256, 0, stream>>>(es, ed, head, pos, srcc, E);
    };
    make_csr(src0_cor, dst0_cor, ND0, E0_N, pos_c0, src_c0, row_c0, head_c0);
    make_csr(src0_sim, dst0_sim, ND0, E0_N, pos_s0, src_s0, row_s0, head_s0);
    make_csr(src1_cor, dst1_cor, ND1, E1_N, pos_c1, src_c1, row_c1, head_c1);
    make_csr(src1_sim, dst1_sim, ND1, E1_N, pos_s1, src_s1, row_s1, head_s1);

    for (int m = 0; m < 2; ++m) {
        // channel -> CSR selection (mode 0: e=cor, i=sim; mode 1: swapped)
        const int *ep0, *ed0, *ip0, *id0;        // original index arrays (layer0)
        const int *pe0, *pi0, *er0, *esr0, *ir0, *isr0;
        const int *ep1, *edd1, *ip1, *idd1;      // layer1
        const int *pe1, *pi1, *er1, *esr1, *ir1, *isr1;
        if (m == 0) {
            ep0 = src0_cor; ed0 = dst0_cor; ip0 = src0_sim; id0 = dst0_sim;
            pe0 = pos_c0; pi0 = pos_s0; er0 = row_c0; esr0 = src_c0; ir0 = row_s0; isr0 = src_s0;
            ep1 = src1_cor; edd1 = dst1_cor; ip1 = src1_sim; idd1 = dst1_sim;
            pe1 = pos_c1; pi1 = pos_s1; er1 = row_c1; esr1 = src_c1; ir1 = row_s1; isr1 = src_s1;
        } else {
            ep0 = src0_sim; ed0 = dst0_sim; ip0 = src0_cor; id0 = dst0_cor;
            pe0 = pos_s0; pi0 = pos_c0; er0 = row_s0; esr0 = src_s0; ir0 = row_c0; isr0 = src_c0;
            ep1 = src1_sim; edd1 = dst1_sim; ip1 = src1_cor; idd1 = dst1_cor;
            pe1 = pos_s1; pi1 = pos_c1; er1 = row_s1; esr1 = src_s1; ir1 = row_c1; isr1 = src_c1;
        }

        // --- Layer 0: z0 = feat @ Win[m] + b_in[m]
        gemm_bias<64, 128, 32, 8, 4><<<(NS0 + 63) / 64, 256, 0, stream>>>(
            feat, Win + (size_t)m * F_DIM * D_DIM, b_in + m * D_DIM, z0,
            NS0, F_DIM, D_DIM);

        // --- Layer 1
        node_proj<<<(NS0 + 3) / 4, 256, 0, stream>>>(
            z0, na1 + m * D_DIM * 2, ea1 + m * 2 * D_DIM * 2, ia1 + m * 2 * D_DIM,
            ps, qs, pd, qd, alpha, NS0, ND0);
        edge_logits_csr<<<(E0_N + 255) / 256, 256, 0, stream>>>(
            ps, pd, qs, qd, ep0, ed0, ip0, id0, pe0, pi0, ee_csr, ei_csr, E0_N);
        gemm_bias<64, 128, 32, 8, 4><<<(NS0 + 63) / 64, 256, 0, stream>>>(
            z0, W1 + (size_t)m * D_DIM * D_DIM, b1 + m * D_DIM, wz,
            NS0, D_DIM, D_DIM);
        gather_combine<<<(ND0 + 3) / 4, 256, 0, stream>>>(
            z0, wz, ee_csr, ei_csr, er0, esr0, ir0, isr0, alpha, z1, ND0);

        // --- Layer 2
        node_proj<<<(NS1 + 3) / 4, 256, 0, stream>>>(
            z1, na2 + m * D_DIM * 2, ea2 + m * 2 * D_DIM * 2, ia2 + m * 2 * D_DIM,
            ps, qs, pd, qd, alpha, NS1, ND1);
        edge_logits_csr<<<(E1_N + 255) / 256, 256, 0, stream>>>(
            ps, pd, qs, qd, ep1, edd1, ip1, idd1, pe1, pi1, ee_csr, ei_csr, E1_N);
        gemm_bias<64, 128, 32, 8, 4><<<(NS1 + 63) / 64, 256, 0, stream>>>(
            z1, W2 + (size_t)m * D_DIM * D_DIM, b2 + m * D_DIM, wz,
            NS1, D_DIM, D_DIM);
        gather_combine<<<(ND1 + 3) / 4, 256, 0, stream>>>(
            z1, wz, ee_csr, ei_csr, er1, esr1, ir1, isr1, alpha, z2, ND1);

        // --- Output: out[m] = z2 @ Wout[m] + bout[m]
        gemm_bias<64, 64, 32, 8, 2><<<(ND1 + 63) / 64, 256, 0, stream>>>(
            z2, Wout + (size_t)m * D_DIM * O_DIM, bout + m * O_DIM,
            (float*)d_out + (size_t)m * ND1 * O_DIM, ND1, D_DIM, O_DIM);
    }
}

// Round 3
// 1094.437 us; speedup vs baseline: 3.7458x; 1.1944x over previous
//
#include <hip/hip_runtime.h>
#include <hip/hip_bf16.h>
#include <math.h>

// Problem constants (fixed by setup_inputs())
#define F_DIM 256
#define D_DIM 128
#define O_DIM 64
#define NS0   100000
#define ND0   25000
#define E0_N  500000
#define NS1   25000
#define ND1   5000
#define E1_N  100000

typedef __attribute__((ext_vector_type(8))) short s8v;   // 8 bf16 (4 VGPRs)
typedef __attribute__((ext_vector_type(4))) float f4v;   // 4 fp32 acc

__device__ __forceinline__ float bf2f(ushort u) {
    union { uint i; float f; } v; v.i = ((uint)u) << 16; return v.f;
}
__device__ __forceinline__ float2 unpack2(uint u) {
    union { uint i; float f; } a, b;
    a.i = (u & 0xffffu) << 16; b.i = u & 0xffff0000u;
    return make_float2(a.f, b.f);
}
__device__ __forceinline__ ushort f2bf(float f) {
    __hip_bfloat16 h = __float2bfloat16(f);
    return *(ushort*)&h;
}

// ---------------------------------------------------------------------------
// fp32 -> bf16 bulk convert (n % 4 == 0)
// ---------------------------------------------------------------------------
__global__ void cvt_bf16(const float* __restrict__ in, ushort* __restrict__ out, int n)
{
    int i = (blockIdx.x * 256 + threadIdx.x) * 4;
    if (i >= n) return;
    float4 v = *(const float4*)(in + i);
    ushort4 o;
    o.x = f2bf(v.x); o.y = f2bf(v.y); o.z = f2bf(v.z); o.w = f2bf(v.w);
    *(ushort4*)(out + i) = o;
}

// Weight [K][N] fp32 -> [N][K] bf16 (transposed, tiny matrices)
__global__ void wt_bf16(const float* __restrict__ W, ushort* __restrict__ Wt, int K, int N)
{
    int i = blockIdx.x * 256 + threadIdx.x;
    if (i >= K * N) return;
    int k = i / N, n = i % N;
    Wt[(size_t)n * K + k] = f2bf(W[(size_t)k * N + n]);
}

// ---------------------------------------------------------------------------
// MFMA bf16 GEMM: C[M,NW] = A[M,KD](bf16,row-major) @ Bt[NW,KD]^T + bias
// Block: 128 rows x NW cols, 256 threads (4 waves).
// NW=128: waves 2x2 (64x64 each). NW=64: waves 4x1 (32x64 each).
// Whole Bt staged in LDS once; A streamed in BK=32 chunks.
// ---------------------------------------------------------------------------
template<int NW, int KD, bool OUTF32>
__global__ __launch_bounds__(256) void mfma_gemm(
    const ushort* __restrict__ A, const ushort* __restrict__ Bt,
    const float* __restrict__ bias, void* __restrict__ Cout, int M)
{
    constexpr int PB = KD + 8;       // +8 bf16 pad -> 2-way bank alias (free)
    constexpr int PA = 40;           // 32 + 8 pad
    constexpr int WAVES_M = (NW == 128) ? 2 : 4;
    constexpr int WM = 128 / WAVES_M;     // 64 or 32
    constexpr int TM = WM / 16;           // 4 or 2
    constexpr int TN = 4;                 // 64 cols per wave
    __shared__ ushort Bs[NW * PB];
    __shared__ ushort As[128 * PA];

    const int tid  = threadIdx.x;
    const int row0 = blockIdx.x * 128;
    const int wave = tid >> 6, lane = tid & 63;
    const int l15 = lane & 15, l4 = lane >> 4;
    int wm0, wn0;
    if (NW == 128) { wm0 = (wave >> 1) * 64; wn0 = (wave & 1) * 64; }
    else           { wm0 = wave * WM;        wn0 = 0; }

    // stage full Bt (vector copies; weights are tiny + L2-hot)
    constexpr int BGROUPS = NW * KD / 8;
    for (int f = tid; f < BGROUPS; f += 256) {
        int r = (f * 8) / KD, c = (f * 8) % KD;
        *(float4*)(&Bs[r * PB + c]) = *(const float4*)(Bt + (size_t)r * KD + c);
    }

    f4v acc[TM][TN];
    #pragma unroll
    for (int i = 0; i < TM; ++i)
        #pragma unroll
        for (int j = 0; j < TN; ++j)
            acc[i][j] = (f4v)(0.0f);

    for (int kc = 0; kc < KD; kc += 32) {
        __syncthreads();
        // stage A chunk: 128 rows x 32 bf16
        #pragma unroll
        for (int it = 0; it < 2; ++it) {
            int f = tid + it * 256;
            int r = f >> 2, g = (f & 3) * 8;
            int gr = row0 + r;
            float4 v = make_float4(0.f, 0.f, 0.f, 0.f);
            if (gr < M) v = *(const float4*)(A + (size_t)gr * KD + kc + g);
            *(float4*)(&As[r * PA + g]) = v;
        }
        __syncthreads();

        s8v af[TM], bfr[TN];
        #pragma unroll
        for (int i = 0; i < TM; ++i)
            af[i] = *(const s8v*)(&As[(wm0 + i * 16 + l15) * PA + l4 * 8]);
        #pragma unroll
        for (int j = 0; j < TN; ++j)
            bfr[j] = *(const s8v*)(&Bs[(wn0 + j * 16 + l15) * PB + kc + l4 * 8]);
        #pragma unroll
        for (int i = 0; i < TM; ++i)
            #pragma unroll
            for (int j = 0; j < TN; ++j)
                acc[i][j] = __builtin_amdgcn_mfma_f32_16x16x32_bf16(
                    af[i], bfr[j], acc[i][j], 0, 0, 0);
    }

    // epilogue: row = wm0 + mt*16 + l4*4 + ii, col = wn0 + nt*16 + l15
    #pragma unroll
    for (int i = 0; i < TM; ++i) {
        #pragma unroll
        for (int ii = 0; ii < 4; ++ii) {
            int row = row0 + wm0 + i * 16 + l4 * 4 + ii;
            if (row < M) {
                #pragma unroll
                for (int j = 0; j < TN; ++j) {
                    int col = wn0 + j * 16 + l15;
                    float val = acc[i][j][ii] + bias[col];
                    if (OUTF32) ((float*)Cout)[(size_t)row * NW + col] = val;
                    else ((ushort*)Cout)[(size_t)row * NW + col] = f2bf(val);
                }
            }
        }
    }
}

// ---------------------------------------------------------------------------
// CSR construction: histogram -> single-block exclusive scan -> rank perm.
// ---------------------------------------------------------------------------
__global__ void histo(const int* __restrict__ ed, int* __restrict__ cnt, int E)
{
    int e = blockIdx.x * 256 + threadIdx.x;
    if (e < E) atomicAdd(&cnt[ed[e]], 1);
}

__global__ __launch_bounds__(1024) void exscan(
    const int* __restrict__ cnt, int* __restrict__ row,
    int* __restrict__ head, int n)
{
    __shared__ int part[1024];
    const int t = threadIdx.x;
    const int chunk = (n + 1023) >> 10;
    const int start = t * chunk;
    int s = 0;
    for (int i = 0; i < chunk; ++i) {
        int idx = start + i;
        if (idx < n) s += cnt[idx];
    }
    part[t] = s;
    __syncthreads();
    for (int off = 1; off < 1024; off <<= 1) {
        int v = (t >= off) ? part[t - off] : 0;
        __syncthreads();
        part[t] += v;
        __syncthreads();
    }
    int run = (t == 0) ? 0 : part[t - 1];
    for (int i = 0; i < chunk; ++i) {
        int idx = start + i;
        if (idx < n) { row[idx] = run; head[idx] = run; run += cnt[idx]; }
    }
    if (t == 1023) row[n] = part[1023];
}

__global__ void build_csr(
    const int* __restrict__ es, const int* __restrict__ ed,
    int* __restrict__ head, int* __restrict__ pos, int* __restrict__ srcc, int E)
{
    int e = blockIdx.x * 256 + threadIdx.x;
    if (e >= E) return;
    int p = atomicAdd(&head[ed[e]], 1);
    pos[e] = p;
    srcc[p] = es[e];
}

// ---------------------------------------------------------------------------
// Per-node projections on bf16 z: one wave per node, 8 dots of length 128.
// ---------------------------------------------------------------------------
__global__ __launch_bounds__(256) void node_proj(
    const ushort* __restrict__ z,
    const float* __restrict__ Wna, const float* __restrict__ We,
    const float* __restrict__ Wi,
    float* __restrict__ ps, float* __restrict__ qs,
    float* __restrict__ pd, float* __restrict__ qd,
    float* __restrict__ alpha,
    int n_src, int n_dst)
{
    __shared__ float w[8][D_DIM];
    for (int k = threadIdx.x; k < D_DIM; k += 256) {
        w[0][k] = We[k * 2 + 0];
        w[1][k] = We[k * 2 + 1];
        w[2][k] = Wi[k];
        w[3][k] = We[(D_DIM + k) * 2 + 0];
        w[4][k] = We[(D_DIM + k) * 2 + 1];
        w[5][k] = Wi[D_DIM + k];
        w[6][k] = Wna[k * 2 + 0];
        w[7][k] = Wna[k * 2 + 1];
    }
    __syncthreads();

    const int lane = threadIdx.x & 63;
    const int node = blockIdx.x * 4 + (threadIdx.x >> 6);
    if (node >= n_src) return;

    float2 zv = unpack2(*(const uint*)(z + (size_t)node * D_DIM + lane * 2));
    float p[8];
    #pragma unroll
    for (int c = 0; c < 8; ++c)
        p[c] = zv.x * w[c][2 * lane] + zv.y * w[c][2 * lane + 1];
    #pragma unroll
    for (int off = 32; off > 0; off >>= 1)
        #pragma unroll
        for (int c = 0; c < 8; ++c)
            p[c] += __shfl_down(p[c], off);

    if (lane == 0) {
        ps[node * 2 + 0] = p[0];
        ps[node * 2 + 1] = p[1];
        qs[node]         = p[2];
        if (node < n_dst) {
            pd[node * 2 + 0] = p[3];
            pd[node * 2 + 1] = p[4];
            qd[node]         = p[5];
            float mx = fmaxf(p[6], p[7]);
            float a0 = expf(p[6] - mx), a1 = expf(p[7] - mx);
            float inv = 1.0f / (a0 + a1);
            alpha[node * 2 + 0] = a0 * inv;
            alpha[node * 2 + 1] = a1 * inv;
        }
    }
}

// ---------------------------------------------------------------------------
// Per-edge attention values, written directly in CSR order via rank arrays.
// ---------------------------------------------------------------------------
__global__ void edge_logits_csr(
    const float* __restrict__ ps, const float* __restrict__ pd,
    const float* __restrict__ qs, const float* __restrict__ qd,
    const int* __restrict__ es, const int* __restrict__ ed,
    const int* __restrict__ is_, const int* __restrict__ id_,
    const int* __restrict__ pos_e, const int* __restrict__ pos_i,
    float* __restrict__ ee_csr, float* __restrict__ ei_csr, int E)
{
    int e = blockIdx.x * blockDim.x + threadIdx.x;
    if (e >= E) return;
    int s = es[e], d = ed[e];
    float l0 = ps[s * 2 + 0] + pd[d * 2 + 0];
    float l1 = ps[s * 2 + 1] + pd[d * 2 + 1];
    float mx = fmaxf(l0, l1);
    float x0 = expf(l0 - mx), x1 = expf(l1 - mx);
    float inv = 1.0f / (x0 + x1);
    int pe = pos_e[e];
    ee_csr[pe * 2 + 0] = x0 * inv;
    ee_csr[pe * 2 + 1] = x1 * inv;
    int si = is_[e], di = id_[e];
    float q = qs[si] + qd[di];
    ei_csr[pos_i[e]] = 1.0f / (1.0f + expf(-q));
}

// ---------------------------------------------------------------------------
// Gather + combine on bf16 rows: one wave per dst node, 2 channels/lane.
//   z_out = 0.5*( relu(s/max(deg,1)) + relu(eh*ih) + (a0+a1)*z_dst )
// ---------------------------------------------------------------------------
__global__ __launch_bounds__(256) void gather_combine(
    const ushort* __restrict__ z, const ushort* __restrict__ wz,
    const float* __restrict__ ee_csr, const float* __restrict__ ei_csr,
    const int* __restrict__ erow, const int* __restrict__ esrc,
    const int* __restrict__ irow, const int* __restrict__ isrc,
    const float* __restrict__ alpha, ushort* __restrict__ zout, int n_dst)
{
    const int d = blockIdx.x * 4 + (threadIdx.x >> 6);
    const int lane = threadIdx.x & 63;
    if (d >= n_dst) return;

    float sx = 0.f, sy = 0.f, ehx = 0.f, ehy = 0.f, ihx = 0.f, ihy = 0.f;

    const int b0 = erow[d], b1 = erow[d + 1];
    for (int j = b0; j < b1; ++j) {
        int s = esrc[j];
        float e0 = ee_csr[j * 2 + 0];
        float e1 = ee_csr[j * 2 + 1];
        float2 wzv = unpack2(*(const uint*)(wz + (size_t)s * D_DIM + lane * 2));
        float2 zv  = unpack2(*(const uint*)(z  + (size_t)s * D_DIM + lane * 2));
        sx  += e0 * wzv.x; sy  += e0 * wzv.y;
        ehx += e1 * zv.x;  ehy += e1 * zv.y;
    }
    const int c0 = irow[d], c1 = irow[d + 1];
    for (int j = c0; j < c1; ++j) {
        int si = isrc[j];
        float sg = ei_csr[j];
        float2 zv = unpack2(*(const uint*)(z + (size_t)si * D_DIM + lane * 2));
        ihx += sg * zv.x; ihy += sg * zv.y;
    }

    float inv = 1.0f / fmaxf((float)(b1 - b0), 1.0f);
    float fx = fmaxf(sx * inv, 0.f), fy = fmaxf(sy * inv, 0.f);
    float ix = fmaxf(ehx * ihx, 0.f), iy = fmaxf(ehy * ihy, 0.f);
    float a = alpha[d * 2 + 0] + alpha[d * 2 + 1];
    float2 zd = unpack2(*(const uint*)(z + (size_t)d * D_DIM + lane * 2));
    float ox = 0.5f * (fx + ix + a * zd.x);
    float oy = 0.5f * (fy + iy + a * zd.y);
    uint pk = (uint)f2bf(ox) | ((uint)f2bf(oy) << 16);
    *(uint*)(zout + (size_t)d * D_DIM + lane * 2) = pk;
}

// ---------------------------------------------------------------------------
extern "C" void kernel_launch(void* const* d_in, const int* in_sizes, int n_in,
                              void* d_out, int out_size, void* d_ws, size_t ws_size,
                              hipStream_t stream)
{
    const float* feat = (const float*)d_in[0];
    const int* src0_cor = (const int*)d_in[1];
    const int* dst0_cor = (const int*)d_in[2];
    const int* src0_sim = (const int*)d_in[3];
    const int* dst0_sim = (const int*)d_in[4];
    const int* src1_cor = (const int*)d_in[5];
    const int* dst1_cor = (const int*)d_in[6];
    const int* src1_sim = (const int*)d_in[7];
    const int* dst1_sim = (const int*)d_in[8];
    const float* Win  = (const float*)d_in[11];
    const float* b_in = (const float*)d_in[12];
    const float* na1  = (const float*)d_in[13];
    const float* ea1  = (const float*)d_in[14];
    const float* ia1  = (const float*)d_in[15];
    const float* W1   = (const float*)d_in[16];
    const float* b1   = (const float*)d_in[17];
    const float* na2  = (const float*)d_in[18];
    const float* ea2  = (const float*)d_in[19];
    const float* ia2  = (const float*)d_in[20];
    const float* W2   = (const float*)d_in[21];
    const float* b2   = (const float*)d_in[22];
    const float* Wout = (const float*)d_in[23];
    const float* bout = (const float*)d_in[24];
    (void)in_sizes; (void)n_in; (void)out_size; (void)ws_size;

    // ---- workspace layout ----
    char* wsb = (char*)d_ws;
    size_t off = 0;
    auto alloc_f = [&](size_t n) { float*  p = (float*) (wsb + off); off += n * 4; return p; };
    auto alloc_i = [&](size_t n) { int*    p = (int*)   (wsb + off); off += n * 4; return p; };
    auto alloc_h = [&](size_t n) { ushort* p = (ushort*)(wsb + off); off += ((n * 2 + 15) & ~15ull); return p; };

    ushort* featb = alloc_h((size_t)NS0 * F_DIM);
    ushort* z0b   = alloc_h((size_t)NS0 * D_DIM);
    ushort* wzb   = alloc_h((size_t)NS0 * D_DIM);
    ushort* z1b   = alloc_h((size_t)NS1 * D_DIM);
    ushort* z2b   = alloc_h((size_t)ND1 * D_DIM);
    ushort* Wtin  = alloc_h((size_t)2 * D_DIM * F_DIM);   // [m][n=128][k=256]
    ushort* Wt1   = alloc_h((size_t)2 * D_DIM * D_DIM);
    ushort* Wt2   = alloc_h((size_t)2 * D_DIM * D_DIM);
    ushort* Wtout = alloc_h((size_t)2 * O_DIM * D_DIM);   // [m][n=64][k=128]

    float* ps     = alloc_f((size_t)NS0 * 2);
    float* qs     = alloc_f(NS0);
    float* pd     = alloc_f((size_t)ND0 * 2);
    float* qd     = alloc_f(ND0);
    float* alpha  = alloc_f((size_t)ND0 * 2);
    float* ee_csr = alloc_f((size_t)E0_N * 2);
    float* ei_csr = alloc_f(E0_N);

    int* pos_c0 = alloc_i(E0_N); int* src_c0 = alloc_i(E0_N);
    int* row_c0 = alloc_i(ND0 + 1); int* head_c0 = alloc_i(ND0);
    int* pos_s0 = alloc_i(E0_N); int* src_s0 = alloc_i(E0_N);
    int* row_s0 = alloc_i(ND0 + 1); int* head_s0 = alloc_i(ND0);
    int* pos_c1 = alloc_i(E1_N); int* src_c1 = alloc_i(E1_N);
    int* row_c1 = alloc_i(ND1 + 1); int* head_c1 = alloc_i(ND1);
    int* pos_s1 = alloc_i(E1_N); int* src_s1 = alloc_i(E1_N);
    int* row_s1 = alloc_i(ND1 + 1); int* head_s1 = alloc_i(ND1);
    int* cnt    = alloc_i(ND0);

    // ---- build the 4 CSRs (launch-invariant graph structure) ----
    auto make_csr = [&](const int* es, const int* ed, int n_dst, int E,
                        int* pos, int* srcc, int* row, int* head) {
        hipMemsetAsync(cnt, 0, (size_t)n_dst * 4, stream);
        histo<<<(E + 255) / 256, 256, 0, stream>>>(ed, cnt, E);
        exscan<<<1, 1024, 0, stream>>>(cnt, row, head, n_dst);
        build_csr<<<(E + 255) / 256, 256, 0, stream>>>(es, ed, head, pos, srcc, E);
    };
    make_csr(src0_cor, dst0_cor, ND0, E0_N, pos_c0, src_c0, row_c0, head_c0);
    make_csr(src0_sim, dst0_sim, ND0, E0_N, pos_s0, src_s0, row_s0, head_s0);
    make_csr(src1_cor, dst1_cor, ND1, E1_N, pos_c1, src_c1, row_c1, head_c1);
    make_csr(src1_sim, dst1_sim, ND1, E1_N, pos_s1, src_s1, row_s1, head_s1);

    // ---- dtype prep: feat + transposed bf16 weights ----
    cvt_bf16<<<((size_t)NS0 * F_DIM / 4 + 255) / 256, 256, 0, stream>>>(
        feat, featb, NS0 * F_DIM);
    for (int m = 0; m < 2; ++m) {
        wt_bf16<<<(F_DIM * D_DIM + 255) / 256, 256, 0, stream>>>(
            Win + (size_t)m * F_DIM * D_DIM, Wtin + (size_t)m * D_DIM * F_DIM, F_DIM, D_DIM);
        wt_bf16<<<(D_DIM * D_DIM + 255) / 256, 256, 0, stream>>>(
            W1 + (size_t)m * D_DIM * D_DIM, Wt1 + (size_t)m * D_DIM * D_DIM, D_DIM, D_DIM);
        wt_bf16<<<(D_DIM * D_DIM + 255) / 256, 256, 0, stream>>>(
            W2 + (size_t)m * D_DIM * D_DIM, Wt2 + (size_t)m * D_DIM * D_DIM, D_DIM, D_DIM);
        wt_bf16<<<(D_DIM * O_DIM + 255) / 256, 256, 0, stream>>>(
            Wout + (size_t)m * D_DIM * O_DIM, Wtout + (size_t)m * O_DIM * D_DIM, D_DIM, O_DIM);
    }

    for (int m = 0; m < 2; ++m) {
        const int *ep0, *ed0, *ip0, *id0;
        const int *pe0, *pi0, *er0, *esr0, *ir0, *isr0;
        const int *ep1, *edd1, *ip1, *idd1;
        const int *pe1, *pi1, *er1, *esr1, *ir1, *isr1;
        if (m == 0) {
            ep0 = src0_cor; ed0 = dst0_cor; ip0 = src0_sim; id0 = dst0_sim;
            pe0 = pos_c0; pi0 = pos_s0; er0 = row_c0; esr0 = src_c0; ir0 = row_s0; isr0 = src_s0;
            ep1 = src1_cor; edd1 = dst1_cor; ip1 = src1_sim; idd1 = dst1_sim;
            pe1 = pos_c1; pi1 = pos_s1; er1 = row_c1; esr1 = src_c1; ir1 = row_s1; isr1 = src_s1;
        } else {
            ep0 = src0_sim; ed0 = dst0_sim; ip0 = src0_cor; id0 = dst0_cor;
            pe0 = pos_s0; pi0 = pos_c0; er0 = row_s0; esr0 = src_s0; ir0 = row_c0; isr0 = src_c0;
            ep1 = src1_sim; edd1 = dst1_sim; ip1 = src1_cor; idd1 = dst1_cor;
            pe1 = pos_s1; pi1 = pos_c1; er1 = row_s1; esr1 = src_s1; ir1 = row_c1; isr1 = src_c1;
        }

        // --- Layer 0: z0 = feat @ Win[m] + b_in[m]  (MFMA bf16)
        mfma_gemm<128, 256, false><<<(NS0 + 127) / 128, 256, 0, stream>>>(
            featb, Wtin + (size_t)m * D_DIM * F_DIM, b_in + m * D_DIM, z0b, NS0);

        // --- Layer 1
        node_proj<<<(NS0 + 3) / 4, 256, 0, stream>>>(
            z0b, na1 + m * D_DIM * 2, ea1 + m * 2 * D_DIM * 2, ia1 + m * 2 * D_DIM,
            ps, qs, pd, qd, alpha, NS0, ND0);
        edge_logits_csr<<<(E0_N + 255) / 256, 256, 0, stream>>>(
            ps, pd, qs, qd, ep0, ed0, ip0, id0, pe0, pi0, ee_csr, ei_csr, E0_N);
        mfma_gemm<128, 128, false><<<(NS0 + 127) / 128, 256, 0, stream>>>(
            z0b, Wt1 + (size_t)m * D_DIM * D_DIM, b1 + m * D_DIM, wzb, NS0);
        gather_combine<<<(ND0 + 3) / 4, 256, 0, stream>>>(
            z0b, wzb, ee_csr, ei_csr, er0, esr0, ir0, isr0, alpha, z1b, ND0);

        // --- Layer 2
        node_proj<<<(NS1 + 3) / 4, 256, 0, stream>>>(
            z1b, na2 + m * D_DIM * 2, ea2 + m * 2 * D_DIM * 2, ia2 + m * 2 * D_DIM,
            ps, qs, pd, qd, alpha, NS1, ND1);
        edge_logits_csr<<<(E1_N + 255) / 256, 256, 0, stream>>>(
            ps, pd, qs, qd, ep1, edd1, ip1, idd1, pe1, pi1, ee_csr, ei_csr, E1_N);
        mfma_gemm<128, 128, false><<<(NS1 + 127) / 128, 256, 0, stream>>>(
            z1b, Wt2 + (size_t)m * D_DIM * D_DIM, b2 + m * D_DIM, wzb, NS1);
        gather_combine<<<(ND1 + 3) / 4, 256, 0, stream>>>(
            z1b, wzb, ee_csr, ei_csr, er1, esr1, ir1, isr1, alpha, z2b, ND1);

        // --- Output: out[m] = z2 @ Wout[m] + bout[m]  (fp32 out)
        mfma_gemm<64, 128, true><<<(ND1 + 127) / 128, 256, 0, stream>>>(
            z2b, Wtout + (size_t)m * O_DIM * D_DIM, bout + m * O_DIM,
            (float*)d_out + (size_t)m * ND1 * O_DIM, ND1);
    }
}

// Round 4
// 942.681 us; speedup vs baseline: 4.3488x; 1.1610x over previous
//
#include <hip/hip_runtime.h>
#include <hip/hip_bf16.h>
#include <math.h>

// Problem constants (fixed by setup_inputs())
#define F_DIM 256
#define D_DIM 128
#define O_DIM 64
#define NS0   100000
#define ND0   25000
#define E0_N  500000
#define NS1   25000
#define ND1   5000
#define E1_N  100000

typedef __attribute__((ext_vector_type(8))) short s8v;   // 8 bf16 (4 VGPRs)
typedef __attribute__((ext_vector_type(4))) float f4v;   // 4 fp32 acc

__device__ __forceinline__ float2 unpack2(uint u) {
    union { uint i; float f; } a, b;
    a.i = (u & 0xffffu) << 16; b.i = u & 0xffff0000u;
    return make_float2(a.f, b.f);
}
__device__ __forceinline__ ushort f2bf(float f) {
    __hip_bfloat16 h = __float2bfloat16(f);
    return *(ushort*)&h;
}

// ---------------------------------------------------------------------------
// fp32 -> bf16 bulk convert (n % 4 == 0)
// ---------------------------------------------------------------------------
__global__ void cvt_bf16(const float* __restrict__ in, ushort* __restrict__ out, int n)
{
    int i = (blockIdx.x * 256 + threadIdx.x) * 4;
    if (i >= n) return;
    float4 v = *(const float4*)(in + i);
    ushort4 o;
    o.x = f2bf(v.x); o.y = f2bf(v.y); o.z = f2bf(v.z); o.w = f2bf(v.w);
    *(ushort4*)(out + i) = o;
}

// Weight [K][N] fp32 -> [N][K] bf16 (transposed, tiny matrices)
__global__ void wt_bf16(const float* __restrict__ W, ushort* __restrict__ Wt, int K, int N)
{
    int i = blockIdx.x * 256 + threadIdx.x;
    if (i >= K * N) return;
    int k = i / N, n = i % N;
    Wt[(size_t)n * K + k] = f2bf(W[(size_t)k * N + n]);
}

// ---------------------------------------------------------------------------
// MFMA bf16 GEMM: C[M,NW] = A[M,KD](bf16,row-major) @ Bt[NW,KD]^T
// EPI 0: +bias -> bf16   EPI 1: +bias -> f32
// EPI 2 (agg-fused): out = partial + 0.5*relu(acc + c[row]*bias[col]) -> bf16
// ---------------------------------------------------------------------------
template<int NW, int KD, int EPI>
__global__ __launch_bounds__(256) void mfma_gemm(
    const ushort* __restrict__ A, const ushort* __restrict__ Bt,
    const float* __restrict__ bias, const float* __restrict__ cvec,
    const float* __restrict__ partial, void* __restrict__ Cout, int M)
{
    constexpr int PB = KD + 8;
    constexpr int PA = 40;
    constexpr int WAVES_M = (NW == 128) ? 2 : 4;
    constexpr int WM = 128 / WAVES_M;
    constexpr int TM = WM / 16;
    constexpr int TN = 4;
    __shared__ ushort Bs[NW * PB];
    __shared__ ushort As[128 * PA];

    const int tid  = threadIdx.x;
    const int row0 = blockIdx.x * 128;
    const int wave = tid >> 6, lane = tid & 63;
    const int l15 = lane & 15, l4 = lane >> 4;
    int wm0, wn0;
    if (NW == 128) { wm0 = (wave >> 1) * 64; wn0 = (wave & 1) * 64; }
    else           { wm0 = wave * WM;        wn0 = 0; }

    constexpr int BGROUPS = NW * KD / 8;
    for (int f = tid; f < BGROUPS; f += 256) {
        int r = (f * 8) / KD, c = (f * 8) % KD;
        *(float4*)(&Bs[r * PB + c]) = *(const float4*)(Bt + (size_t)r * KD + c);
    }

    f4v acc[TM][TN];
    #pragma unroll
    for (int i = 0; i < TM; ++i)
        #pragma unroll
        for (int j = 0; j < TN; ++j)
            acc[i][j] = (f4v)(0.0f);

    for (int kc = 0; kc < KD; kc += 32) {
        __syncthreads();
        #pragma unroll
        for (int it = 0; it < 2; ++it) {
            int f = tid + it * 256;
            int r = f >> 2, g = (f & 3) * 8;
            int gr = row0 + r;
            float4 v = make_float4(0.f, 0.f, 0.f, 0.f);
            if (gr < M) v = *(const float4*)(A + (size_t)gr * KD + kc + g);
            *(float4*)(&As[r * PA + g]) = v;
        }
        __syncthreads();

        s8v af[TM], bfr[TN];
        #pragma unroll
        for (int i = 0; i < TM; ++i)
            af[i] = *(const s8v*)(&As[(wm0 + i * 16 + l15) * PA + l4 * 8]);
        #pragma unroll
        for (int j = 0; j < TN; ++j)
            bfr[j] = *(const s8v*)(&Bs[(wn0 + j * 16 + l15) * PB + kc + l4 * 8]);
        #pragma unroll
        for (int i = 0; i < TM; ++i)
            #pragma unroll
            for (int j = 0; j < TN; ++j)
                acc[i][j] = __builtin_amdgcn_mfma_f32_16x16x32_bf16(
                    af[i], bfr[j], acc[i][j], 0, 0, 0);
    }

    #pragma unroll
    for (int i = 0; i < TM; ++i) {
        #pragma unroll
        for (int ii = 0; ii < 4; ++ii) {
            int row = row0 + wm0 + i * 16 + l4 * 4 + ii;
            if (row < M) {
                #pragma unroll
                for (int j = 0; j < TN; ++j) {
                    int col = wn0 + j * 16 + l15;
                    float a = acc[i][j][ii];
                    if (EPI == 0) {
                        ((ushort*)Cout)[(size_t)row * NW + col] = f2bf(a + bias[col]);
                    } else if (EPI == 1) {
                        ((float*)Cout)[(size_t)row * NW + col] = a + bias[col];
                    } else {
                        float val = a + cvec[row] * bias[col];
                        float o = partial[(size_t)row * NW + col] + 0.5f * fmaxf(val, 0.f);
                        ((ushort*)Cout)[(size_t)row * NW + col] = f2bf(o);
                    }
                }
            }
        }
    }
}

// ---------------------------------------------------------------------------
// CSR construction: histogram -> single-block exclusive scan -> perm.
// ---------------------------------------------------------------------------
__global__ void histo(const int* __restrict__ ed, int* __restrict__ cnt, int E)
{
    int e = blockIdx.x * 256 + threadIdx.x;
    if (e < E) atomicAdd(&cnt[ed[e]], 1);
}

__global__ __launch_bounds__(1024) void exscan(
    const int* __restrict__ cnt, int* __restrict__ row,
    int* __restrict__ head, int n)
{
    __shared__ int part[1024];
    const int t = threadIdx.x;
    const int chunk = (n + 1023) >> 10;
    const int start = t * chunk;
    int s = 0;
    for (int i = 0; i < chunk; ++i) {
        int idx = start + i;
        if (idx < n) s += cnt[idx];
    }
    part[t] = s;
    __syncthreads();
    for (int off = 1; off < 1024; off <<= 1) {
        int v = (t >= off) ? part[t - off] : 0;
        __syncthreads();
        part[t] += v;
        __syncthreads();
    }
    int run = (t == 0) ? 0 : part[t - 1];
    for (int i = 0; i < chunk; ++i) {
        int idx = start + i;
        if (idx < n) { row[idx] = run; head[idx] = run; run += cnt[idx]; }
    }
    if (t == 1023) row[n] = part[1023];
}

__global__ void build_csr(
    const int* __restrict__ es, const int* __restrict__ ed,
    int* __restrict__ head, int* __restrict__ srcc, int* __restrict__ dstc, int E)
{
    int e = blockIdx.x * 256 + threadIdx.x;
    if (e >= E) return;
    int d = ed[e];
    int p = atomicAdd(&head[d], 1);
    srcc[p] = es[e];
    dstc[p] = d;
}

// ---------------------------------------------------------------------------
// Per-node projections on bf16 z: one wave per node, 8 dots of length 128.
// ---------------------------------------------------------------------------
__global__ __launch_bounds__(256) void node_proj(
    const ushort* __restrict__ z,
    const float* __restrict__ Wna, const float* __restrict__ We,
    const float* __restrict__ Wi,
    float* __restrict__ ps, float* __restrict__ qs,
    float* __restrict__ pd, float* __restrict__ qd,
    float* __restrict__ alpha,
    int n_src, int n_dst)
{
    __shared__ float w[8][D_DIM];
    for (int k = threadIdx.x; k < D_DIM; k += 256) {
        w[0][k] = We[k * 2 + 0];
        w[1][k] = We[k * 2 + 1];
        w[2][k] = Wi[k];
        w[3][k] = We[(D_DIM + k) * 2 + 0];
        w[4][k] = We[(D_DIM + k) * 2 + 1];
        w[5][k] = Wi[D_DIM + k];
        w[6][k] = Wna[k * 2 + 0];
        w[7][k] = Wna[k * 2 + 1];
    }
    __syncthreads();

    const int lane = threadIdx.x & 63;
    const int node = blockIdx.x * 4 + (threadIdx.x >> 6);
    if (node >= n_src) return;

    float2 zv = unpack2(*(const uint*)(z + (size_t)node * D_DIM + lane * 2));
    float p[8];
    #pragma unroll
    for (int c = 0; c < 8; ++c)
        p[c] = zv.x * w[c][2 * lane] + zv.y * w[c][2 * lane + 1];
    #pragma unroll
    for (int off = 32; off > 0; off >>= 1)
        #pragma unroll
        for (int c = 0; c < 8; ++c)
            p[c] += __shfl_down(p[c], off);

    if (lane == 0) {
        ps[node * 2 + 0] = p[0];
        ps[node * 2 + 1] = p[1];
        qs[node]         = p[2];
        if (node < n_dst) {
            pd[node * 2 + 0] = p[3];
            pd[node * 2 + 1] = p[4];
            qd[node]         = p[5];
            float mx = fmaxf(p[6], p[7]);
            float a0 = expf(p[6] - mx), a1 = expf(p[7] - mx);
            float inv = 1.0f / (a0 + a1);
            alpha[node * 2 + 0] = a0 * inv;
            alpha[node * 2 + 1] = a1 * inv;
        }
    }
}

// ---------------------------------------------------------------------------
// Edge attention values in CSR order (coalesced writes, semi-sorted dst reads)
// ---------------------------------------------------------------------------
__global__ void ee_kernel(
    const float* __restrict__ ps, const float* __restrict__ pd,
    const int* __restrict__ srcc, const int* __restrict__ dstc,
    float* __restrict__ ee, int E)
{
    int p = blockIdx.x * 256 + threadIdx.x;
    if (p >= E) return;
    int s = srcc[p], d = dstc[p];
    float2 a = *(const float2*)(ps + s * 2);
    float2 b = *(const float2*)(pd + d * 2);
    float l0 = a.x + b.x, l1 = a.y + b.y;
    float mx = fmaxf(l0, l1);
    float x0 = expf(l0 - mx), x1 = expf(l1 - mx);
    float inv = 1.0f / (x0 + x1);
    *(float2*)(ee + 2 * p) = make_float2(x0 * inv, x1 * inv);
}

__global__ void ei_kernel(
    const float* __restrict__ qs, const float* __restrict__ qd,
    const int* __restrict__ srcc, const int* __restrict__ dstc,
    float* __restrict__ ei, int E)
{
    int p = blockIdx.x * 256 + threadIdx.x;
    if (p >= E) return;
    float q = qs[srcc[p]] + qd[dstc[p]];
    ei[p] = 1.0f / (1.0f + expf(-q));
}

// ---------------------------------------------------------------------------
// Gather-accumulate (aggregate-first): one wave per dst node.
//   h0 = (Σ e0 z_s)/deg  -> bf16,   c = (Σ e0)/deg,
//   partial = 0.5*(relu(eh*ih) + (a0+a1)*z_d)  (f32)
// where eh = Σ e1 z_s (e-CSR), ih = Σ sg z_s (i-CSR). Unroll-4 for MLP.
// ---------------------------------------------------------------------------
__global__ __launch_bounds__(256) void gather_acc(
    const ushort* __restrict__ z,
    const float* __restrict__ ee, const float* __restrict__ ei,
    const int* __restrict__ erow, const int* __restrict__ esrc,
    const int* __restrict__ irow, const int* __restrict__ isrc,
    const float* __restrict__ alpha,
    ushort* __restrict__ h0b, float* __restrict__ cvec,
    float* __restrict__ partial, int n_dst)
{
    const int d = blockIdx.x * 4 + (threadIdx.x >> 6);
    const int lane = threadIdx.x & 63;
    if (d >= n_dst) return;

    float h0x = 0.f, h0y = 0.f, ehx = 0.f, ehy = 0.f;
    float ihx = 0.f, ihy = 0.f, se0 = 0.f;

    const int b0 = erow[d], b1 = erow[d + 1];
    int j = b0;
    for (; j + 4 <= b1; j += 4) {
        int s0 = esrc[j], s1 = esrc[j + 1], s2 = esrc[j + 2], s3 = esrc[j + 3];
        float2 w0 = *(const float2*)(ee + 2 * (j + 0));
        float2 w1 = *(const float2*)(ee + 2 * (j + 1));
        float2 w2 = *(const float2*)(ee + 2 * (j + 2));
        float2 w3 = *(const float2*)(ee + 2 * (j + 3));
        uint r0 = *(const uint*)(z + (size_t)s0 * D_DIM + lane * 2);
        uint r1 = *(const uint*)(z + (size_t)s1 * D_DIM + lane * 2);
        uint r2 = *(const uint*)(z + (size_t)s2 * D_DIM + lane * 2);
        uint r3 = *(const uint*)(z + (size_t)s3 * D_DIM + lane * 2);
        float2 v0 = unpack2(r0), v1 = unpack2(r1), v2 = unpack2(r2), v3 = unpack2(r3);
        h0x += w0.x * v0.x + w1.x * v1.x + w2.x * v2.x + w3.x * v3.x;
        h0y += w0.x * v0.y + w1.x * v1.y + w2.x * v2.y + w3.x * v3.y;
        ehx += w0.y * v0.x + w1.y * v1.x + w2.y * v2.x + w3.y * v3.x;
        ehy += w0.y * v0.y + w1.y * v1.y + w2.y * v2.y + w3.y * v3.y;
        se0 += w0.x + w1.x + w2.x + w3.x;
    }
    for (; j < b1; ++j) {
        int s = esrc[j];
        float2 w = *(const float2*)(ee + 2 * j);
        float2 v = unpack2(*(const uint*)(z + (size_t)s * D_DIM + lane * 2));
        h0x += w.x * v.x; h0y += w.x * v.y;
        ehx += w.y * v.x; ehy += w.y * v.y;
        se0 += w.x;
    }

    const int c0 = irow[d], c1 = irow[d + 1];
    j = c0;
    for (; j + 4 <= c1; j += 4) {
        int s0 = isrc[j], s1 = isrc[j + 1], s2 = isrc[j + 2], s3 = isrc[j + 3];
        float g0 = ei[j], g1 = ei[j + 1], g2 = ei[j + 2], g3 = ei[j + 3];
        uint r0 = *(const uint*)(z + (size_t)s0 * D_DIM + lane * 2);
        uint r1 = *(const uint*)(z + (size_t)s1 * D_DIM + lane * 2);
        uint r2 = *(const uint*)(z + (size_t)s2 * D_DIM + lane * 2);
        uint r3 = *(const uint*)(z + (size_t)s3 * D_DIM + lane * 2);
        float2 v0 = unpack2(r0), v1 = unpack2(r1), v2 = unpack2(r2), v3 = unpack2(r3);
        ihx += g0 * v0.x + g1 * v1.x + g2 * v2.x + g3 * v3.x;
        ihy += g0 * v0.y + g1 * v1.y + g2 * v2.y + g3 * v3.y;
    }
    for (; j < c1; ++j) {
        int s = isrc[j];
        float g = ei[j];
        float2 v = unpack2(*(const uint*)(z + (size_t)s * D_DIM + lane * 2));
        ihx += g * v.x; ihy += g * v.y;
    }

    float inv = 1.0f / fmaxf((float)(b1 - b0), 1.0f);
    uint hp = (uint)f2bf(h0x * inv) | ((uint)f2bf(h0y * inv) << 16);
    *(uint*)(h0b + (size_t)d * D_DIM + lane * 2) = hp;
    if (lane == 0) cvec[d] = se0 * inv;

    float a = alpha[d * 2 + 0] + alpha[d * 2 + 1];
    float2 zd = unpack2(*(const uint*)(z + (size_t)d * D_DIM + lane * 2));
    float px = 0.5f * (fmaxf(ehx * ihx, 0.f) + a * zd.x);
    float py = 0.5f * (fmaxf(ehy * ihy, 0.f) + a * zd.y);
    *(float2*)(partial + (size_t)d * D_DIM + lane * 2) = make_float2(px, py);
}

// ---------------------------------------------------------------------------
extern "C" void kernel_launch(void* const* d_in, const int* in_sizes, int n_in,
                              void* d_out, int out_size, void* d_ws, size_t ws_size,
                              hipStream_t stream)
{
    const float* feat = (const float*)d_in[0];
    const int* src0_cor = (const int*)d_in[1];
    const int* dst0_cor = (const int*)d_in[2];
    const int* src0_sim = (const int*)d_in[3];
    const int* dst0_sim = (const int*)d_in[4];
    const int* src1_cor = (const int*)d_in[5];
    const int* dst1_cor = (const int*)d_in[6];
    const int* src1_sim = (const int*)d_in[7];
    const int* dst1_sim = (const int*)d_in[8];
    const float* Win  = (const float*)d_in[11];
    const float* b_in = (const float*)d_in[12];
    const float* na1  = (const float*)d_in[13];
    const float* ea1  = (const float*)d_in[14];
    const float* ia1  = (const float*)d_in[15];
    const float* W1   = (const float*)d_in[16];
    const float* b1   = (const float*)d_in[17];
    const float* na2  = (const float*)d_in[18];
    const float* ea2  = (const float*)d_in[19];
    const float* ia2  = (const float*)d_in[20];
    const float* W2   = (const float*)d_in[21];
    const float* b2   = (const float*)d_in[22];
    const float* Wout = (const float*)d_in[23];
    const float* bout = (const float*)d_in[24];
    (void)in_sizes; (void)n_in; (void)out_size; (void)ws_size;

    // ---- workspace layout ----
    char* wsb = (char*)d_ws;
    size_t off = 0;
    auto alloc_f = [&](size_t n) { float*  p = (float*) (wsb + off); off += n * 4; return p; };
    auto alloc_i = [&](size_t n) { int*    p = (int*)   (wsb + off); off += n * 4; return p; };
    auto alloc_h = [&](size_t n) { ushort* p = (ushort*)(wsb + off); off += ((n * 2 + 15) & ~15ull); return p; };

    ushort* featb = alloc_h((size_t)NS0 * F_DIM);
    ushort* z0b   = alloc_h((size_t)NS0 * D_DIM);
    ushort* z1b   = alloc_h((size_t)NS1 * D_DIM);
    ushort* z2b   = alloc_h((size_t)ND1 * D_DIM);
    ushort* h0b   = alloc_h((size_t)ND0 * D_DIM);
    ushort* Wtin  = alloc_h((size_t)2 * D_DIM * F_DIM);
    ushort* Wt1   = alloc_h((size_t)2 * D_DIM * D_DIM);
    ushort* Wt2   = alloc_h((size_t)2 * D_DIM * D_DIM);
    ushort* Wtout = alloc_h((size_t)2 * O_DIM * D_DIM);

    float* ps      = alloc_f((size_t)NS0 * 2);
    float* qs      = alloc_f(NS0);
    float* pd      = alloc_f((size_t)ND0 * 2);
    float* qd      = alloc_f(ND0);
    float* alpha   = alloc_f((size_t)ND0 * 2);
    float* ee_csr  = alloc_f((size_t)E0_N * 2);
    float* ei_csr  = alloc_f(E0_N);
    float* cvec    = alloc_f(ND0);
    float* partial = alloc_f((size_t)ND0 * D_DIM);

    int* src_c0 = alloc_i(E0_N); int* dst_c0 = alloc_i(E0_N);
    int* row_c0 = alloc_i(ND0 + 1); int* head_c0 = alloc_i(ND0);
    int* src_s0 = alloc_i(E0_N); int* dst_s0 = alloc_i(E0_N);
    int* row_s0 = alloc_i(ND0 + 1); int* head_s0 = alloc_i(ND0);
    int* src_c1 = alloc_i(E1_N); int* dst_c1 = alloc_i(E1_N);
    int* row_c1 = alloc_i(ND1 + 1); int* head_c1 = alloc_i(ND1);
    int* src_s1 = alloc_i(E1_N); int* dst_s1 = alloc_i(E1_N);
    int* row_s1 = alloc_i(ND1 + 1); int* head_s1 = alloc_i(ND1);
    int* cnt    = alloc_i(ND0);

    // ---- build the 4 CSRs (launch-invariant graph structure) ----
    auto make_csr = [&](const int* es, const int* ed, int n_dst, int E,
                        int* srcc, int* dstc, int* row, int* head) {
        hipMemsetAsync(cnt, 0, (size_t)n_dst * 4, stream);
        histo<<<(E + 255) / 256, 256, 0, stream>>>(ed, cnt, E);
        exscan<<<1, 1024, 0, stream>>>(cnt, row, head, n_dst);
        build_csr<<<(E + 255) / 256, 256, 0, stream>>>(es, ed, head, srcc, dstc, E);
    };
    make_csr(src0_cor, dst0_cor, ND0, E0_N, src_c0, dst_c0, row_c0, head_c0);
    make_csr(src0_sim, dst0_sim, ND0, E0_N, src_s0, dst_s0, row_s0, head_s0);
    make_csr(src1_cor, dst1_cor, ND1, E1_N, src_c1, dst_c1, row_c1, head_c1);
    make_csr(src1_sim, dst1_sim, ND1, E1_N, src_s1, dst_s1, row_s1, head_s1);

    // ---- dtype prep: feat + transposed bf16 weights ----
    cvt_bf16<<<((size_t)NS0 * F_DIM / 4 + 255) / 256, 256, 0, stream>>>(
        feat, featb, NS0 * F_DIM);
    for (int m = 0; m < 2; ++m) {
        wt_bf16<<<(F_DIM * D_DIM + 255) / 256, 256, 0, stream>>>(
            Win + (size_t)m * F_DIM * D_DIM, Wtin + (size_t)m * D_DIM * F_DIM, F_DIM, D_DIM);
        wt_bf16<<<(D_DIM * D_DIM + 255) / 256, 256, 0, stream>>>(
            W1 + (size_t)m * D_DIM * D_DIM, Wt1 + (size_t)m * D_DIM * D_DIM, D_DIM, D_DIM);
        wt_bf16<<<(D_DIM * D_DIM + 255) / 256, 256, 0, stream>>>(
            W2 + (size_t)m * D_DIM * D_DIM, Wt2 + (size_t)m * D_DIM * D_DIM, D_DIM, D_DIM);
        wt_bf16<<<(D_DIM * O_DIM + 255) / 256, 256, 0, stream>>>(
            Wout + (size_t)m * D_DIM * O_DIM, Wtout + (size_t)m * O_DIM * D_DIM, D_DIM, O_DIM);
    }

    for (int m = 0; m < 2; ++m) {
        // e-channel CSR / i-channel CSR selection per mode
        const int *er0, *es0, *ed0c, *ir0, *is0, *id0c;
        const int *er1, *es1, *ed1c, *ir1, *is1, *id1c;
        if (m == 0) {
            er0 = row_c0; es0 = src_c0; ed0c = dst_c0; ir0 = row_s0; is0 = src_s0; id0c = dst_s0;
            er1 = row_c1; es1 = src_c1; ed1c = dst_c1; ir1 = row_s1; is1 = src_s1; id1c = dst_s1;
        } else {
            er0 = row_s0; es0 = src_s0; ed0c = dst_s0; ir0 = row_c0; is0 = src_c0; id0c = dst_c0;
            er1 = row_s1; es1 = src_s1; ed1c = dst_s1; ir1 = row_c1; is1 = src_c1; id1c = dst_c1;
        }

        // --- Layer 0: z0 = feat @ Win[m] + b_in[m]
        mfma_gemm<128, 256, 0><<<(NS0 + 127) / 128, 256, 0, stream>>>(
            featb, Wtin + (size_t)m * D_DIM * F_DIM, b_in + m * D_DIM,
            nullptr, nullptr, z0b, NS0);

        // --- Layer 1
        node_proj<<<(NS0 + 3) / 4, 256, 0, stream>>>(
            z0b, na1 + m * D_DIM * 2, ea1 + m * 2 * D_DIM * 2, ia1 + m * 2 * D_DIM,
            ps, qs, pd, qd, alpha, NS0, ND0);
        ee_kernel<<<(E0_N + 255) / 256, 256, 0, stream>>>(ps, pd, es0, ed0c, ee_csr, E0_N);
        ei_kernel<<<(E0_N + 255) / 256, 256, 0, stream>>>(qs, qd, is0, id0c, ei_csr, E0_N);
        gather_acc<<<(ND0 + 3) / 4, 256, 0, stream>>>(
            z0b, ee_csr, ei_csr, er0, es0, ir0, is0, alpha, h0b, cvec, partial, ND0);
        mfma_gemm<128, 128, 2><<<(ND0 + 127) / 128, 256, 0, stream>>>(
            h0b, Wt1 + (size_t)m * D_DIM * D_DIM, b1 + m * D_DIM,
            cvec, partial, z1b, ND0);

        // --- Layer 2
        node_proj<<<(NS1 + 3) / 4, 256, 0, stream>>>(
            z1b, na2 + m * D_DIM * 2, ea2 + m * 2 * D_DIM * 2, ia2 + m * 2 * D_DIM,
            ps, qs, pd, qd, alpha, NS1, ND1);
        ee_kernel<<<(E1_N + 255) / 256, 256, 0, stream>>>(ps, pd, es1, ed1c, ee_csr, E1_N);
        ei_kernel<<<(E1_N + 255) / 256, 256, 0, stream>>>(qs, qd, is1, id1c, ei_csr, E1_N);
        gather_acc<<<(ND1 + 3) / 4, 256, 0, stream>>>(
            z1b, ee_csr, ei_csr, er1, es1, ir1, is1, alpha, h0b, cvec, partial, ND1);
        mfma_gemm<128, 128, 2><<<(ND1 + 127) / 128, 256, 0, stream>>>(
            h0b, Wt2 + (size_t)m * D_DIM * D_DIM, b2 + m * D_DIM,
            cvec, partial, z2b, ND1);

        // --- Output: out[m] = z2 @ Wout[m] + bout[m]  (fp32 out)
        mfma_gemm<64, 128, 1><<<(ND1 + 127) / 128, 256, 0, stream>>>(
            z2b, Wtout + (size_t)m * O_DIM * D_DIM, bout + m * O_DIM,
            nullptr, nullptr, (float*)d_out + (size_t)m * ND1 * O_DIM, ND1);
    }
}

// Round 5
// 808.950 us; speedup vs baseline: 5.0677x; 1.1653x over previous
//
#include <hip/hip_runtime.h>
#include <hip/hip_bf16.h>
#include <math.h>

// Problem constants (fixed by setup_inputs())
#define F_DIM 256
#define D_DIM 128
#define O_DIM 64
#define NS0   100000
#define ND0   25000
#define E0_N  500000
#define NS1   25000
#define ND1   5000
#define E1_N  100000

typedef __attribute__((ext_vector_type(8))) short s8v;   // 8 bf16 (4 VGPRs)
typedef __attribute__((ext_vector_type(4))) float f4v;   // 4 fp32 acc

__device__ __forceinline__ float2 unpack2(uint u) {
    union { uint i; float f; } a, b;
    a.i = (u & 0xffffu) << 16; b.i = u & 0xffff0000u;
    return make_float2(a.f, b.f);
}
__device__ __forceinline__ ushort f2bf(float f) {
    __hip_bfloat16 h = __float2bfloat16(f);
    return *(ushort*)&h;
}

// ---------------------------------------------------------------------------
// fp32 -> bf16 bulk convert (n % 4 == 0)
// ---------------------------------------------------------------------------
__global__ void cvt_bf16(const float* __restrict__ in, ushort* __restrict__ out, int n)
{
    int i = (blockIdx.x * 256 + threadIdx.x) * 4;
    if (i >= n) return;
    float4 v = *(const float4*)(in + i);
    ushort4 o;
    o.x = f2bf(v.x); o.y = f2bf(v.y); o.z = f2bf(v.z); o.w = f2bf(v.w);
    *(ushort4*)(out + i) = o;
}

// Weight [K][N] fp32 -> [N][K] bf16 (transposed, tiny matrices)
__global__ void wt_bf16(const float* __restrict__ W, ushort* __restrict__ Wt, int K, int N)
{
    int i = blockIdx.x * 256 + threadIdx.x;
    if (i >= K * N) return;
    int k = i / N, n = i % N;
    Wt[(size_t)n * K + k] = f2bf(W[(size_t)k * N + n]);
}

// ---------------------------------------------------------------------------
// MFMA bf16 GEMM: C[M,NW] = A[M,KD](bf16,row-major) @ Bt[NW,KD]^T
// EPI 0: +bias -> bf16   EPI 1: +bias -> f32
// EPI 2 (agg-fused): out = partial + 0.5*relu(acc + c[row]*bias[col]) -> bf16
// ---------------------------------------------------------------------------
template<int NW, int KD, int EPI>
__global__ __launch_bounds__(256) void mfma_gemm(
    const ushort* __restrict__ A, const ushort* __restrict__ Bt,
    const float* __restrict__ bias, const float* __restrict__ cvec,
    const float* __restrict__ partial, void* __restrict__ Cout, int M)
{
    constexpr int PB = KD + 8;
    constexpr int PA = 40;
    constexpr int WAVES_M = (NW == 128) ? 2 : 4;
    constexpr int WM = 128 / WAVES_M;
    constexpr int TM = WM / 16;
    constexpr int TN = 4;
    __shared__ ushort Bs[NW * PB];
    __shared__ ushort As[128 * PA];

    const int tid  = threadIdx.x;
    const int row0 = blockIdx.x * 128;
    const int wave = tid >> 6, lane = tid & 63;
    const int l15 = lane & 15, l4 = lane >> 4;
    int wm0, wn0;
    if (NW == 128) { wm0 = (wave >> 1) * 64; wn0 = (wave & 1) * 64; }
    else           { wm0 = wave * WM;        wn0 = 0; }

    constexpr int BGROUPS = NW * KD / 8;
    for (int f = tid; f < BGROUPS; f += 256) {
        int r = (f * 8) / KD, c = (f * 8) % KD;
        *(float4*)(&Bs[r * PB + c]) = *(const float4*)(Bt + (size_t)r * KD + c);
    }

    f4v acc[TM][TN];
    #pragma unroll
    for (int i = 0; i < TM; ++i)
        #pragma unroll
        for (int j = 0; j < TN; ++j)
            acc[i][j] = (f4v)(0.0f);

    for (int kc = 0; kc < KD; kc += 32) {
        __syncthreads();
        #pragma unroll
        for (int it = 0; it < 2; ++it) {
            int f = tid + it * 256;
            int r = f >> 2, g = (f & 3) * 8;
            int gr = row0 + r;
            float4 v = make_float4(0.f, 0.f, 0.f, 0.f);
            if (gr < M) v = *(const float4*)(A + (size_t)gr * KD + kc + g);
            *(float4*)(&As[r * PA + g]) = v;
        }
        __syncthreads();

        s8v af[TM], bfr[TN];
        #pragma unroll
        for (int i = 0; i < TM; ++i)
            af[i] = *(const s8v*)(&As[(wm0 + i * 16 + l15) * PA + l4 * 8]);
        #pragma unroll
        for (int j = 0; j < TN; ++j)
            bfr[j] = *(const s8v*)(&Bs[(wn0 + j * 16 + l15) * PB + kc + l4 * 8]);
        #pragma unroll
        for (int i = 0; i < TM; ++i)
            #pragma unroll
            for (int j = 0; j < TN; ++j)
                acc[i][j] = __builtin_amdgcn_mfma_f32_16x16x32_bf16(
                    af[i], bfr[j], acc[i][j], 0, 0, 0);
    }

    #pragma unroll
    for (int i = 0; i < TM; ++i) {
        #pragma unroll
        for (int ii = 0; ii < 4; ++ii) {
            int row = row0 + wm0 + i * 16 + l4 * 4 + ii;
            if (row < M) {
                #pragma unroll
                for (int j = 0; j < TN; ++j) {
                    int col = wn0 + j * 16 + l15;
                    float a = acc[i][j][ii];
                    if (EPI == 0) {
                        ((ushort*)Cout)[(size_t)row * NW + col] = f2bf(a + bias[col]);
                    } else if (EPI == 1) {
                        ((float*)Cout)[(size_t)row * NW + col] = a + bias[col];
                    } else {
                        float val = a + cvec[row] * bias[col];
                        float o = partial[(size_t)row * NW + col] + 0.5f * fmaxf(val, 0.f);
                        ((ushort*)Cout)[(size_t)row * NW + col] = f2bf(o);
                    }
                }
            }
        }
    }
}

// ---------------------------------------------------------------------------
// CSR construction: histogram -> single-block exclusive scan -> perm.
// ---------------------------------------------------------------------------
__global__ void histo(const int* __restrict__ ed, int* __restrict__ cnt, int E)
{
    int e = blockIdx.x * 256 + threadIdx.x;
    if (e < E) atomicAdd(&cnt[ed[e]], 1);
}

__global__ __launch_bounds__(1024) void exscan(
    const int* __restrict__ cnt, int* __restrict__ row,
    int* __restrict__ head, int n)
{
    __shared__ int part[1024];
    const int t = threadIdx.x;
    const int chunk = (n + 1023) >> 10;
    const int start = t * chunk;
    int s = 0;
    for (int i = 0; i < chunk; ++i) {
        int idx = start + i;
        if (idx < n) s += cnt[idx];
    }
    part[t] = s;
    __syncthreads();
    for (int off = 1; off < 1024; off <<= 1) {
        int v = (t >= off) ? part[t - off] : 0;
        __syncthreads();
        part[t] += v;
        __syncthreads();
    }
    int run = (t == 0) ? 0 : part[t - 1];
    for (int i = 0; i < chunk; ++i) {
        int idx = start + i;
        if (idx < n) { row[idx] = run; head[idx] = run; run += cnt[idx]; }
    }
    if (t == 1023) row[n] = part[1023];
}

__global__ void build_csr(
    const int* __restrict__ es, const int* __restrict__ ed,
    int* __restrict__ head, int* __restrict__ srcc, int* __restrict__ dstc, int E)
{
    int e = blockIdx.x * 256 + threadIdx.x;
    if (e >= E) return;
    int d = ed[e];
    int p = atomicAdd(&head[d], 1);
    srcc[p] = es[e];
    dstc[p] = d;
}

// ---------------------------------------------------------------------------
// Per-node projections on bf16 z. 8 lanes per node; weight slices held in
// registers (96 VGPRs); 4 nodes per 8-lane group. alpha dropped entirely
// (softmax over 2 logits sums to 1 -> (a0+a1)*z_d == z_d).
// Channels: 0:ps0 1:ps1 2:qs 3:pd0 4:pd1 5:qd
// ---------------------------------------------------------------------------
#define NP_NPB 128   // nodes per block (256 threads / 8 lanes * 4 iters)
__global__ __launch_bounds__(256) void node_proj(
    const ushort* __restrict__ z,
    const float* __restrict__ We,    // 2D x 2
    const float* __restrict__ Wi,    // 2D x 1
    float* __restrict__ ps, float* __restrict__ qs,
    float* __restrict__ pd, float* __restrict__ qd,
    int n_src, int n_dst)
{
    __shared__ float w[6][D_DIM];
    for (int k = threadIdx.x; k < D_DIM; k += 256) {
        w[0][k] = We[k * 2 + 0];
        w[1][k] = We[k * 2 + 1];
        w[2][k] = Wi[k];
        w[3][k] = We[(D_DIM + k) * 2 + 0];
        w[4][k] = We[(D_DIM + k) * 2 + 1];
        w[5][k] = Wi[D_DIM + k];
    }
    __syncthreads();

    const int sub = threadIdx.x & 7;   // lane within 8-lane node group
    const int g   = threadIdx.x >> 3;  // group index within block (0..31)

    // one-time: pull this lane's 6x16 weight slice into registers
    float wr[6][16];
    #pragma unroll
    for (int c = 0; c < 6; ++c)
        #pragma unroll
        for (int q = 0; q < 4; ++q) {
            float4 f = *(const float4*)(&w[c][sub * 16 + q * 4]);
            wr[c][q * 4 + 0] = f.x; wr[c][q * 4 + 1] = f.y;
            wr[c][q * 4 + 2] = f.z; wr[c][q * 4 + 3] = f.w;
        }

    #pragma unroll
    for (int it = 0; it < 4; ++it) {
        int node = blockIdx.x * NP_NPB + it * 32 + g;
        if (node >= n_src) continue;
        const ushort* zp = z + (size_t)node * D_DIM + sub * 16;
        uint4 ra = *(const uint4*)zp;
        uint4 rb = *(const uint4*)(zp + 8);
        uint rr[8] = {ra.x, ra.y, ra.z, ra.w, rb.x, rb.y, rb.z, rb.w};
        float p[6] = {0.f, 0.f, 0.f, 0.f, 0.f, 0.f};
        #pragma unroll
        for (int e = 0; e < 8; ++e) {
            float2 f2 = unpack2(rr[e]);
            #pragma unroll
            for (int c = 0; c < 6; ++c)
                p[c] += f2.x * wr[c][2 * e] + f2.y * wr[c][2 * e + 1];
        }
        // reduce across the 8-lane group (chain verified to stay in-group)
        #pragma unroll
        for (int off = 4; off > 0; off >>= 1)
            #pragma unroll
            for (int c = 0; c < 6; ++c)
                p[c] += __shfl_down(p[c], off);

        if (sub == 0) {
            *(float2*)(ps + (size_t)node * 2) = make_float2(p[0], p[1]);
            qs[node] = p[2];
            if (node < n_dst) {
                *(float2*)(pd + (size_t)node * 2) = make_float2(p[3], p[4]);
                qd[node] = p[5];
            }
        }
    }
}

// ---------------------------------------------------------------------------
// Edge attention values in CSR order (e-softmax + i-sigmoid in one kernel)
// ---------------------------------------------------------------------------
__global__ void edge_att(
    const float* __restrict__ ps, const float* __restrict__ pd,
    const float* __restrict__ qs, const float* __restrict__ qd,
    const int* __restrict__ esrcc, const int* __restrict__ edstc,
    const int* __restrict__ isrcc, const int* __restrict__ idstc,
    float* __restrict__ ee, float* __restrict__ ei, int E)
{
    int p = blockIdx.x * 256 + threadIdx.x;
    if (p >= E) return;
    {
        int s = esrcc[p], d = edstc[p];
        float2 a = *(const float2*)(ps + (size_t)s * 2);
        float2 b = *(const float2*)(pd + (size_t)d * 2);
        float l0 = a.x + b.x, l1 = a.y + b.y;
        float mx = fmaxf(l0, l1);
        float x0 = expf(l0 - mx), x1 = expf(l1 - mx);
        float inv = 1.0f / (x0 + x1);
        *(float2*)(ee + 2 * (size_t)p) = make_float2(x0 * inv, x1 * inv);
    }
    {
        float q = qs[isrcc[p]] + qd[idstc[p]];
        ei[p] = 1.0f / (1.0f + expf(-q));
    }
}

// ---------------------------------------------------------------------------
// Gather-accumulate (aggregate-first): one wave per dst node.
//   h0 = (Σ e0 z_s)/deg  -> bf16,   c = (Σ e0)/deg,
//   partial = 0.5*(relu(eh*ih) + z_d)  (f32)   [alpha sums to 1]
// ---------------------------------------------------------------------------
__global__ __launch_bounds__(256) void gather_acc(
    const ushort* __restrict__ z,
    const float* __restrict__ ee, const float* __restrict__ ei,
    const int* __restrict__ erow, const int* __restrict__ esrc,
    const int* __restrict__ irow, const int* __restrict__ isrc,
    ushort* __restrict__ h0b, float* __restrict__ cvec,
    float* __restrict__ partial, int n_dst)
{
    const int d = blockIdx.x * 4 + (threadIdx.x >> 6);
    const int lane = threadIdx.x & 63;
    if (d >= n_dst) return;

    float h0x = 0.f, h0y = 0.f, ehx = 0.f, ehy = 0.f;
    float ihx = 0.f, ihy = 0.f, se0 = 0.f;

    const int b0 = erow[d], b1 = erow[d + 1];
    int j = b0;
    for (; j + 4 <= b1; j += 4) {
        int s0 = esrc[j], s1 = esrc[j + 1], s2 = esrc[j + 2], s3 = esrc[j + 3];
        float2 w0 = *(const float2*)(ee + 2 * (size_t)(j + 0));
        float2 w1 = *(const float2*)(ee + 2 * (size_t)(j + 1));
        float2 w2 = *(const float2*)(ee + 2 * (size_t)(j + 2));
        float2 w3 = *(const float2*)(ee + 2 * (size_t)(j + 3));
        uint r0 = *(const uint*)(z + (size_t)s0 * D_DIM + lane * 2);
        uint r1 = *(const uint*)(z + (size_t)s1 * D_DIM + lane * 2);
        uint r2 = *(const uint*)(z + (size_t)s2 * D_DIM + lane * 2);
        uint r3 = *(const uint*)(z + (size_t)s3 * D_DIM + lane * 2);
        float2 v0 = unpack2(r0), v1 = unpack2(r1), v2 = unpack2(r2), v3 = unpack2(r3);
        h0x += w0.x * v0.x + w1.x * v1.x + w2.x * v2.x + w3.x * v3.x;
        h0y += w0.x * v0.y + w1.x * v1.y + w2.x * v2.y + w3.x * v3.y;
        ehx += w0.y * v0.x + w1.y * v1.x + w2.y * v2.x + w3.y * v3.x;
        ehy += w0.y * v0.y + w1.y * v1.y + w2.y * v2.y + w3.y * v3.y;
        se0 += w0.x + w1.x + w2.x + w3.x;
    }
    for (; j < b1; ++j) {
        int s = esrc[j];
        float2 w = *(const float2*)(ee + 2 * (size_t)j);
        float2 v = unpack2(*(const uint*)(z + (size_t)s * D_DIM + lane * 2));
        h0x += w.x * v.x; h0y += w.x * v.y;
        ehx += w.y * v.x; ehy += w.y * v.y;
        se0 += w.x;
    }

    const int c0 = irow[d], c1 = irow[d + 1];
    j = c0;
    for (; j + 4 <= c1; j += 4) {
        int s0 = isrc[j], s1 = isrc[j + 1], s2 = isrc[j + 2], s3 = isrc[j + 3];
        float g0 = ei[j], g1 = ei[j + 1], g2 = ei[j + 2], g3 = ei[j + 3];
        uint r0 = *(const uint*)(z + (size_t)s0 * D_DIM + lane * 2);
        uint r1 = *(const uint*)(z + (size_t)s1 * D_DIM + lane * 2);
        uint r2 = *(const uint*)(z + (size_t)s2 * D_DIM + lane * 2);
        uint r3 = *(const uint*)(z + (size_t)s3 * D_DIM + lane * 2);
        float2 v0 = unpack2(r0), v1 = unpack2(r1), v2 = unpack2(r2), v3 = unpack2(r3);
        ihx += g0 * v0.x + g1 * v1.x + g2 * v2.x + g3 * v3.x;
        ihy += g0 * v0.y + g1 * v1.y + g2 * v2.y + g3 * v3.y;
    }
    for (; j < c1; ++j) {
        int s = isrc[j];
        float g = ei[j];
        float2 v = unpack2(*(const uint*)(z + (size_t)s * D_DIM + lane * 2));
        ihx += g * v.x; ihy += g * v.y;
    }

    float inv = 1.0f / fmaxf((float)(b1 - b0), 1.0f);
    uint hp = (uint)f2bf(h0x * inv) | ((uint)f2bf(h0y * inv) << 16);
    *(uint*)(h0b + (size_t)d * D_DIM + lane * 2) = hp;
    if (lane == 0) cvec[d] = se0 * inv;

    float2 zd = unpack2(*(const uint*)(z + (size_t)d * D_DIM + lane * 2));
    float px = 0.5f * (fmaxf(ehx * ihx, 0.f) + zd.x);
    float py = 0.5f * (fmaxf(ehy * ihy, 0.f) + zd.y);
    *(float2*)(partial + (size_t)d * D_DIM + lane * 2) = make_float2(px, py);
}

// ---------------------------------------------------------------------------
extern "C" void kernel_launch(void* const* d_in, const int* in_sizes, int n_in,
                              void* d_out, int out_size, void* d_ws, size_t ws_size,
                              hipStream_t stream)
{
    const float* feat = (const float*)d_in[0];
    const int* src0_cor = (const int*)d_in[1];
    const int* dst0_cor = (const int*)d_in[2];
    const int* src0_sim = (const int*)d_in[3];
    const int* dst0_sim = (const int*)d_in[4];
    const int* src1_cor = (const int*)d_in[5];
    const int* dst1_cor = (const int*)d_in[6];
    const int* src1_sim = (const int*)d_in[7];
    const int* dst1_sim = (const int*)d_in[8];
    const float* Win  = (const float*)d_in[11];
    const float* b_in = (const float*)d_in[12];
    const float* ea1  = (const float*)d_in[14];
    const float* ia1  = (const float*)d_in[15];
    const float* W1   = (const float*)d_in[16];
    const float* b1   = (const float*)d_in[17];
    const float* ea2  = (const float*)d_in[19];
    const float* ia2  = (const float*)d_in[20];
    const float* W2   = (const float*)d_in[21];
    const float* b2   = (const float*)d_in[22];
    const float* Wout = (const float*)d_in[23];
    const float* bout = (const float*)d_in[24];
    (void)in_sizes; (void)n_in; (void)out_size; (void)ws_size;

    // ---- workspace layout ----
    char* wsb = (char*)d_ws;
    size_t off = 0;
    auto alloc_f = [&](size_t n) { float*  p = (float*) (wsb + off); off += n * 4; return p; };
    auto alloc_i = [&](size_t n) { int*    p = (int*)   (wsb + off); off += n * 4; return p; };
    auto alloc_h = [&](size_t n) { ushort* p = (ushort*)(wsb + off); off += ((n * 2 + 15) & ~15ull); return p; };

    ushort* featb = alloc_h((size_t)NS0 * F_DIM);
    ushort* z0b   = alloc_h((size_t)NS0 * D_DIM);
    ushort* z1b   = alloc_h((size_t)NS1 * D_DIM);
    ushort* z2b   = alloc_h((size_t)ND1 * D_DIM);
    ushort* h0b   = alloc_h((size_t)ND0 * D_DIM);
    ushort* Wtin  = alloc_h((size_t)2 * D_DIM * F_DIM);
    ushort* Wt1   = alloc_h((size_t)2 * D_DIM * D_DIM);
    ushort* Wt2   = alloc_h((size_t)2 * D_DIM * D_DIM);
    ushort* Wtout = alloc_h((size_t)2 * O_DIM * D_DIM);

    float* ps      = alloc_f((size_t)NS0 * 2);
    float* qs      = alloc_f(NS0);
    float* pd      = alloc_f((size_t)ND0 * 2);
    float* qd      = alloc_f(ND0);
    float* ee_csr  = alloc_f((size_t)E0_N * 2);
    float* ei_csr  = alloc_f(E0_N);
    float* cvec    = alloc_f(ND0);
    float* partial = alloc_f((size_t)ND0 * D_DIM);

    int* src_c0 = alloc_i(E0_N); int* dst_c0 = alloc_i(E0_N);
    int* row_c0 = alloc_i(ND0 + 1); int* head_c0 = alloc_i(ND0);
    int* src_s0 = alloc_i(E0_N); int* dst_s0 = alloc_i(E0_N);
    int* row_s0 = alloc_i(ND0 + 1); int* head_s0 = alloc_i(ND0);
    int* src_c1 = alloc_i(E1_N); int* dst_c1 = alloc_i(E1_N);
    int* row_c1 = alloc_i(ND1 + 1); int* head_c1 = alloc_i(ND1);
    int* src_s1 = alloc_i(E1_N); int* dst_s1 = alloc_i(E1_N);
    int* row_s1 = alloc_i(ND1 + 1); int* head_s1 = alloc_i(ND1);
    int* cnt    = alloc_i(ND0);

    // ---- build the 4 CSRs (launch-invariant graph structure) ----
    auto make_csr = [&](const int* es, const int* ed, int n_dst, int E,
                        int* srcc, int* dstc, int* row, int* head) {
        hipMemsetAsync(cnt, 0, (size_t)n_dst * 4, stream);
        histo<<<(E + 255) / 256, 256, 0, stream>>>(ed, cnt, E);
        exscan<<<1, 1024, 0, stream>>>(cnt, row, head, n_dst);
        build_csr<<<(E + 255) / 256, 256, 0, stream>>>(es, ed, head, srcc, dstc, E);
    };
    make_csr(src0_cor, dst0_cor, ND0, E0_N, src_c0, dst_c0, row_c0, head_c0);
    make_csr(src0_sim, dst0_sim, ND0, E0_N, src_s0, dst_s0, row_s0, head_s0);
    make_csr(src1_cor, dst1_cor, ND1, E1_N, src_c1, dst_c1, row_c1, head_c1);
    make_csr(src1_sim, dst1_sim, ND1, E1_N, src_s1, dst_s1, row_s1, head_s1);

    // ---- dtype prep: feat + transposed bf16 weights ----
    cvt_bf16<<<((size_t)NS0 * F_DIM / 4 + 255) / 256, 256, 0, stream>>>(
        feat, featb, NS0 * F_DIM);
    for (int m = 0; m < 2; ++m) {
        wt_bf16<<<(F_DIM * D_DIM + 255) / 256, 256, 0, stream>>>(
            Win + (size_t)m * F_DIM * D_DIM, Wtin + (size_t)m * D_DIM * F_DIM, F_DIM, D_DIM);
        wt_bf16<<<(D_DIM * D_DIM + 255) / 256, 256, 0, stream>>>(
            W1 + (size_t)m * D_DIM * D_DIM, Wt1 + (size_t)m * D_DIM * D_DIM, D_DIM, D_DIM);
        wt_bf16<<<(D_DIM * D_DIM + 255) / 256, 256, 0, stream>>>(
            W2 + (size_t)m * D_DIM * D_DIM, Wt2 + (size_t)m * D_DIM * D_DIM, D_DIM, D_DIM);
        wt_bf16<<<(D_DIM * O_DIM + 255) / 256, 256, 0, stream>>>(
            Wout + (size_t)m * D_DIM * O_DIM, Wtout + (size_t)m * O_DIM * D_DIM, D_DIM, O_DIM);
    }

    for (int m = 0; m < 2; ++m) {
        // e-channel CSR / i-channel CSR selection per mode
        const int *er0, *es0, *ed0c, *ir0, *is0, *id0c;
        const int *er1, *es1, *ed1c, *ir1, *is1, *id1c;
        if (m == 0) {
            er0 = row_c0; es0 = src_c0; ed0c = dst_c0; ir0 = row_s0; is0 = src_s0; id0c = dst_s0;
            er1 = row_c1; es1 = src_c1; ed1c = dst_c1; ir1 = row_s1; is1 = src_s1; id1c = dst_s1;
        } else {
            er0 = row_s0; es0 = src_s0; ed0c = dst_s0; ir0 = row_c0; is0 = src_c0; id0c = dst_c0;
            er1 = row_s1; es1 = src_s1; ed1c = dst_s1; ir1 = row_c1; is1 = src_c1; id1c = dst_c1;
        }

        // --- Layer 0: z0 = feat @ Win[m] + b_in[m]
        mfma_gemm<128, 256, 0><<<(NS0 + 127) / 128, 256, 0, stream>>>(
            featb, Wtin + (size_t)m * D_DIM * F_DIM, b_in + m * D_DIM,
            nullptr, nullptr, z0b, NS0);

        // --- Layer 1
        node_proj<<<(NS0 + NP_NPB - 1) / NP_NPB, 256, 0, stream>>>(
            z0b, ea1 + m * 2 * D_DIM * 2, ia1 + m * 2 * D_DIM,
            ps, qs, pd, qd, NS0, ND0);
        edge_att<<<(E0_N + 255) / 256, 256, 0, stream>>>(
            ps, pd, qs, qd, es0, ed0c, is0, id0c, ee_csr, ei_csr, E0_N);
        gather_acc<<<(ND0 + 3) / 4, 256, 0, stream>>>(
            z0b, ee_csr, ei_csr, er0, es0, ir0, is0, h0b, cvec, partial, ND0);
        mfma_gemm<128, 128, 2><<<(ND0 + 127) / 128, 256, 0, stream>>>(
            h0b, Wt1 + (size_t)m * D_DIM * D_DIM, b1 + m * D_DIM,
            cvec, partial, z1b, ND0);

        // --- Layer 2
        node_proj<<<(NS1 + NP_NPB - 1) / NP_NPB, 256, 0, stream>>>(
            z1b, ea2 + m * 2 * D_DIM * 2, ia2 + m * 2 * D_DIM,
            ps, qs, pd, qd, NS1, ND1);
        edge_att<<<(E1_N + 255) / 256, 256, 0, stream>>>(
            ps, pd, qs, qd, es1, ed1c, is1, id1c, ee_csr, ei_csr, E1_N);
        gather_acc<<<(ND1 + 3) / 4, 256, 0, stream>>>(
            z1b, ee_csr, ei_csr, er1, es1, ir1, is1, h0b, cvec, partial, ND1);
        mfma_gemm<128, 128, 2><<<(ND1 + 127) / 128, 256, 0, stream>>>(
            h0b, Wt2 + (size_t)m * D_DIM * D_DIM, b2 + m * D_DIM,
            cvec, partial, z2b, ND1);

        // --- Output: out[m] = z2 @ Wout[m] + bout[m]  (fp32 out)
        mfma_gemm<64, 128, 1><<<(ND1 + 127) / 128, 256, 0, stream>>>(
            z2b, Wtout + (size_t)m * O_DIM * D_DIM, bout + m * O_DIM,
            nullptr, nullptr, (float*)d_out + (size_t)m * ND1 * O_DIM, ND1);
    }
}

// Round 6
// 703.913 us; speedup vs baseline: 5.8239x; 1.1492x over previous
//
#include <hip/hip_runtime.h>
#include <hip/hip_bf16.h>
#include <math.h>

// Problem constants (fixed by setup_inputs())
#define F_DIM 256
#define D_DIM 128
#define O_DIM 64
#define NS0   100000
#define ND0   25000
#define E0_N  500000
#define NS1   25000
#define ND1   5000
#define E1_N  100000

#define NBE0  1954   // ceil(E0_N/256)
#define NBE1  391    // ceil(E1_N/256)

typedef __attribute__((ext_vector_type(8))) short s8v;   // 8 bf16 (4 VGPRs)
typedef __attribute__((ext_vector_type(4))) float f4v;   // 4 fp32 acc

struct CPtr4 { const int *p0, *p1, *p2, *p3; };
struct MPtr4 { int *p0, *p1, *p2, *p3; };

__device__ __forceinline__ float2 unpack2(uint u) {
    union { uint i; float f; } a, b;
    a.i = (u & 0xffffu) << 16; b.i = u & 0xffff0000u;
    return make_float2(a.f, b.f);
}
__device__ __forceinline__ ushort f2bf(float f) {
    __hip_bfloat16 h = __float2bfloat16(f);
    return *(ushort*)&h;
}

// ---------------------------------------------------------------------------
// fp32 -> bf16 bulk convert (n % 4 == 0)
// ---------------------------------------------------------------------------
__global__ void cvt_bf16(const float* __restrict__ in, ushort* __restrict__ out, int n)
{
    int i = (blockIdx.x * 256 + threadIdx.x) * 4;
    if (i >= n) return;
    float4 v = *(const float4*)(in + i);
    ushort4 o;
    o.x = f2bf(v.x); o.y = f2bf(v.y); o.z = f2bf(v.z); o.w = f2bf(v.w);
    *(ushort4*)(out + i) = o;
}

// ---------------------------------------------------------------------------
// All weight transposes in ONE launch: [K][N] fp32 -> [N][K] bf16, 8 matrices.
// Element ranges: Wtin 2x256x128 | Wt1 2x128x128 | Wt2 2x128x128 | Wtout 2x128x64
// ---------------------------------------------------------------------------
__global__ void prep_weights(
    const float* __restrict__ Win, const float* __restrict__ W1,
    const float* __restrict__ W2,  const float* __restrict__ Wout,
    ushort* __restrict__ Wtin, ushort* __restrict__ Wt1,
    ushort* __restrict__ Wt2,  ushort* __restrict__ Wtout)
{
    int i = blockIdx.x * 256 + threadIdx.x;
    if (i < 65536) {                                  // Win
        int m = i >> 15, r = i & 32767, k = r >> 7, n = r & 127;
        Wtin[m * 32768 + n * 256 + k] = f2bf(Win[m * 32768 + k * 128 + n]);
    } else if (i < 98304) {                           // W1
        int i2 = i - 65536;
        int m = i2 >> 14, r = i2 & 16383, k = r >> 7, n = r & 127;
        Wt1[m * 16384 + n * 128 + k] = f2bf(W1[m * 16384 + k * 128 + n]);
    } else if (i < 131072) {                          // W2
        int i2 = i - 98304;
        int m = i2 >> 14, r = i2 & 16383, k = r >> 7, n = r & 127;
        Wt2[m * 16384 + n * 128 + k] = f2bf(W2[m * 16384 + k * 128 + n]);
    } else if (i < 147456) {                          // Wout
        int i2 = i - 131072;
        int m = i2 >> 13, r = i2 & 8191, k = r >> 6, n = r & 63;
        Wtout[m * 8192 + n * 128 + k] = f2bf(Wout[m * 8192 + k * 64 + n]);
    }
}

// ---------------------------------------------------------------------------
// MFMA bf16 GEMM: C[M,NW] = A[M,KD](bf16,row-major) @ Bt[NW,KD]^T
// Per-chunk staging of BOTH A and B (LDS 20.5 KB -> high occupancy).
// EPI 0: +bias -> bf16   EPI 1: +bias -> f32
// EPI 2 (agg-fused): out = partial + 0.5*relu(acc + c[row]*bias[col]) -> bf16
// ---------------------------------------------------------------------------
template<int NW, int KD, int EPI>
__global__ __launch_bounds__(256) void mfma_gemm(
    const ushort* __restrict__ A, const ushort* __restrict__ Bt,
    const float* __restrict__ bias, const float* __restrict__ cvec,
    const float* __restrict__ partial, void* __restrict__ Cout, int M)
{
    constexpr int PA = 40;           // 32 + 8 bf16 pad
    constexpr int WAVES_M = (NW == 128) ? 2 : 4;
    constexpr int WM = 128 / WAVES_M;
    constexpr int TM = WM / 16;
    constexpr int TN = 4;
    __shared__ ushort As[128 * PA];
    __shared__ ushort Bs[NW * PA];

    const int tid  = threadIdx.x;
    const int row0 = blockIdx.x * 128;
    const int wave = tid >> 6, lane = tid & 63;
    const int l15 = lane & 15, l4 = lane >> 4;
    int wm0, wn0;
    if (NW == 128) { wm0 = (wave >> 1) * 64; wn0 = (wave & 1) * 64; }
    else           { wm0 = wave * WM;        wn0 = 0; }

    f4v acc[TM][TN];
    #pragma unroll
    for (int i = 0; i < TM; ++i)
        #pragma unroll
        for (int j = 0; j < TN; ++j)
            acc[i][j] = (f4v)(0.0f);

    for (int kc = 0; kc < KD; kc += 32) {
        __syncthreads();
        // stage A chunk: 128 rows x 32 bf16
        #pragma unroll
        for (int it = 0; it < 2; ++it) {
            int f = tid + it * 256;
            int r = f >> 2, g = (f & 3) * 8;
            int gr = row0 + r;
            float4 v = make_float4(0.f, 0.f, 0.f, 0.f);
            if (gr < M) v = *(const float4*)(A + (size_t)gr * KD + kc + g);
            *(float4*)(&As[r * PA + g]) = v;
        }
        // stage B chunk: NW cols x 32 bf16
        #pragma unroll
        for (int it = 0; it < NW * 32 / (256 * 8); ++it) {
            int f = tid + it * 256;
            int r = f >> 2, g = (f & 3) * 8;
            *(float4*)(&Bs[r * PA + g]) = *(const float4*)(Bt + (size_t)r * KD + kc + g);
        }
        __syncthreads();

        s8v af[TM], bfr[TN];
        #pragma unroll
        for (int i = 0; i < TM; ++i)
            af[i] = *(const s8v*)(&As[(wm0 + i * 16 + l15) * PA + l4 * 8]);
        #pragma unroll
        for (int j = 0; j < TN; ++j)
            bfr[j] = *(const s8v*)(&Bs[(wn0 + j * 16 + l15) * PA + l4 * 8]);
        #pragma unroll
        for (int i = 0; i < TM; ++i)
            #pragma unroll
            for (int j = 0; j < TN; ++j)
                acc[i][j] = __builtin_amdgcn_mfma_f32_16x16x32_bf16(
                    af[i], bfr[j], acc[i][j], 0, 0, 0);
    }

    #pragma unroll
    for (int i = 0; i < TM; ++i) {
        #pragma unroll
        for (int ii = 0; ii < 4; ++ii) {
            int row = row0 + wm0 + i * 16 + l4 * 4 + ii;
            if (row < M) {
                #pragma unroll
                for (int j = 0; j < TN; ++j) {
                    int col = wn0 + j * 16 + l15;
                    float a = acc[i][j][ii];
                    if (EPI == 0) {
                        ((ushort*)Cout)[(size_t)row * NW + col] = f2bf(a + bias[col]);
                    } else if (EPI == 1) {
                        ((float*)Cout)[(size_t)row * NW + col] = a + bias[col];
                    } else {
                        float val = a + cvec[row] * bias[col];
                        float o = partial[(size_t)row * NW + col] + 0.5f * fmaxf(val, 0.f);
                        ((ushort*)Cout)[(size_t)row * NW + col] = f2bf(o);
                    }
                }
            }
        }
    }
}

// ---------------------------------------------------------------------------
// CSR construction, all 4 edge lists batched per kernel.
// Block ranges: [0,NBE0) cor0 | [NBE0,2*NBE0) sim0 | then cor1 | sim1.
// ---------------------------------------------------------------------------
__global__ void histo4(CPtr4 ed, MPtr4 cnt)
{
    int b = blockIdx.x, t = threadIdx.x;
    const int* edp; int* cp; int e, E;
    if (b < NBE0)          { edp = ed.p0; cp = cnt.p0; e = b * 256 + t;              E = E0_N; }
    else if (b < 2 * NBE0) { edp = ed.p1; cp = cnt.p1; e = (b - NBE0) * 256 + t;     E = E0_N; }
    else if (b < 2 * NBE0 + NBE1)
                           { edp = ed.p2; cp = cnt.p2; e = (b - 2 * NBE0) * 256 + t; E = E1_N; }
    else                   { edp = ed.p3; cp = cnt.p3; e = (b - 2 * NBE0 - NBE1) * 256 + t; E = E1_N; }
    if (e < E) atomicAdd(&cp[edp[e]], 1);
}

__global__ __launch_bounds__(1024) void exscan4(MPtr4 cnt, MPtr4 row, MPtr4 head)
{
    __shared__ int part[1024];
    const int b = blockIdx.x, t = threadIdx.x;
    int* cp; int* rp; int* hp; int n;
    if (b == 0)      { cp = cnt.p0; rp = row.p0; hp = head.p0; n = ND0; }
    else if (b == 1) { cp = cnt.p1; rp = row.p1; hp = head.p1; n = ND0; }
    else if (b == 2) { cp = cnt.p2; rp = row.p2; hp = head.p2; n = ND1; }
    else             { cp = cnt.p3; rp = row.p3; hp = head.p3; n = ND1; }

    const int chunk = (n + 1023) >> 10;
    const int start = t * chunk;
    int s = 0;
    for (int i = 0; i < chunk; ++i) {
        int idx = start + i;
        if (idx < n) s += cp[idx];
    }
    part[t] = s;
    __syncthreads();
    for (int off = 1; off < 1024; off <<= 1) {
        int v = (t >= off) ? part[t - off] : 0;
        __syncthreads();
        part[t] += v;
        __syncthreads();
    }
    int run = (t == 0) ? 0 : part[t - 1];
    for (int i = 0; i < chunk; ++i) {
        int idx = start + i;
        if (idx < n) { rp[idx] = run; hp[idx] = run; run += cp[idx]; }
    }
    if (t == 1023) rp[n] = part[1023];
}

__global__ void build4(CPtr4 es, CPtr4 ed, MPtr4 head, MPtr4 src)
{
    int b = blockIdx.x, t = threadIdx.x;
    const int *esp, *edp; int *hp, *sp; int e, E;
    if (b < NBE0)          { esp = es.p0; edp = ed.p0; hp = head.p0; sp = src.p0; e = b * 256 + t;              E = E0_N; }
    else if (b < 2 * NBE0) { esp = es.p1; edp = ed.p1; hp = head.p1; sp = src.p1; e = (b - NBE0) * 256 + t;     E = E0_N; }
    else if (b < 2 * NBE0 + NBE1)
                           { esp = es.p2; edp = ed.p2; hp = head.p2; sp = src.p2; e = (b - 2 * NBE0) * 256 + t; E = E1_N; }
    else                   { esp = es.p3; edp = ed.p3; hp = head.p3; sp = src.p3; e = (b - 2 * NBE0 - NBE1) * 256 + t; E = E1_N; }
    if (e >= E) return;
    int p = atomicAdd(&hp[edp[e]], 1);
    sp[p] = esp[e];
}

// ---------------------------------------------------------------------------
// Per-node projections on bf16 z. 8 lanes per node; weight slices in regs.
// Channels: 0:ps0 1:ps1 2:qs 3:pd0 4:pd1 5:qd   (alpha eliminated: a0+a1==1)
// ---------------------------------------------------------------------------
#define NP_NPB 128
__global__ __launch_bounds__(256) void node_proj(
    const ushort* __restrict__ z,
    const float* __restrict__ We,    // 2D x 2
    const float* __restrict__ Wi,    // 2D x 1
    float* __restrict__ ps, float* __restrict__ qs,
    float* __restrict__ pd, float* __restrict__ qd,
    int n_src, int n_dst)
{
    __shared__ float w[6][D_DIM];
    for (int k = threadIdx.x; k < D_DIM; k += 256) {
        w[0][k] = We[k * 2 + 0];
        w[1][k] = We[k * 2 + 1];
        w[2][k] = Wi[k];
        w[3][k] = We[(D_DIM + k) * 2 + 0];
        w[4][k] = We[(D_DIM + k) * 2 + 1];
        w[5][k] = Wi[D_DIM + k];
    }
    __syncthreads();

    const int sub = threadIdx.x & 7;
    const int g   = threadIdx.x >> 3;

    float wr[6][16];
    #pragma unroll
    for (int c = 0; c < 6; ++c)
        #pragma unroll
        for (int q = 0; q < 4; ++q) {
            float4 f = *(const float4*)(&w[c][sub * 16 + q * 4]);
            wr[c][q * 4 + 0] = f.x; wr[c][q * 4 + 1] = f.y;
            wr[c][q * 4 + 2] = f.z; wr[c][q * 4 + 3] = f.w;
        }

    #pragma unroll
    for (int it = 0; it < 4; ++it) {
        int node = blockIdx.x * NP_NPB + it * 32 + g;
        if (node >= n_src) continue;
        const ushort* zp = z + (size_t)node * D_DIM + sub * 16;
        uint4 ra = *(const uint4*)zp;
        uint4 rb = *(const uint4*)(zp + 8);
        uint rr[8] = {ra.x, ra.y, ra.z, ra.w, rb.x, rb.y, rb.z, rb.w};
        float p[6] = {0.f, 0.f, 0.f, 0.f, 0.f, 0.f};
        #pragma unroll
        for (int e = 0; e < 8; ++e) {
            float2 f2 = unpack2(rr[e]);
            #pragma unroll
            for (int c = 0; c < 6; ++c)
                p[c] += f2.x * wr[c][2 * e] + f2.y * wr[c][2 * e + 1];
        }
        #pragma unroll
        for (int off = 4; off > 0; off >>= 1)
            #pragma unroll
            for (int c = 0; c < 6; ++c)
                p[c] += __shfl_down(p[c], off);

        if (sub == 0) {
            *(float2*)(ps + (size_t)node * 2) = make_float2(p[0], p[1]);
            qs[node] = p[2];
            if (node < n_dst) {
                *(float2*)(pd + (size_t)node * 2) = make_float2(p[3], p[4]);
                qd[node] = p[5];
            }
        }
    }
}

// ---------------------------------------------------------------------------
// Fused attention + gather-accumulate: one wave per dst node. Attention
// values (softmax / sigmoid) computed inline from ps/qs (src, per edge) and
// pd/qd (dst, wave-uniform). Unroll-8 -> 8 outstanding row loads.
//   h0 = (Σ e0 z_s)/deg  -> bf16,   c = (Σ e0)/deg,
//   partial = 0.5*(relu(eh*ih) + z_d)  (f32)
// ---------------------------------------------------------------------------
__global__ __launch_bounds__(256) void gather_att(
    const ushort* __restrict__ z,
    const float* __restrict__ ps, const float* __restrict__ pdv,
    const float* __restrict__ qs, const float* __restrict__ qdv,
    const int* __restrict__ erow, const int* __restrict__ esrc,
    const int* __restrict__ irow, const int* __restrict__ isrc,
    ushort* __restrict__ h0b, float* __restrict__ cvec,
    float* __restrict__ partial, int n_dst)
{
    const int d = blockIdx.x * 4 + (threadIdx.x >> 6);
    const int lane = threadIdx.x & 63;
    if (d >= n_dst) return;

    const float pd0 = pdv[2 * d], pd1 = pdv[2 * d + 1];
    const float qdd = qdv[d];

    float h0x = 0.f, h0y = 0.f, ehx = 0.f, ehy = 0.f;
    float ihx = 0.f, ihy = 0.f, se0 = 0.f;

    const int b0 = erow[d], b1 = erow[d + 1];
    int j = b0;
    for (; j + 8 <= b1; j += 8) {
        int sdx[8]; float2 pp[8]; uint rr[8];
        #pragma unroll
        for (int k = 0; k < 8; ++k) sdx[k] = esrc[j + k];
        #pragma unroll
        for (int k = 0; k < 8; ++k) pp[k] = *(const float2*)(ps + 2 * (size_t)sdx[k]);
        #pragma unroll
        for (int k = 0; k < 8; ++k) rr[k] = *(const uint*)(z + (size_t)sdx[k] * D_DIM + lane * 2);
        #pragma unroll
        for (int k = 0; k < 8; ++k) {
            float l0 = pp[k].x + pd0, l1 = pp[k].y + pd1;
            float mx = fmaxf(l0, l1);
            float x0 = __expf(l0 - mx), x1 = __expf(l1 - mx);
            float inv = 1.0f / (x0 + x1);
            float e0 = x0 * inv, e1 = x1 * inv;
            float2 v = unpack2(rr[k]);
            h0x += e0 * v.x; h0y += e0 * v.y;
            ehx += e1 * v.x; ehy += e1 * v.y;
            se0 += e0;
        }
    }
    for (; j < b1; ++j) {
        int s = esrc[j];
        float2 pp = *(const float2*)(ps + 2 * (size_t)s);
        float2 v = unpack2(*(const uint*)(z + (size_t)s * D_DIM + lane * 2));
        float l0 = pp.x + pd0, l1 = pp.y + pd1;
        float mx = fmaxf(l0, l1);
        float x0 = __expf(l0 - mx), x1 = __expf(l1 - mx);
        float inv = 1.0f / (x0 + x1);
        float e0 = x0 * inv, e1 = x1 * inv;
        h0x += e0 * v.x; h0y += e0 * v.y;
        ehx += e1 * v.x; ehy += e1 * v.y;
        se0 += e0;
    }

    const int c0 = irow[d], c1 = irow[d + 1];
    j = c0;
    for (; j + 8 <= c1; j += 8) {
        int sdx[8]; float qq[8]; uint rr[8];
        #pragma unroll
        for (int k = 0; k < 8; ++k) sdx[k] = isrc[j + k];
        #pragma unroll
        for (int k = 0; k < 8; ++k) qq[k] = qs[sdx[k]];
        #pragma unroll
        for (int k = 0; k < 8; ++k) rr[k] = *(const uint*)(z + (size_t)sdx[k] * D_DIM + lane * 2);
        #pragma unroll
        for (int k = 0; k < 8; ++k) {
            float g = 1.0f / (1.0f + __expf(-(qq[k] + qdd)));
            float2 v = unpack2(rr[k]);
            ihx += g * v.x; ihy += g * v.y;
        }
    }
    for (; j < c1; ++j) {
        int s = isrc[j];
        float g = 1.0f / (1.0f + __expf(-(qs[s] + qdd)));
        float2 v = unpack2(*(const uint*)(z + (size_t)s * D_DIM + lane * 2));
        ihx += g * v.x; ihy += g * v.y;
    }

    float inv = 1.0f / fmaxf((float)(b1 - b0), 1.0f);
    uint hp = (uint)f2bf(h0x * inv) | ((uint)f2bf(h0y * inv) << 16);
    *(uint*)(h0b + (size_t)d * D_DIM + lane * 2) = hp;
    if (lane == 0) cvec[d] = se0 * inv;

    float2 zd = unpack2(*(const uint*)(z + (size_t)d * D_DIM + lane * 2));
    float px = 0.5f * (fmaxf(ehx * ihx, 0.f) + zd.x);
    float py = 0.5f * (fmaxf(ehy * ihy, 0.f) + zd.y);
    *(float2*)(partial + (size_t)d * D_DIM + lane * 2) = make_float2(px, py);
}

// ---------------------------------------------------------------------------
extern "C" void kernel_launch(void* const* d_in, const int* in_sizes, int n_in,
                              void* d_out, int out_size, void* d_ws, size_t ws_size,
                              hipStream_t stream)
{
    const float* feat = (const float*)d_in[0];
    const int* src0_cor = (const int*)d_in[1];
    const int* dst0_cor = (const int*)d_in[2];
    const int* src0_sim = (const int*)d_in[3];
    const int* dst0_sim = (const int*)d_in[4];
    const int* src1_cor = (const int*)d_in[5];
    const int* dst1_cor = (const int*)d_in[6];
    const int* src1_sim = (const int*)d_in[7];
    const int* dst1_sim = (const int*)d_in[8];
    const float* Win  = (const float*)d_in[11];
    const float* b_in = (const float*)d_in[12];
    const float* ea1  = (const float*)d_in[14];
    const float* ia1  = (const float*)d_in[15];
    const float* W1   = (const float*)d_in[16];
    const float* b1   = (const float*)d_in[17];
    const float* ea2  = (const float*)d_in[19];
    const float* ia2  = (const float*)d_in[20];
    const float* W2   = (const float*)d_in[21];
    const float* b2   = (const float*)d_in[22];
    const float* Wout = (const float*)d_in[23];
    const float* bout = (const float*)d_in[24];
    (void)in_sizes; (void)n_in; (void)out_size; (void)ws_size;

    // ---- workspace layout ----
    char* wsb = (char*)d_ws;
    size_t off = 0;
    auto alloc_f = [&](size_t n) { float*  p = (float*) (wsb + off); off += n * 4; return p; };
    auto alloc_i = [&](size_t n) { int*    p = (int*)   (wsb + off); off += n * 4; return p; };
    auto alloc_h = [&](size_t n) { ushort* p = (ushort*)(wsb + off); off += ((n * 2 + 15) & ~15ull); return p; };

    ushort* featb = alloc_h((size_t)NS0 * F_DIM);
    ushort* z0b   = alloc_h((size_t)NS0 * D_DIM);
    ushort* z1b   = alloc_h((size_t)NS1 * D_DIM);
    ushort* z2b   = alloc_h((size_t)ND1 * D_DIM);
    ushort* h0b   = alloc_h((size_t)ND0 * D_DIM);
    ushort* Wtin  = alloc_h((size_t)2 * D_DIM * F_DIM);
    ushort* Wt1   = alloc_h((size_t)2 * D_DIM * D_DIM);
    ushort* Wt2   = alloc_h((size_t)2 * D_DIM * D_DIM);
    ushort* Wtout = alloc_h((size_t)2 * O_DIM * D_DIM);

    float* ps      = alloc_f((size_t)NS0 * 2);
    float* qs      = alloc_f(NS0);
    float* pd      = alloc_f((size_t)ND0 * 2);
    float* qd      = alloc_f(ND0);
    float* cvec    = alloc_f(ND0);
    float* partial = alloc_f((size_t)ND0 * D_DIM);

    int* src_c0 = alloc_i(E0_N); int* row_c0 = alloc_i(ND0 + 1);
    int* src_s0 = alloc_i(E0_N); int* row_s0 = alloc_i(ND0 + 1);
    int* src_c1 = alloc_i(E1_N); int* row_c1 = alloc_i(ND1 + 1);
    int* src_s1 = alloc_i(E1_N); int* row_s1 = alloc_i(ND1 + 1);
    int* cnt_all  = alloc_i(2 * ND0 + 2 * ND1);
    int* head_all = alloc_i(2 * ND0 + 2 * ND1);

    int* cnt_c0 = cnt_all;            int* head_c0 = head_all;
    int* cnt_s0 = cnt_all + ND0;      int* head_s0 = head_all + ND0;
    int* cnt_c1 = cnt_all + 2 * ND0;  int* head_c1 = head_all + 2 * ND0;
    int* cnt_s1 = cnt_c1 + ND1;       int* head_s1 = head_c1 + ND1;

    // ---- batched CSR build for the 4 edge lists ----
    const int NB_ALL = 2 * NBE0 + 2 * NBE1;
    hipMemsetAsync(cnt_all, 0, (size_t)(2 * ND0 + 2 * ND1) * 4, stream);
    {
        CPtr4 edp  = {dst0_cor, dst0_sim, dst1_cor, dst1_sim};
        CPtr4 esp  = {src0_cor, src0_sim, src1_cor, src1_sim};
        MPtr4 cntp = {cnt_c0, cnt_s0, cnt_c1, cnt_s1};
        MPtr4 rowp = {row_c0, row_s0, row_c1, row_s1};
        MPtr4 hdp  = {head_c0, head_s0, head_c1, head_s1};
        MPtr4 srcp = {src_c0, src_s0, src_c1, src_s1};
        histo4<<<NB_ALL, 256, 0, stream>>>(edp, cntp);
        exscan4<<<4, 1024, 0, stream>>>(cntp, rowp, hdp);
        build4<<<NB_ALL, 256, 0, stream>>>(esp, edp, hdp, srcp);
    }

    // ---- dtype prep ----
    cvt_bf16<<<((size_t)NS0 * F_DIM / 4 + 255) / 256, 256, 0, stream>>>(
        feat, featb, NS0 * F_DIM);
    prep_weights<<<576, 256, 0, stream>>>(Win, W1, W2, Wout, Wtin, Wt1, Wt2, Wtout);

    for (int m = 0; m < 2; ++m) {
        // e-channel / i-channel CSR selection per mode
        const int *er0, *es0, *ir0, *is0, *er1, *es1, *ir1, *is1;
        if (m == 0) {
            er0 = row_c0; es0 = src_c0; ir0 = row_s0; is0 = src_s0;
            er1 = row_c1; es1 = src_c1; ir1 = row_s1; is1 = src_s1;
        } else {
            er0 = row_s0; es0 = src_s0; ir0 = row_c0; is0 = src_c0;
            er1 = row_s1; es1 = src_s1; ir1 = row_c1; is1 = src_c1;
        }

        // --- Layer 0: z0 = feat @ Win[m] + b_in[m]
        mfma_gemm<128, 256, 0><<<(NS0 + 127) / 128, 256, 0, stream>>>(
            featb, Wtin + (size_t)m * D_DIM * F_DIM, b_in + m * D_DIM,
            nullptr, nullptr, z0b, NS0);

        // --- Layer 1
        node_proj<<<(NS0 + NP_NPB - 1) / NP_NPB, 256, 0, stream>>>(
            z0b, ea1 + m * 2 * D_DIM * 2, ia1 + m * 2 * D_DIM,
            ps, qs, pd, qd, NS0, ND0);
        gather_att<<<(ND0 + 3) / 4, 256, 0, stream>>>(
            z0b, ps, pd, qs, qd, er0, es0, ir0, is0, h0b, cvec, partial, ND0);
        mfma_gemm<128, 128, 2><<<(ND0 + 127) / 128, 256, 0, stream>>>(
            h0b, Wt1 + (size_t)m * D_DIM * D_DIM, b1 + m * D_DIM,
            cvec, partial, z1b, ND0);

        // --- Layer 2
        node_proj<<<(NS1 + NP_NPB - 1) / NP_NPB, 256, 0, stream>>>(
            z1b, ea2 + m * 2 * D_DIM * 2, ia2 + m * 2 * D_DIM,
            ps, qs, pd, qd, NS1, ND1);
        gather_att<<<(ND1 + 3) / 4, 256, 0, stream>>>(
            z1b, ps, pd, qs, qd, er1, es1, ir1, is1, h0b, cvec, partial, ND1);
        mfma_gemm<128, 128, 2><<<(ND1 + 127) / 128, 256, 0, stream>>>(
            h0b, Wt2 + (size_t)m * D_DIM * D_DIM, b2 + m * D_DIM,
            cvec, partial, z2b, ND1);

        // --- Output: out[m] = z2 @ Wout[m] + bout[m]  (fp32 out)
        mfma_gemm<64, 128, 1><<<(ND1 + 127) / 128, 256, 0, stream>>>(
            z2b, Wtout + (size_t)m * O_DIM * D_DIM, bout + m * O_DIM,
            nullptr, nullptr, (float*)d_out + (size_t)m * ND1 * O_DIM, ND1);
    }
}

// Round 7
// 595.749 us; speedup vs baseline: 6.8813x; 1.1816x over previous
//
#include <hip/hip_runtime.h>
#include <hip/hip_bf16.h>
#include <math.h>

// Problem constants (fixed by setup_inputs())
#define F_DIM 256
#define D_DIM 128
#define O_DIM 64
#define NS0   100000
#define ND0   25000
#define E0_N  500000
#define NS1   25000
#define ND1   5000
#define E1_N  100000

#define NBE0  1954   // ceil(E0_N/256)
#define NBE1  391    // ceil(E1_N/256)

typedef __attribute__((ext_vector_type(8))) short s8v;   // 8 bf16 (4 VGPRs)
typedef __attribute__((ext_vector_type(4))) float f4v;   // 4 fp32 acc

struct CPtr4 { const int *p0, *p1, *p2, *p3; };
struct MPtr4 { int *p0, *p1, *p2, *p3; };

__device__ __forceinline__ float2 unpack2(uint u) {
    union { uint i; float f; } a, b;
    a.i = (u & 0xffffu) << 16; b.i = u & 0xffff0000u;
    return make_float2(a.f, b.f);
}
__device__ __forceinline__ ushort f2bf(float f) {
    __hip_bfloat16 h = __float2bfloat16(f);
    return *(ushort*)&h;
}

// ---------------------------------------------------------------------------
// fp32 -> bf16 bulk convert (n % 4 == 0)
// ---------------------------------------------------------------------------
__global__ void cvt_bf16(const float* __restrict__ in, ushort* __restrict__ out, int n)
{
    int i = (blockIdx.x * 256 + threadIdx.x) * 4;
    if (i >= n) return;
    float4 v = *(const float4*)(in + i);
    ushort4 o;
    o.x = f2bf(v.x); o.y = f2bf(v.y); o.z = f2bf(v.z); o.w = f2bf(v.w);
    *(ushort4*)(out + i) = o;
}

// ---------------------------------------------------------------------------
// All weight transposes in ONE launch: [K][N] fp32 -> [N][K] bf16, 8 matrices.
// ---------------------------------------------------------------------------
__global__ void prep_weights(
    const float* __restrict__ Win, const float* __restrict__ W1,
    const float* __restrict__ W2,  const float* __restrict__ Wout,
    ushort* __restrict__ Wtin, ushort* __restrict__ Wt1,
    ushort* __restrict__ Wt2,  ushort* __restrict__ Wtout)
{
    int i = blockIdx.x * 256 + threadIdx.x;
    if (i < 65536) {                                  // Win
        int m = i >> 15, r = i & 32767, k = r >> 7, n = r & 127;
        Wtin[m * 32768 + n * 256 + k] = f2bf(Win[m * 32768 + k * 128 + n]);
    } else if (i < 98304) {                           // W1
        int i2 = i - 65536;
        int m = i2 >> 14, r = i2 & 16383, k = r >> 7, n = r & 127;
        Wt1[m * 16384 + n * 128 + k] = f2bf(W1[m * 16384 + k * 128 + n]);
    } else if (i < 131072) {                          // W2
        int i2 = i - 98304;
        int m = i2 >> 14, r = i2 & 16383, k = r >> 7, n = r & 127;
        Wt2[m * 16384 + n * 128 + k] = f2bf(W2[m * 16384 + k * 128 + n]);
    } else if (i < 147456) {                          // Wout
        int i2 = i - 131072;
        int m = i2 >> 13, r = i2 & 8191, k = r >> 6, n = r & 63;
        Wtout[m * 8192 + n * 128 + k] = f2bf(Wout[m * 8192 + k * 64 + n]);
    }
}

// ---------------------------------------------------------------------------
// MFMA bf16 GEMM, mode-fused (blockIdx.y = m): per-mode strides in elements.
// EPI 0: +bias -> bf16   EPI 1: +bias -> f32
// EPI 2 (agg-fused): out = partial + 0.5*relu(acc + c[row]*bias[col]) -> bf16
// ---------------------------------------------------------------------------
template<int NW, int KD, int EPI>
__global__ __launch_bounds__(256) void mfma_gemm(
    const ushort* __restrict__ Ab, size_t astr,
    const ushort* __restrict__ Btb, size_t btstr,
    const float* __restrict__ biasb, size_t bstr,
    const float* __restrict__ cvecb, size_t cvstr,
    const float* __restrict__ partialb, size_t pstr,
    void* __restrict__ Coutb, size_t coutstr, int M)
{
    const int m = blockIdx.y;
    const ushort* A  = Ab + m * astr;
    const ushort* Bt = Btb + m * btstr;
    const float* bias = biasb + m * bstr;
    const float* cvec = (EPI == 2) ? cvecb + m * cvstr : nullptr;
    const float* partial = (EPI == 2) ? partialb + m * pstr : nullptr;
    char* Cout = (char*)Coutb + m * coutstr * (EPI == 1 ? 4 : 2);

    constexpr int PA = 40;           // 32 + 8 bf16 pad
    constexpr int WAVES_M = (NW == 128) ? 2 : 4;
    constexpr int WM = 128 / WAVES_M;
    constexpr int TM = WM / 16;
    constexpr int TN = 4;
    __shared__ ushort As[128 * PA];
    __shared__ ushort Bs[NW * PA];

    const int tid  = threadIdx.x;
    const int row0 = blockIdx.x * 128;
    const int wave = tid >> 6, lane = tid & 63;
    const int l15 = lane & 15, l4 = lane >> 4;
    int wm0, wn0;
    if (NW == 128) { wm0 = (wave >> 1) * 64; wn0 = (wave & 1) * 64; }
    else           { wm0 = wave * WM;        wn0 = 0; }

    f4v acc[TM][TN];
    #pragma unroll
    for (int i = 0; i < TM; ++i)
        #pragma unroll
        for (int j = 0; j < TN; ++j)
            acc[i][j] = (f4v)(0.0f);

    for (int kc = 0; kc < KD; kc += 32) {
        __syncthreads();
        #pragma unroll
        for (int it = 0; it < 2; ++it) {
            int f = tid + it * 256;
            int r = f >> 2, g = (f & 3) * 8;
            int gr = row0 + r;
            float4 v = make_float4(0.f, 0.f, 0.f, 0.f);
            if (gr < M) v = *(const float4*)(A + (size_t)gr * KD + kc + g);
            *(float4*)(&As[r * PA + g]) = v;
        }
        #pragma unroll
        for (int it = 0; it < NW * 32 / (256 * 8); ++it) {
            int f = tid + it * 256;
            int r = f >> 2, g = (f & 3) * 8;
            *(float4*)(&Bs[r * PA + g]) = *(const float4*)(Bt + (size_t)r * KD + kc + g);
        }
        __syncthreads();

        s8v af[TM], bfr[TN];
        #pragma unroll
        for (int i = 0; i < TM; ++i)
            af[i] = *(const s8v*)(&As[(wm0 + i * 16 + l15) * PA + l4 * 8]);
        #pragma unroll
        for (int j = 0; j < TN; ++j)
            bfr[j] = *(const s8v*)(&Bs[(wn0 + j * 16 + l15) * PA + l4 * 8]);
        #pragma unroll
        for (int i = 0; i < TM; ++i)
            #pragma unroll
            for (int j = 0; j < TN; ++j)
                acc[i][j] = __builtin_amdgcn_mfma_f32_16x16x32_bf16(
                    af[i], bfr[j], acc[i][j], 0, 0, 0);
    }

    #pragma unroll
    for (int i = 0; i < TM; ++i) {
        #pragma unroll
        for (int ii = 0; ii < 4; ++ii) {
            int row = row0 + wm0 + i * 16 + l4 * 4 + ii;
            if (row < M) {
                #pragma unroll
                for (int j = 0; j < TN; ++j) {
                    int col = wn0 + j * 16 + l15;
                    float a = acc[i][j][ii];
                    if (EPI == 0) {
                        ((ushort*)Cout)[(size_t)row * NW + col] = f2bf(a + bias[col]);
                    } else if (EPI == 1) {
                        ((float*)Cout)[(size_t)row * NW + col] = a + bias[col];
                    } else {
                        float val = a + cvec[row] * bias[col];
                        float o = partial[(size_t)row * NW + col] + 0.5f * fmaxf(val, 0.f);
                        ((ushort*)Cout)[(size_t)row * NW + col] = f2bf(o);
                    }
                }
            }
        }
    }
}

// ---------------------------------------------------------------------------
// CSR construction, all 4 edge lists batched per kernel.
// ---------------------------------------------------------------------------
__global__ void histo4(CPtr4 ed, MPtr4 cnt)
{
    int b = blockIdx.x, t = threadIdx.x;
    const int* edp; int* cp; int e, E;
    if (b < NBE0)          { edp = ed.p0; cp = cnt.p0; e = b * 256 + t;              E = E0_N; }
    else if (b < 2 * NBE0) { edp = ed.p1; cp = cnt.p1; e = (b - NBE0) * 256 + t;     E = E0_N; }
    else if (b < 2 * NBE0 + NBE1)
                           { edp = ed.p2; cp = cnt.p2; e = (b - 2 * NBE0) * 256 + t; E = E1_N; }
    else                   { edp = ed.p3; cp = cnt.p3; e = (b - 2 * NBE0 - NBE1) * 256 + t; E = E1_N; }
    if (e < E) atomicAdd(&cp[edp[e]], 1);
}

__global__ __launch_bounds__(1024) void exscan4(MPtr4 cnt, MPtr4 row, MPtr4 head)
{
    __shared__ int part[1024];
    const int b = blockIdx.x, t = threadIdx.x;
    int* cp; int* rp; int* hp; int n;
    if (b == 0)      { cp = cnt.p0; rp = row.p0; hp = head.p0; n = ND0; }
    else if (b == 1) { cp = cnt.p1; rp = row.p1; hp = head.p1; n = ND0; }
    else if (b == 2) { cp = cnt.p2; rp = row.p2; hp = head.p2; n = ND1; }
    else             { cp = cnt.p3; rp = row.p3; hp = head.p3; n = ND1; }

    const int chunk = (n + 1023) >> 10;
    const int start = t * chunk;
    int s = 0;
    for (int i = 0; i < chunk; ++i) {
        int idx = start + i;
        if (idx < n) s += cp[idx];
    }
    part[t] = s;
    __syncthreads();
    for (int off = 1; off < 1024; off <<= 1) {
        int v = (t >= off) ? part[t - off] : 0;
        __syncthreads();
        part[t] += v;
        __syncthreads();
    }
    int run = (t == 0) ? 0 : part[t - 1];
    for (int i = 0; i < chunk; ++i) {
        int idx = start + i;
        if (idx < n) { rp[idx] = run; hp[idx] = run; run += cp[idx]; }
    }
    if (t == 1023) rp[n] = part[1023];
}

__global__ void build4(CPtr4 es, CPtr4 ed, MPtr4 head, MPtr4 src)
{
    int b = blockIdx.x, t = threadIdx.x;
    const int *esp, *edp; int *hp, *sp; int e, E;
    if (b < NBE0)          { esp = es.p0; edp = ed.p0; hp = head.p0; sp = src.p0; e = b * 256 + t;              E = E0_N; }
    else if (b < 2 * NBE0) { esp = es.p1; edp = ed.p1; hp = head.p1; sp = src.p1; e = (b - NBE0) * 256 + t;     E = E0_N; }
    else if (b < 2 * NBE0 + NBE1)
                           { esp = es.p2; edp = ed.p2; hp = head.p2; sp = src.p2; e = (b - 2 * NBE0) * 256 + t; E = E1_N; }
    else                   { esp = es.p3; edp = ed.p3; hp = head.p3; sp = src.p3; e = (b - 2 * NBE0 - NBE1) * 256 + t; E = E1_N; }
    if (e >= E) return;
    int p = atomicAdd(&hp[edp[e]], 1);
    sp[p] = esp[e];
}

// ---------------------------------------------------------------------------
// Per-node projections, mode-fused (blockIdx.y = m). 8 lanes/node, weight
// slices in registers. Channels: ps0 ps1 qs pd0 pd1 qd. (alpha: a0+a1==1)
// ps/qs/pd/qd strides fixed at layer-1 sizes for both layers.
// ---------------------------------------------------------------------------
#define NP_NPB 128
__global__ __launch_bounds__(256) void node_proj(
    const ushort* __restrict__ zb, size_t zstr,
    const float* __restrict__ Web,   // + m*512
    const float* __restrict__ Wib,   // + m*256
    float* __restrict__ psb, float* __restrict__ qsb,
    float* __restrict__ pdb, float* __restrict__ qdb,
    int n_src, int n_dst)
{
    const int m = blockIdx.y;
    const ushort* z = zb + m * zstr;
    const float* We = Web + m * 512;
    const float* Wi = Wib + m * 256;
    float* ps = psb + (size_t)m * NS0 * 2;
    float* qs = qsb + (size_t)m * NS0;
    float* pd = pdb + (size_t)m * ND0 * 2;
    float* qd = qdb + (size_t)m * ND0;

    __shared__ float w[6][D_DIM];
    for (int k = threadIdx.x; k < D_DIM; k += 256) {
        w[0][k] = We[k * 2 + 0];
        w[1][k] = We[k * 2 + 1];
        w[2][k] = Wi[k];
        w[3][k] = We[(D_DIM + k) * 2 + 0];
        w[4][k] = We[(D_DIM + k) * 2 + 1];
        w[5][k] = Wi[D_DIM + k];
    }
    __syncthreads();

    const int sub = threadIdx.x & 7;
    const int g   = threadIdx.x >> 3;

    float wr[6][16];
    #pragma unroll
    for (int c = 0; c < 6; ++c)
        #pragma unroll
        for (int q = 0; q < 4; ++q) {
            float4 f = *(const float4*)(&w[c][sub * 16 + q * 4]);
            wr[c][q * 4 + 0] = f.x; wr[c][q * 4 + 1] = f.y;
            wr[c][q * 4 + 2] = f.z; wr[c][q * 4 + 3] = f.w;
        }

    #pragma unroll
    for (int it = 0; it < 4; ++it) {
        int node = blockIdx.x * NP_NPB + it * 32 + g;
        if (node >= n_src) continue;
        const ushort* zp = z + (size_t)node * D_DIM + sub * 16;
        uint4 ra = *(const uint4*)zp;
        uint4 rb = *(const uint4*)(zp + 8);
        uint rr[8] = {ra.x, ra.y, ra.z, ra.w, rb.x, rb.y, rb.z, rb.w};
        float p[6] = {0.f, 0.f, 0.f, 0.f, 0.f, 0.f};
        #pragma unroll
        for (int e = 0; e < 8; ++e) {
            float2 f2 = unpack2(rr[e]);
            #pragma unroll
            for (int c = 0; c < 6; ++c)
                p[c] += f2.x * wr[c][2 * e] + f2.y * wr[c][2 * e + 1];
        }
        #pragma unroll
        for (int off = 4; off > 0; off >>= 1)
            #pragma unroll
            for (int c = 0; c < 6; ++c)
                p[c] += __shfl_down(p[c], off);

        if (sub == 0) {
            *(float2*)(ps + (size_t)node * 2) = make_float2(p[0], p[1]);
            qs[node] = p[2];
            if (node < n_dst) {
                *(float2*)(pd + (size_t)node * 2) = make_float2(p[3], p[4]);
                qd[node] = p[5];
            }
        }
    }
}

// ---------------------------------------------------------------------------
// Edge attention, mode-fused: one wave per dst, one LANE per CSR slot.
// pd/qd wave-uniform; ee/ei written coalesced in CSR order. m swaps cor/sim.
// ---------------------------------------------------------------------------
__global__ __launch_bounds__(256) void edge_att(
    const float* __restrict__ psb, const float* __restrict__ pdb,
    const float* __restrict__ qsb, const float* __restrict__ qdb,
    const int* __restrict__ row_c, const int* __restrict__ src_c,
    const int* __restrict__ row_s, const int* __restrict__ src_s,
    float* __restrict__ eeb, float* __restrict__ eib, int n_dst)
{
    const int m = blockIdx.y;
    const int d = blockIdx.x * 4 + (threadIdx.x >> 6);
    const int lane = threadIdx.x & 63;
    if (d >= n_dst) return;

    const float* ps = psb + (size_t)m * NS0 * 2;
    const float* qs = qsb + (size_t)m * NS0;
    const float* pdv = pdb + (size_t)m * ND0 * 2;
    const float* qdv = qdb + (size_t)m * ND0;
    const int* erow = m ? row_s : row_c;
    const int* esrc = m ? src_s : src_c;
    const int* irow = m ? row_c : row_s;
    const int* isrc = m ? src_c : src_s;
    float* ee = eeb + (size_t)m * E0_N * 2;
    float* ei = eib + (size_t)m * E0_N;

    const float pd0 = pdv[2 * d], pd1 = pdv[2 * d + 1];
    const float qdd = qdv[d];

    const int b0 = erow[d], b1 = erow[d + 1];
    for (int j = b0 + lane; j < b1; j += 64) {
        int s = esrc[j];
        float2 pp = *(const float2*)(ps + 2 * (size_t)s);
        float l0 = pp.x + pd0, l1 = pp.y + pd1;
        float mx = fmaxf(l0, l1);
        float x0 = __expf(l0 - mx), x1 = __expf(l1 - mx);
        float inv = 1.0f / (x0 + x1);
        *(float2*)(ee + 2 * (size_t)j) = make_float2(x0 * inv, x1 * inv);
    }
    const int c0 = irow[d], c1 = irow[d + 1];
    for (int j = c0 + lane; j < c1; j += 64) {
        float q = qs[isrc[j]] + qdd;
        ei[j] = 1.0f / (1.0f + __expf(-q));
    }
}

// ---------------------------------------------------------------------------
// Gather-accumulate, mode-fused: one wave per dst node, unroll-8, reads
// precomputed ee/ei (wave-uniform broadcast loads).
//   h0 = (Σ e0 z_s)/deg  -> bf16,   c = (Σ e0)/deg,
//   partial = 0.5*(relu(eh*ih) + z_d)  (f32)
// ---------------------------------------------------------------------------
__global__ __launch_bounds__(256) void gather_acc(
    const ushort* __restrict__ zb, size_t zstr,
    const float* __restrict__ eeb, const float* __restrict__ eib,
    const int* __restrict__ row_c, const int* __restrict__ src_c,
    const int* __restrict__ row_s, const int* __restrict__ src_s,
    ushort* __restrict__ h0base, float* __restrict__ cvecb,
    float* __restrict__ partialb, int n_dst)
{
    const int m = blockIdx.y;
    const int d = blockIdx.x * 4 + (threadIdx.x >> 6);
    const int lane = threadIdx.x & 63;
    if (d >= n_dst) return;

    const ushort* z = zb + m * zstr;
    const float* ee = eeb + (size_t)m * E0_N * 2;
    const float* ei = eib + (size_t)m * E0_N;
    const int* erow = m ? row_s : row_c;
    const int* esrc = m ? src_s : src_c;
    const int* irow = m ? row_c : row_s;
    const int* isrc = m ? src_c : src_s;
    ushort* h0b = h0base + (size_t)m * ND0 * D_DIM;
    float* cvec = cvecb + (size_t)m * ND0;
    float* partial = partialb + (size_t)m * ND0 * D_DIM;

    float h0x = 0.f, h0y = 0.f, ehx = 0.f, ehy = 0.f;
    float ihx = 0.f, ihy = 0.f, se0 = 0.f;

    const int b0 = erow[d], b1 = erow[d + 1];
    int j = b0;
    for (; j + 8 <= b1; j += 8) {
        int sdx[8]; float2 ww[8]; uint rr[8];
        #pragma unroll
        for (int k = 0; k < 8; ++k) sdx[k] = esrc[j + k];
        #pragma unroll
        for (int k = 0; k < 8; ++k) ww[k] = *(const float2*)(ee + 2 * (size_t)(j + k));
        #pragma unroll
        for (int k = 0; k < 8; ++k) rr[k] = *(const uint*)(z + (size_t)sdx[k] * D_DIM + lane * 2);
        #pragma unroll
        for (int k = 0; k < 8; ++k) {
            float2 v = unpack2(rr[k]);
            h0x += ww[k].x * v.x; h0y += ww[k].x * v.y;
            ehx += ww[k].y * v.x; ehy += ww[k].y * v.y;
            se0 += ww[k].x;
        }
    }
    for (; j < b1; ++j) {
        int s = esrc[j];
        float2 w = *(const float2*)(ee + 2 * (size_t)j);
        float2 v = unpack2(*(const uint*)(z + (size_t)s * D_DIM + lane * 2));
        h0x += w.x * v.x; h0y += w.x * v.y;
        ehx += w.y * v.x; ehy += w.y * v.y;
        se0 += w.x;
    }

    const int c0 = irow[d], c1 = irow[d + 1];
    j = c0;
    for (; j + 8 <= c1; j += 8) {
        int sdx[8]; float gg[8]; uint rr[8];
        #pragma unroll
        for (int k = 0; k < 8; ++k) sdx[k] = isrc[j + k];
        #pragma unroll
        for (int k = 0; k < 8; ++k) gg[k] = ei[j + k];
        #pragma unroll
        for (int k = 0; k < 8; ++k) rr[k] = *(const uint*)(z + (size_t)sdx[k] * D_DIM + lane * 2);
        #pragma unroll
        for (int k = 0; k < 8; ++k) {
            float2 v = unpack2(rr[k]);
            ihx += gg[k] * v.x; ihy += gg[k] * v.y;
        }
    }
    for (; j < c1; ++j) {
        int s = isrc[j];
        float g = ei[j];
        float2 v = unpack2(*(const uint*)(z + (size_t)s * D_DIM + lane * 2));
        ihx += g * v.x; ihy += g * v.y;
    }

    float inv = 1.0f / fmaxf((float)(b1 - b0), 1.0f);
    uint hp = (uint)f2bf(h0x * inv) | ((uint)f2bf(h0y * inv) << 16);
    *(uint*)(h0b + (size_t)d * D_DIM + lane * 2) = hp;
    if (lane == 0) cvec[d] = se0 * inv;

    float2 zd = unpack2(*(const uint*)(z + (size_t)d * D_DIM + lane * 2));
    float px = 0.5f * (fmaxf(ehx * ihx, 0.f) + zd.x);
    float py = 0.5f * (fmaxf(ehy * ihy, 0.f) + zd.y);
    *(float2*)(partial + (size_t)d * D_DIM + lane * 2) = make_float2(px, py);
}

// ---------------------------------------------------------------------------
extern "C" void kernel_launch(void* const* d_in, const int* in_sizes, int n_in,
                              void* d_out, int out_size, void* d_ws, size_t ws_size,
                              hipStream_t stream)
{
    const float* feat = (const float*)d_in[0];
    const int* src0_cor = (const int*)d_in[1];
    const int* dst0_cor = (const int*)d_in[2];
    const int* src0_sim = (const int*)d_in[3];
    const int* dst0_sim = (const int*)d_in[4];
    const int* src1_cor = (const int*)d_in[5];
    const int* dst1_cor = (const int*)d_in[6];
    const int* src1_sim = (const int*)d_in[7];
    const int* dst1_sim = (const int*)d_in[8];
    const float* Win  = (const float*)d_in[11];
    const float* b_in = (const float*)d_in[12];
    const float* ea1  = (const float*)d_in[14];
    const float* ia1  = (const float*)d_in[15];
    const float* W1   = (const float*)d_in[16];
    const float* b1   = (const float*)d_in[17];
    const float* ea2  = (const float*)d_in[19];
    const float* ia2  = (const float*)d_in[20];
    const float* W2   = (const float*)d_in[21];
    const float* b2   = (const float*)d_in[22];
    const float* Wout = (const float*)d_in[23];
    const float* bout = (const float*)d_in[24];
    (void)in_sizes; (void)n_in; (void)out_size; (void)ws_size;

    // ---- workspace layout (per-mode arrays contiguous, stride = layer-1 size) ----
    char* wsb = (char*)d_ws;
    size_t off = 0;
    auto alloc_f = [&](size_t n) { float*  p = (float*) (wsb + off); off += n * 4; return p; };
    auto alloc_i = [&](size_t n) { int*    p = (int*)   (wsb + off); off += n * 4; return p; };
    auto alloc_h = [&](size_t n) { ushort* p = (ushort*)(wsb + off); off += ((n * 2 + 15) & ~15ull); return p; };

    ushort* featb = alloc_h((size_t)NS0 * F_DIM);
    ushort* z0b   = alloc_h((size_t)2 * NS0 * D_DIM);
    ushort* z1b   = alloc_h((size_t)2 * NS1 * D_DIM);
    ushort* z2b   = alloc_h((size_t)2 * ND1 * D_DIM);
    ushort* h0b   = alloc_h((size_t)2 * ND0 * D_DIM);
    ushort* Wtin  = alloc_h((size_t)2 * D_DIM * F_DIM);
    ushort* Wt1   = alloc_h((size_t)2 * D_DIM * D_DIM);
    ushort* Wt2   = alloc_h((size_t)2 * D_DIM * D_DIM);
    ushort* Wtout = alloc_h((size_t)2 * O_DIM * D_DIM);

    float* ps      = alloc_f((size_t)2 * NS0 * 2);
    float* qs      = alloc_f((size_t)2 * NS0);
    float* pd      = alloc_f((size_t)2 * ND0 * 2);
    float* qd      = alloc_f((size_t)2 * ND0);
    float* cvec    = alloc_f((size_t)2 * ND0);
    float* partial = alloc_f((size_t)2 * ND0 * D_DIM);
    float* ee      = alloc_f((size_t)2 * E0_N * 2);
    float* ei      = alloc_f((size_t)2 * E0_N);

    int* src_c0 = alloc_i(E0_N); int* row_c0 = alloc_i(ND0 + 1);
    int* src_s0 = alloc_i(E0_N); int* row_s0 = alloc_i(ND0 + 1);
    int* src_c1 = alloc_i(E1_N); int* row_c1 = alloc_i(ND1 + 1);
    int* src_s1 = alloc_i(E1_N); int* row_s1 = alloc_i(ND1 + 1);
    int* cnt_all  = alloc_i(2 * ND0 + 2 * ND1);
    int* head_all = alloc_i(2 * ND0 + 2 * ND1);

    int* cnt_c0 = cnt_all;            int* head_c0 = head_all;
    int* cnt_s0 = cnt_all + ND0;      int* head_s0 = head_all + ND0;
    int* cnt_c1 = cnt_all + 2 * ND0;  int* head_c1 = head_all + 2 * ND0;
    int* cnt_s1 = cnt_c1 + ND1;       int* head_s1 = head_c1 + ND1;

    // ---- batched CSR build for the 4 edge lists ----
    const int NB_ALL = 2 * NBE0 + 2 * NBE1;
    hipMemsetAsync(cnt_all, 0, (size_t)(2 * ND0 + 2 * ND1) * 4, stream);
    {
        CPtr4 edp  = {dst0_cor, dst0_sim, dst1_cor, dst1_sim};
        CPtr4 esp  = {src0_cor, src0_sim, src1_cor, src1_sim};
        MPtr4 cntp = {cnt_c0, cnt_s0, cnt_c1, cnt_s1};
        MPtr4 rowp = {row_c0, row_s0, row_c1, row_s1};
        MPtr4 hdp  = {head_c0, head_s0, head_c1, head_s1};
        MPtr4 srcp = {src_c0, src_s0, src_c1, src_s1};
        histo4<<<NB_ALL, 256, 0, stream>>>(edp, cntp);
        exscan4<<<4, 1024, 0, stream>>>(cntp, rowp, hdp);
        build4<<<NB_ALL, 256, 0, stream>>>(esp, edp, hdp, srcp);
    }

    // ---- dtype prep ----
    cvt_bf16<<<((size_t)NS0 * F_DIM / 4 + 255) / 256, 256, 0, stream>>>(
        feat, featb, NS0 * F_DIM);
    prep_weights<<<576, 256, 0, stream>>>(Win, W1, W2, Wout, Wtin, Wt1, Wt2, Wtout);

    // ======== both modes fused via blockIdx.y ========
    const size_t Z0S = (size_t)NS0 * D_DIM, Z1S = (size_t)NS1 * D_DIM;
    const size_t Z2S = (size_t)ND1 * D_DIM, H0S = (size_t)ND0 * D_DIM;

    // --- Layer 0: z0 = feat @ Win[m] + b_in[m]
    mfma_gemm<128, 256, 0><<<dim3((NS0 + 127) / 128, 2), 256, 0, stream>>>(
        featb, 0, Wtin, (size_t)D_DIM * F_DIM, b_in, D_DIM,
        nullptr, 0, nullptr, 0, z0b, Z0S, NS0);

    // --- Layer 1
    node_proj<<<dim3((NS0 + NP_NPB - 1) / NP_NPB, 2), 256, 0, stream>>>(
        z0b, Z0S, ea1, ia1, ps, qs, pd, qd, NS0, ND0);
    edge_att<<<dim3((ND0 + 3) / 4, 2), 256, 0, stream>>>(
        ps, pd, qs, qd, row_c0, src_c0, row_s0, src_s0, ee, ei, ND0);
    gather_acc<<<dim3((ND0 + 3) / 4, 2), 256, 0, stream>>>(
        z0b, Z0S, ee, ei, row_c0, src_c0, row_s0, src_s0,
        h0b, cvec, partial, ND0);
    mfma_gemm<128, 128, 2><<<dim3((ND0 + 127) / 128, 2), 256, 0, stream>>>(
        h0b, H0S, Wt1, (size_t)D_DIM * D_DIM, b1, D_DIM,
        cvec, ND0, partial, H0S, z1b, Z1S, ND0);

    // --- Layer 2
    node_proj<<<dim3((NS1 + NP_NPB - 1) / NP_NPB, 2), 256, 0, stream>>>(
        z1b, Z1S, ea2, ia2, ps, qs, pd, qd, NS1, ND1);
    edge_att<<<dim3((ND1 + 3) / 4, 2), 256, 0, stream>>>(
        ps, pd, qs, qd, row_c1, src_c1, row_s1, src_s1, ee, ei, ND1);
    gather_acc<<<dim3((ND1 + 3) / 4, 2), 256, 0, stream>>>(
        z1b, Z1S, ee, ei, row_c1, src_c1, row_s1, src_s1,
        h0b, cvec, partial, ND1);
    mfma_gemm<128, 128, 2><<<dim3((ND1 + 127) / 128, 2), 256, 0, stream>>>(
        h0b, H0S, Wt2, (size_t)D_DIM * D_DIM, b2, D_DIM,
        cvec, ND0, partial, H0S, z2b, Z2S, ND1);

    // --- Output: out[m] = z2 @ Wout[m] + bout[m]  (fp32 out)
    mfma_gemm<64, 128, 1><<<dim3((ND1 + 127) / 128, 2), 256, 0, stream>>>(
        z2b, Z2S, Wtout, (size_t)O_DIM * D_DIM, bout, O_DIM,
        nullptr, 0, nullptr, 0, (float*)d_out, (size_t)ND1 * O_DIM, ND1);
}

// Round 8
// 588.511 us; speedup vs baseline: 6.9659x; 1.0123x over previous
//
#include <hip/hip_runtime.h>
#include <hip/hip_bf16.h>
#include <math.h>

// Problem constants (fixed by setup_inputs())
#define F_DIM 256
#define D_DIM 128
#define O_DIM 64
#define NS0   100000
#define ND0   25000
#define E0_N  500000
#define NS1   25000
#define ND1   5000
#define E1_N  100000

#define NBE0  1954   // ceil(E0_N/256)
#define NBE1  391    // ceil(E1_N/256)

typedef __attribute__((ext_vector_type(8))) short s8v;   // 8 bf16 (4 VGPRs)
typedef __attribute__((ext_vector_type(4))) float f4v;   // 4 fp32 acc

struct CPtr4 { const int *p0, *p1, *p2, *p3; };
struct MPtr4 { int *p0, *p1, *p2, *p3; };

__device__ __forceinline__ float2 unpack2(uint u) {
    union { uint i; float f; } a, b;
    a.i = (u & 0xffffu) << 16; b.i = u & 0xffff0000u;
    return make_float2(a.f, b.f);
}
__device__ __forceinline__ ushort f2bf(float f) {
    __hip_bfloat16 h = __float2bfloat16(f);
    return *(ushort*)&h;
}
__device__ __forceinline__ float u2f(uint u) {
    union { uint i; float f; } v; v.i = u; return v.f;
}
__device__ __forceinline__ uint f2u(float f) {
    union { uint i; float f; } v; v.f = f; return v.i;
}

// ---------------------------------------------------------------------------
// All weight transposes in ONE launch: [K][N] fp32 -> [N][K] bf16, 8 matrices.
// ---------------------------------------------------------------------------
__global__ void prep_weights(
    const float* __restrict__ Win, const float* __restrict__ W1,
    const float* __restrict__ W2,  const float* __restrict__ Wout,
    ushort* __restrict__ Wtin, ushort* __restrict__ Wt1,
    ushort* __restrict__ Wt2,  ushort* __restrict__ Wtout)
{
    int i = blockIdx.x * 256 + threadIdx.x;
    if (i < 65536) {                                  // Win
        int m = i >> 15, r = i & 32767, k = r >> 7, n = r & 127;
        Wtin[m * 32768 + n * 256 + k] = f2bf(Win[m * 32768 + k * 128 + n]);
    } else if (i < 98304) {                           // W1
        int i2 = i - 65536;
        int m = i2 >> 14, r = i2 & 16383, k = r >> 7, n = r & 127;
        Wt1[m * 16384 + n * 128 + k] = f2bf(W1[m * 16384 + k * 128 + n]);
    } else if (i < 131072) {                          // W2
        int i2 = i - 98304;
        int m = i2 >> 14, r = i2 & 16383, k = r >> 7, n = r & 127;
        Wt2[m * 16384 + n * 128 + k] = f2bf(W2[m * 16384 + k * 128 + n]);
    } else if (i < 147456) {                          // Wout
        int i2 = i - 131072;
        int m = i2 >> 13, r = i2 & 8191, k = r >> 6, n = r & 63;
        Wtout[m * 8192 + n * 128 + k] = f2bf(Wout[m * 8192 + k * 64 + n]);
    }
}

// ---------------------------------------------------------------------------
// MFMA bf16 GEMM, mode-fused (blockIdx.y = m). AF32: A is fp32, converted
// to bf16 during LDS staging (saves the separate cvt pass).
// EPI 0: +bias -> bf16   EPI 1: +bias -> f32
// EPI 2 (agg-fused): out = partial + 0.5*relu(acc + c[row]*bias[col]) -> bf16
// ---------------------------------------------------------------------------
template<int NW, int KD, int EPI, bool AF32>
__global__ __launch_bounds__(256) void mfma_gemm(
    const void* __restrict__ Ab, size_t astr,
    const ushort* __restrict__ Btb, size_t btstr,
    const float* __restrict__ biasb, size_t bstr,
    const float* __restrict__ cvecb, size_t cvstr,
    const float* __restrict__ partialb, size_t pstr,
    void* __restrict__ Coutb, size_t coutstr, int M)
{
    const int m = blockIdx.y;
    const ushort* A16 = AF32 ? nullptr : ((const ushort*)Ab + m * astr);
    const float*  A32 = AF32 ? ((const float*)Ab + m * astr) : nullptr;
    const ushort* Bt = Btb + m * btstr;
    const float* bias = biasb + m * bstr;
    const float* cvec = (EPI == 2) ? cvecb + m * cvstr : nullptr;
    const float* partial = (EPI == 2) ? partialb + m * pstr : nullptr;
    char* Cout = (char*)Coutb + m * coutstr * (EPI == 1 ? 4 : 2);

    constexpr int PA = 40;           // 32 + 8 bf16 pad
    constexpr int WAVES_M = (NW == 128) ? 2 : 4;
    constexpr int WM = 128 / WAVES_M;
    constexpr int TM = WM / 16;
    constexpr int TN = 4;
    __shared__ ushort As[128 * PA];
    __shared__ ushort Bs[NW * PA];

    const int tid  = threadIdx.x;
    const int row0 = blockIdx.x * 128;
    const int wave = tid >> 6, lane = tid & 63;
    const int l15 = lane & 15, l4 = lane >> 4;
    int wm0, wn0;
    if (NW == 128) { wm0 = (wave >> 1) * 64; wn0 = (wave & 1) * 64; }
    else           { wm0 = wave * WM;        wn0 = 0; }

    f4v acc[TM][TN];
    #pragma unroll
    for (int i = 0; i < TM; ++i)
        #pragma unroll
        for (int j = 0; j < TN; ++j)
            acc[i][j] = (f4v)(0.0f);

    for (int kc = 0; kc < KD; kc += 32) {
        __syncthreads();
        #pragma unroll
        for (int it = 0; it < 2; ++it) {
            int f = tid + it * 256;
            int r = f >> 2, g = (f & 3) * 8;
            int gr = row0 + r;
            if (AF32) {
                float4 v0 = make_float4(0.f, 0.f, 0.f, 0.f);
                float4 v1 = make_float4(0.f, 0.f, 0.f, 0.f);
                if (gr < M) {
                    v0 = *(const float4*)(A32 + (size_t)gr * KD + kc + g);
                    v1 = *(const float4*)(A32 + (size_t)gr * KD + kc + g + 4);
                }
                ushort4 o0, o1;
                o0.x = f2bf(v0.x); o0.y = f2bf(v0.y); o0.z = f2bf(v0.z); o0.w = f2bf(v0.w);
                o1.x = f2bf(v1.x); o1.y = f2bf(v1.y); o1.z = f2bf(v1.z); o1.w = f2bf(v1.w);
                *(ushort4*)(&As[r * PA + g]) = o0;
                *(ushort4*)(&As[r * PA + g + 4]) = o1;
            } else {
                float4 v = make_float4(0.f, 0.f, 0.f, 0.f);
                if (gr < M) v = *(const float4*)(A16 + (size_t)gr * KD + kc + g);
                *(float4*)(&As[r * PA + g]) = v;
            }
        }
        #pragma unroll
        for (int it = 0; it < NW * 32 / (256 * 8); ++it) {
            int f = tid + it * 256;
            int r = f >> 2, g = (f & 3) * 8;
            *(float4*)(&Bs[r * PA + g]) = *(const float4*)(Bt + (size_t)r * KD + kc + g);
        }
        __syncthreads();

        s8v af[TM], bfr[TN];
        #pragma unroll
        for (int i = 0; i < TM; ++i)
            af[i] = *(const s8v*)(&As[(wm0 + i * 16 + l15) * PA + l4 * 8]);
        #pragma unroll
        for (int j = 0; j < TN; ++j)
            bfr[j] = *(const s8v*)(&Bs[(wn0 + j * 16 + l15) * PA + l4 * 8]);
        #pragma unroll
        for (int i = 0; i < TM; ++i)
            #pragma unroll
            for (int j = 0; j < TN; ++j)
                acc[i][j] = __builtin_amdgcn_mfma_f32_16x16x32_bf16(
                    af[i], bfr[j], acc[i][j], 0, 0, 0);
    }

    #pragma unroll
    for (int i = 0; i < TM; ++i) {
        #pragma unroll
        for (int ii = 0; ii < 4; ++ii) {
            int row = row0 + wm0 + i * 16 + l4 * 4 + ii;
            if (row < M) {
                #pragma unroll
                for (int j = 0; j < TN; ++j) {
                    int col = wn0 + j * 16 + l15;
                    float a = acc[i][j][ii];
                    if (EPI == 0) {
                        ((ushort*)Cout)[(size_t)row * NW + col] = f2bf(a + bias[col]);
                    } else if (EPI == 1) {
                        ((float*)Cout)[(size_t)row * NW + col] = a + bias[col];
                    } else {
                        float val = a + cvec[row] * bias[col];
                        float o = partial[(size_t)row * NW + col] + 0.5f * fmaxf(val, 0.f);
                        ((ushort*)Cout)[(size_t)row * NW + col] = f2bf(o);
                    }
                }
            }
        }
    }
}

// ---------------------------------------------------------------------------
// CSR construction, all 4 edge lists batched per kernel.
// ---------------------------------------------------------------------------
__global__ void histo4(CPtr4 ed, MPtr4 cnt)
{
    int b = blockIdx.x, t = threadIdx.x;
    const int* edp; int* cp; int e, E;
    if (b < NBE0)          { edp = ed.p0; cp = cnt.p0; e = b * 256 + t;              E = E0_N; }
    else if (b < 2 * NBE0) { edp = ed.p1; cp = cnt.p1; e = (b - NBE0) * 256 + t;     E = E0_N; }
    else if (b < 2 * NBE0 + NBE1)
                           { edp = ed.p2; cp = cnt.p2; e = (b - 2 * NBE0) * 256 + t; E = E1_N; }
    else                   { edp = ed.p3; cp = cnt.p3; e = (b - 2 * NBE0 - NBE1) * 256 + t; E = E1_N; }
    if (e < E) atomicAdd(&cp[edp[e]], 1);
}

__global__ __launch_bounds__(1024) void exscan4(MPtr4 cnt, MPtr4 row, MPtr4 head)
{
    __shared__ int part[1024];
    const int b = blockIdx.x, t = threadIdx.x;
    int* cp; int* rp; int* hp; int n;
    if (b == 0)      { cp = cnt.p0; rp = row.p0; hp = head.p0; n = ND0; }
    else if (b == 1) { cp = cnt.p1; rp = row.p1; hp = head.p1; n = ND0; }
    else if (b == 2) { cp = cnt.p2; rp = row.p2; hp = head.p2; n = ND1; }
    else             { cp = cnt.p3; rp = row.p3; hp = head.p3; n = ND1; }

    const int chunk = (n + 1023) >> 10;
    const int start = t * chunk;
    int s = 0;
    for (int i = 0; i < chunk; ++i) {
        int idx = start + i;
        if (idx < n) s += cp[idx];
    }
    part[t] = s;
    __syncthreads();
    for (int off = 1; off < 1024; off <<= 1) {
        int v = (t >= off) ? part[t - off] : 0;
        __syncthreads();
        part[t] += v;
        __syncthreads();
    }
    int run = (t == 0) ? 0 : part[t - 1];
    for (int i = 0; i < chunk; ++i) {
        int idx = start + i;
        if (idx < n) { rp[idx] = run; hp[idx] = run; run += cp[idx]; }
    }
    if (t == 1023) rp[n] = part[1023];
}

__global__ void build4(CPtr4 es, CPtr4 ed, MPtr4 head, MPtr4 src)
{
    int b = blockIdx.x, t = threadIdx.x;
    const int *esp, *edp; int *hp, *sp; int e, E;
    if (b < NBE0)          { esp = es.p0; edp = ed.p0; hp = head.p0; sp = src.p0; e = b * 256 + t;              E = E0_N; }
    else if (b < 2 * NBE0) { esp = es.p1; edp = ed.p1; hp = head.p1; sp = src.p1; e = (b - NBE0) * 256 + t;     E = E0_N; }
    else if (b < 2 * NBE0 + NBE1)
                           { esp = es.p2; edp = ed.p2; hp = head.p2; sp = src.p2; e = (b - 2 * NBE0) * 256 + t; E = E1_N; }
    else                   { esp = es.p3; edp = ed.p3; hp = head.p3; sp = src.p3; e = (b - 2 * NBE0 - NBE1) * 256 + t; E = E1_N; }
    if (e >= E) return;
    int p = atomicAdd(&hp[edp[e]], 1);
    sp[p] = esp[e];
}

// ---------------------------------------------------------------------------
// Per-node projections, mode-fused (blockIdx.y = m). 8 lanes/node, weight
// slices in registers. Channels: ps0 ps1 qs pd0 pd1 qd. (alpha: a0+a1==1)
// ---------------------------------------------------------------------------
#define NP_NPB 128
__global__ __launch_bounds__(256) void node_proj(
    const ushort* __restrict__ zb, size_t zstr,
    const float* __restrict__ Web,   // + m*512
    const float* __restrict__ Wib,   // + m*256
    float* __restrict__ psb, float* __restrict__ qsb,
    float* __restrict__ pdb, float* __restrict__ qdb,
    int n_src, int n_dst)
{
    const int m = blockIdx.y;
    const ushort* z = zb + m * zstr;
    const float* We = Web + m * 512;
    const float* Wi = Wib + m * 256;
    float* ps = psb + (size_t)m * NS0 * 2;
    float* qs = qsb + (size_t)m * NS0;
    float* pd = pdb + (size_t)m * ND0 * 2;
    float* qd = qdb + (size_t)m * ND0;

    __shared__ float w[6][D_DIM];
    for (int k = threadIdx.x; k < D_DIM; k += 256) {
        w[0][k] = We[k * 2 + 0];
        w[1][k] = We[k * 2 + 1];
        w[2][k] = Wi[k];
        w[3][k] = We[(D_DIM + k) * 2 + 0];
        w[4][k] = We[(D_DIM + k) * 2 + 1];
        w[5][k] = Wi[D_DIM + k];
    }
    __syncthreads();

    const int sub = threadIdx.x & 7;
    const int g   = threadIdx.x >> 3;

    float wr[6][16];
    #pragma unroll
    for (int c = 0; c < 6; ++c)
        #pragma unroll
        for (int q = 0; q < 4; ++q) {
            float4 f = *(const float4*)(&w[c][sub * 16 + q * 4]);
            wr[c][q * 4 + 0] = f.x; wr[c][q * 4 + 1] = f.y;
            wr[c][q * 4 + 2] = f.z; wr[c][q * 4 + 3] = f.w;
        }

    #pragma unroll
    for (int it = 0; it < 4; ++it) {
        int node = blockIdx.x * NP_NPB + it * 32 + g;
        if (node >= n_src) continue;
        const ushort* zp = z + (size_t)node * D_DIM + sub * 16;
        uint4 ra = *(const uint4*)zp;
        uint4 rb = *(const uint4*)(zp + 8);
        uint rr[8] = {ra.x, ra.y, ra.z, ra.w, rb.x, rb.y, rb.z, rb.w};
        float p[6] = {0.f, 0.f, 0.f, 0.f, 0.f, 0.f};
        #pragma unroll
        for (int e = 0; e < 8; ++e) {
            float2 f2 = unpack2(rr[e]);
            #pragma unroll
            for (int c = 0; c < 6; ++c)
                p[c] += f2.x * wr[c][2 * e] + f2.y * wr[c][2 * e + 1];
        }
        #pragma unroll
        for (int off = 4; off > 0; off >>= 1)
            #pragma unroll
            for (int c = 0; c < 6; ++c)
                p[c] += __shfl_down(p[c], off);

        if (sub == 0) {
            *(float2*)(ps + (size_t)node * 2) = make_float2(p[0], p[1]);
            qs[node] = p[2];
            if (node < n_dst) {
                *(float2*)(pd + (size_t)node * 2) = make_float2(p[3], p[4]);
                qd[node] = p[5];
            }
        }
    }
}

// ---------------------------------------------------------------------------
// Edge attention, mode-fused: one wave per dst, one LANE per CSR slot.
// Writes PACKED (weight, src) uint2 per edge; also wave-reduces Σe0 and
// writes cvec[d] = Σe0/deg (removes redundant per-lane se0 in gather).
// ---------------------------------------------------------------------------
__global__ __launch_bounds__(256) void edge_att(
    const float* __restrict__ psb, const float* __restrict__ pdb,
    const float* __restrict__ qsb, const float* __restrict__ qdb,
    const int* __restrict__ row_c, const int* __restrict__ src_c,
    const int* __restrict__ row_s, const int* __restrict__ src_s,
    uint2* __restrict__ epkb, uint2* __restrict__ ipkb,
    float* __restrict__ cvecb, int n_dst)
{
    const int m = blockIdx.y;
    const int d = blockIdx.x * 4 + (threadIdx.x >> 6);
    const int lane = threadIdx.x & 63;
    if (d >= n_dst) return;

    const float* ps = psb + (size_t)m * NS0 * 2;
    const float* qs = qsb + (size_t)m * NS0;
    const float* pdv = pdb + (size_t)m * ND0 * 2;
    const float* qdv = qdb + (size_t)m * ND0;
    const int* erow = m ? row_s : row_c;
    const int* esrc = m ? src_s : src_c;
    const int* irow = m ? row_c : row_s;
    const int* isrc = m ? src_c : src_s;
    uint2* epk = epkb + (size_t)m * E0_N;
    uint2* ipk = ipkb + (size_t)m * E0_N;
    float* cvec = cvecb + (size_t)m * ND0;

    const float pd0 = pdv[2 * d], pd1 = pdv[2 * d + 1];
    const float qdd = qdv[d];

    const int b0 = erow[d], b1 = erow[d + 1];
    float se0 = 0.f;
    for (int j = b0 + lane; j < b1; j += 64) {
        int s = esrc[j];
        float2 pp = *(const float2*)(ps + 2 * (size_t)s);
        float l0 = pp.x + pd0, l1 = pp.y + pd1;
        float mx = fmaxf(l0, l1);
        float x0 = __expf(l0 - mx), x1 = __expf(l1 - mx);
        float e0 = x0 / (x0 + x1);
        epk[j] = make_uint2(f2u(e0), (uint)s);
        se0 += e0;
    }
    #pragma unroll
    for (int off = 32; off > 0; off >>= 1)
        se0 += __shfl_down(se0, off);
    if (lane == 0) cvec[d] = se0 / fmaxf((float)(b1 - b0), 1.0f);

    const int c0 = irow[d], c1 = irow[d + 1];
    for (int j = c0 + lane; j < c1; j += 64) {
        int s = isrc[j];
        float q = qs[s] + qdd;
        float sg = 1.0f / (1.0f + __expf(-q));
        ipk[j] = make_uint2(f2u(sg), (uint)s);
    }
}

// ---------------------------------------------------------------------------
// Gather-accumulate, mode-fused: one wave per dst node, unroll-8.
// e-loop uses e1 = 1-e0:  accumulate sz (add) + h0 (fma); eh = sz - h0.
//   h0 -> bf16 (normalized by deg), partial = 0.5*(relu(eh*ih) + z_d)
// ---------------------------------------------------------------------------
__global__ __launch_bounds__(256) void gather_acc(
    const ushort* __restrict__ zb, size_t zstr,
    const uint2* __restrict__ epkb, const uint2* __restrict__ ipkb,
    const int* __restrict__ row_c, const int* __restrict__ row_s,
    ushort* __restrict__ h0base, float* __restrict__ partialb, int n_dst)
{
    const int m = blockIdx.y;
    const int d = blockIdx.x * 4 + (threadIdx.x >> 6);
    const int lane = threadIdx.x & 63;
    if (d >= n_dst) return;

    const ushort* z = zb + m * zstr;
    const uint2* epk = epkb + (size_t)m * E0_N;
    const uint2* ipk = ipkb + (size_t)m * E0_N;
    const int* erow = m ? row_s : row_c;
    const int* irow = m ? row_c : row_s;
    ushort* h0b = h0base + (size_t)m * ND0 * D_DIM;
    float* partial = partialb + (size_t)m * ND0 * D_DIM;

    float h0x = 0.f, h0y = 0.f, szx = 0.f, szy = 0.f;
    float ihx = 0.f, ihy = 0.f;

    const int b0 = erow[d], b1 = erow[d + 1];
    int j = b0;
    for (; j + 8 <= b1; j += 8) {
        uint2 ew[8]; uint rr[8];
        #pragma unroll
        for (int k = 0; k < 8; ++k) ew[k] = epk[j + k];
        #pragma unroll
        for (int k = 0; k < 8; ++k) rr[k] = *(const uint*)(z + (size_t)ew[k].y * D_DIM + lane * 2);
        #pragma unroll
        for (int k = 0; k < 8; ++k) {
            float w0 = u2f(ew[k].x);
            float2 v = unpack2(rr[k]);
            szx += v.x; szy += v.y;
            h0x += w0 * v.x; h0y += w0 * v.y;
        }
    }
    for (; j < b1; ++j) {
        uint2 ew = epk[j];
        float w0 = u2f(ew.x);
        float2 v = unpack2(*(const uint*)(z + (size_t)ew.y * D_DIM + lane * 2));
        szx += v.x; szy += v.y;
        h0x += w0 * v.x; h0y += w0 * v.y;
    }

    const int c0 = irow[d], c1 = irow[d + 1];
    j = c0;
    for (; j + 8 <= c1; j += 8) {
        uint2 ew[8]; uint rr[8];
        #pragma unroll
        for (int k = 0; k < 8; ++k) ew[k] = ipk[j + k];
        #pragma unroll
        for (int k = 0; k < 8; ++k) rr[k] = *(const uint*)(z + (size_t)ew[k].y * D_DIM + lane * 2);
        #pragma unroll
        for (int k = 0; k < 8; ++k) {
            float g = u2f(ew[k].x);
            float2 v = unpack2(rr[k]);
            ihx += g * v.x; ihy += g * v.y;
        }
    }
    for (; j < c1; ++j) {
        uint2 ew = ipk[j];
        float g = u2f(ew.x);
        float2 v = unpack2(*(const uint*)(z + (size_t)ew.y * D_DIM + lane * 2));
        ihx += g * v.x; ihy += g * v.y;
    }

    float ehx = szx - h0x, ehy = szy - h0y;   // e1 = 1 - e0
    float inv = 1.0f / fmaxf((float)(b1 - b0), 1.0f);
    uint hp = (uint)f2bf(h0x * inv) | ((uint)f2bf(h0y * inv) << 16);
    *(uint*)(h0b + (size_t)d * D_DIM + lane * 2) = hp;

    float2 zd = unpack2(*(const uint*)(z + (size_t)d * D_DIM + lane * 2));
    float px = 0.5f * (fmaxf(ehx * ihx, 0.f) + zd.x);
    float py = 0.5f * (fmaxf(ehy * ihy, 0.f) + zd.y);
    *(float2*)(partial + (size_t)d * D_DIM + lane * 2) = make_float2(px, py);
}

// ---------------------------------------------------------------------------
extern "C" void kernel_launch(void* const* d_in, const int* in_sizes, int n_in,
                              void* d_out, int out_size, void* d_ws, size_t ws_size,
                              hipStream_t stream)
{
    const float* feat = (const float*)d_in[0];
    const int* src0_cor = (const int*)d_in[1];
    const int* dst0_cor = (const int*)d_in[2];
    const int* src0_sim = (const int*)d_in[3];
    const int* dst0_sim = (const int*)d_in[4];
    const int* src1_cor = (const int*)d_in[5];
    const int* dst1_cor = (const int*)d_in[6];
    const int* src1_sim = (const int*)d_in[7];
    const int* dst1_sim = (const int*)d_in[8];
    const float* Win  = (const float*)d_in[11];
    const float* b_in = (const float*)d_in[12];
    const float* ea1  = (const float*)d_in[14];
    const float* ia1  = (const float*)d_in[15];
    const float* W1   = (const float*)d_in[16];
    const float* b1   = (const float*)d_in[17];
    const float* ea2  = (const float*)d_in[19];
    const float* ia2  = (const float*)d_in[20];
    const float* W2   = (const float*)d_in[21];
    const float* b2   = (const float*)d_in[22];
    const float* Wout = (const float*)d_in[23];
    const float* bout = (const float*)d_in[24];
    (void)in_sizes; (void)n_in; (void)out_size; (void)ws_size;

    // ---- workspace layout ----
    char* wsb = (char*)d_ws;
    size_t off = 0;
    auto alloc_f = [&](size_t n) { float*  p = (float*) (wsb + off); off += n * 4; return p; };
    auto alloc_i = [&](size_t n) { int*    p = (int*)   (wsb + off); off += n * 4; return p; };
    auto alloc_h = [&](size_t n) { ushort* p = (ushort*)(wsb + off); off += ((n * 2 + 15) & ~15ull); return p; };
    auto alloc_u2 = [&](size_t n) { uint2* p = (uint2*)(wsb + off); off += n * 8; return p; };

    ushort* z0b   = alloc_h((size_t)2 * NS0 * D_DIM);
    ushort* z1b   = alloc_h((size_t)2 * NS1 * D_DIM);
    ushort* z2b   = alloc_h((size_t)2 * ND1 * D_DIM);
    ushort* h0b   = alloc_h((size_t)2 * ND0 * D_DIM);
    ushort* Wtin  = alloc_h((size_t)2 * D_DIM * F_DIM);
    ushort* Wt1   = alloc_h((size_t)2 * D_DIM * D_DIM);
    ushort* Wt2   = alloc_h((size_t)2 * D_DIM * D_DIM);
    ushort* Wtout = alloc_h((size_t)2 * O_DIM * D_DIM);

    float* ps      = alloc_f((size_t)2 * NS0 * 2);
    float* qs      = alloc_f((size_t)2 * NS0);
    float* pd      = alloc_f((size_t)2 * ND0 * 2);
    float* qd      = alloc_f((size_t)2 * ND0);
    float* cvec    = alloc_f((size_t)2 * ND0);
    float* partial = alloc_f((size_t)2 * ND0 * D_DIM);
    uint2* epk     = alloc_u2((size_t)2 * E0_N);
    uint2* ipk     = alloc_u2((size_t)2 * E0_N);

    int* src_c0 = alloc_i(E0_N); int* row_c0 = alloc_i(ND0 + 1);
    int* src_s0 = alloc_i(E0_N); int* row_s0 = alloc_i(ND0 + 1);
    int* src_c1 = alloc_i(E1_N); int* row_c1 = alloc_i(ND1 + 1);
    int* src_s1 = alloc_i(E1_N); int* row_s1 = alloc_i(ND1 + 1);
    int* cnt_all  = alloc_i(2 * ND0 + 2 * ND1);
    int* head_all = alloc_i(2 * ND0 + 2 * ND1);

    int* cnt_c0 = cnt_all;            int* head_c0 = head_all;
    int* cnt_s0 = cnt_all + ND0;      int* head_s0 = head_all + ND0;
    int* cnt_c1 = cnt_all + 2 * ND0;  int* head_c1 = head_all + 2 * ND0;
    int* cnt_s1 = cnt_c1 + ND1;       int* head_s1 = head_c1 + ND1;

    // ---- batched CSR build for the 4 edge lists ----
    const int NB_ALL = 2 * NBE0 + 2 * NBE1;
    hipMemsetAsync(cnt_all, 0, (size_t)(2 * ND0 + 2 * ND1) * 4, stream);
    {
        CPtr4 edp  = {dst0_cor, dst0_sim, dst1_cor, dst1_sim};
        CPtr4 esp  = {src0_cor, src0_sim, src1_cor, src1_sim};
        MPtr4 cntp = {cnt_c0, cnt_s0, cnt_c1, cnt_s1};
        MPtr4 rowp = {row_c0, row_s0, row_c1, row_s1};
        MPtr4 hdp  = {head_c0, head_s0, head_c1, head_s1};
        MPtr4 srcp = {src_c0, src_s0, src_c1, src_s1};
        histo4<<<NB_ALL, 256, 0, stream>>>(edp, cntp);
        exscan4<<<4, 1024, 0, stream>>>(cntp, rowp, hdp);
        build4<<<NB_ALL, 256, 0, stream>>>(esp, edp, hdp, srcp);
    }

    // ---- weight prep (bf16 transpose) ----
    prep_weights<<<576, 256, 0, stream>>>(Win, W1, W2, Wout, Wtin, Wt1, Wt2, Wtout);

    // ======== both modes fused via blockIdx.y ========
    const size_t Z0S = (size_t)NS0 * D_DIM, Z1S = (size_t)NS1 * D_DIM;
    const size_t Z2S = (size_t)ND1 * D_DIM, H0S = (size_t)ND0 * D_DIM;

    // --- Layer 0: z0 = feat @ Win[m] + b_in[m]  (fp32 A, converted in staging)
    mfma_gemm<128, 256, 0, true><<<dim3((NS0 + 127) / 128, 2), 256, 0, stream>>>(
        feat, 0, Wtin, (size_t)D_DIM * F_DIM, b_in, D_DIM,
        nullptr, 0, nullptr, 0, z0b, Z0S, NS0);

    // --- Layer 1
    node_proj<<<dim3((NS0 + NP_NPB - 1) / NP_NPB, 2), 256, 0, stream>>>(
        z0b, Z0S, ea1, ia1, ps, qs, pd, qd, NS0, ND0);
    edge_att<<<dim3((ND0 + 3) / 4, 2), 256, 0, stream>>>(
        ps, pd, qs, qd, row_c0, src_c0, row_s0, src_s0, epk, ipk, cvec, ND0);
    gather_acc<<<dim3((ND0 + 3) / 4, 2), 256, 0, stream>>>(
        z0b, Z0S, epk, ipk, row_c0, row_s0, h0b, partial, ND0);
    mfma_gemm<128, 128, 2, false><<<dim3((ND0 + 127) / 128, 2), 256, 0, stream>>>(
        h0b, H0S, Wt1, (size_t)D_DIM * D_DIM, b1, D_DIM,
        cvec, ND0, partial, H0S, z1b, Z1S, ND0);

    // --- Layer 2
    node_proj<<<dim3((NS1 + NP_NPB - 1) / NP_NPB, 2), 256, 0, stream>>>(
        z1b, Z1S, ea2, ia2, ps, qs, pd, qd, NS1, ND1);
    edge_att<<<dim3((ND1 + 3) / 4, 2), 256, 0, stream>>>(
        ps, pd, qs, qd, row_c1, src_c1, row_s1, src_s1, epk, ipk, cvec, ND1);
    gather_acc<<<dim3((ND1 + 3) / 4, 2), 256, 0, stream>>>(
        z1b, Z1S, epk, ipk, row_c1, row_s1, h0b, partial, ND1);
    mfma_gemm<128, 128, 2, false><<<dim3((ND1 + 127) / 128, 2), 256, 0, stream>>>(
        h0b, H0S, Wt2, (size_t)D_DIM * D_DIM, b2, D_DIM,
        cvec, ND0, partial, H0S, z2b, Z2S, ND1);

    // --- Output: out[m] = z2 @ Wout[m] + bout[m]  (fp32 out)
    mfma_gemm<64, 128, 1, false><<<dim3((ND1 + 127) / 128, 2), 256, 0, stream>>>(
        z2b, Z2S, Wtout, (size_t)O_DIM * D_DIM, bout, O_DIM,
        nullptr, 0, nullptr, 0, (float*)d_out, (size_t)ND1 * O_DIM, ND1);
}

// Round 9
// 553.587 us; speedup vs baseline: 7.4054x; 1.0631x over previous
//
#include <hip/hip_runtime.h>
#include <hip/hip_bf16.h>
#include <math.h>

// Problem constants (fixed by setup_inputs())
#define F_DIM 256
#define D_DIM 128
#define O_DIM 64
#define NS0   100000
#define ND0   25000
#define E0_N  500000
#define NS1   25000
#define ND1   5000
#define E1_N  100000

#define NBE0  1954   // ceil(E0_N/256)
#define NBE1  391    // ceil(E1_N/256)
#define NB_CSR (2 * NBE0 + 2 * NBE1)
#define NB_WPREP 576

typedef __attribute__((ext_vector_type(8))) short s8v;   // 8 bf16 (4 VGPRs)
typedef __attribute__((ext_vector_type(4))) float f4v;   // 4 fp32 acc

struct CPtr4 { const int *p0, *p1, *p2, *p3; };
struct MPtr4 { int *p0, *p1, *p2, *p3; };

__device__ __forceinline__ float2 unpack2(uint u) {
    union { uint i; float f; } a, b;
    a.i = (u & 0xffffu) << 16; b.i = u & 0xffff0000u;
    return make_float2(a.f, b.f);
}
__device__ __forceinline__ ushort f2bf(float f) {
    __hip_bfloat16 h = __float2bfloat16(f);
    return *(ushort*)&h;
}
__device__ __forceinline__ float u2f(uint u) {
    union { uint i; float f; } v; v.i = u; return v.f;
}
__device__ __forceinline__ uint f2u(float f) {
    union { uint i; float f; } v; v.f = f; return v.i;
}

// ---------------------------------------------------------------------------
// Layer-0 GEMM, dual-mode A-sharing: stage fp32 feat chunk ONCE, multiply by
// both modes' Wtin. Block = 64 rows x 128 cols x 2 modes. 4 waves (2x2).
// ---------------------------------------------------------------------------
__global__ __launch_bounds__(256) void gemm_l0(
    const float* __restrict__ A,          // feat [M][256] fp32
    const ushort* __restrict__ Btb,       // Wtin [2][128][256] bf16
    const float* __restrict__ biasb,      // b_in [2][128]
    ushort* __restrict__ Coutb, size_t coutstr, int M)
{
    constexpr int PA = 40;
    __shared__ ushort As[64 * PA];
    __shared__ ushort Bs[2][128 * PA];

    const int tid = threadIdx.x;
    const int row0 = blockIdx.x * 64;
    const int wave = tid >> 6, lane = tid & 63;
    const int l15 = lane & 15, l4 = lane >> 4;
    const int wm0 = (wave >> 1) * 32;   // 0 or 32
    const int wn0 = (wave & 1) * 64;    // 0 or 64

    f4v acc[2][2][4];
    #pragma unroll
    for (int m2 = 0; m2 < 2; ++m2)
        #pragma unroll
        for (int i = 0; i < 2; ++i)
            #pragma unroll
            for (int j = 0; j < 4; ++j)
                acc[m2][i][j] = (f4v)(0.0f);

    for (int kc = 0; kc < F_DIM; kc += 32) {
        __syncthreads();
        // A chunk: 64 rows x 32 fp32 -> bf16 (one 8-elem group per thread)
        {
            int r = tid >> 2, g = (tid & 3) * 8;
            int gr = row0 + r;
            float4 v0 = make_float4(0.f, 0.f, 0.f, 0.f);
            float4 v1 = make_float4(0.f, 0.f, 0.f, 0.f);
            if (gr < M) {
                v0 = *(const float4*)(A + (size_t)gr * F_DIM + kc + g);
                v1 = *(const float4*)(A + (size_t)gr * F_DIM + kc + g + 4);
            }
            ushort4 o0, o1;
            o0.x = f2bf(v0.x); o0.y = f2bf(v0.y); o0.z = f2bf(v0.z); o0.w = f2bf(v0.w);
            o1.x = f2bf(v1.x); o1.y = f2bf(v1.y); o1.z = f2bf(v1.z); o1.w = f2bf(v1.w);
            *(ushort4*)(&As[r * PA + g]) = o0;
            *(ushort4*)(&As[r * PA + g + 4]) = o1;
        }
        // B chunks: both modes, 128 rows x 32 bf16 each
        #pragma unroll
        for (int m2 = 0; m2 < 2; ++m2)
            #pragma unroll
            for (int it = 0; it < 2; ++it) {
                int f = tid + it * 256;
                int r = f >> 2, g = (f & 3) * 8;
                *(float4*)(&Bs[m2][r * PA + g]) =
                    *(const float4*)(Btb + m2 * (D_DIM * F_DIM) + (size_t)r * F_DIM + kc + g);
            }
        __syncthreads();

        s8v af[2];
        #pragma unroll
        for (int i = 0; i < 2; ++i)
            af[i] = *(const s8v*)(&As[(wm0 + i * 16 + l15) * PA + l4 * 8]);
        #pragma unroll
        for (int m2 = 0; m2 < 2; ++m2) {
            s8v bfr[4];
            #pragma unroll
            for (int j = 0; j < 4; ++j)
                bfr[j] = *(const s8v*)(&Bs[m2][(wn0 + j * 16 + l15) * PA + l4 * 8]);
            #pragma unroll
            for (int i = 0; i < 2; ++i)
                #pragma unroll
                for (int j = 0; j < 4; ++j)
                    acc[m2][i][j] = __builtin_amdgcn_mfma_f32_16x16x32_bf16(
                        af[i], bfr[j], acc[m2][i][j], 0, 0, 0);
        }
    }

    #pragma unroll
    for (int m2 = 0; m2 < 2; ++m2)
        #pragma unroll
        for (int i = 0; i < 2; ++i)
            #pragma unroll
            for (int ii = 0; ii < 4; ++ii) {
                int row = row0 + wm0 + i * 16 + l4 * 4 + ii;
                if (row < M) {
                    #pragma unroll
                    for (int j = 0; j < 4; ++j) {
                        int col = wn0 + j * 16 + l15;
                        Coutb[m2 * coutstr + (size_t)row * D_DIM + col] =
                            f2bf(acc[m2][i][j][ii] + biasb[m2 * D_DIM + col]);
                    }
                }
            }
}

// ---------------------------------------------------------------------------
// MFMA bf16 GEMM, mode-fused (blockIdx.y = m), bf16 A.
// EPI 1: +bias -> f32
// EPI 2 (agg-fused): out = partial + 0.5*relu(acc + c[row]*bias[col]) -> bf16
// ---------------------------------------------------------------------------
template<int NW, int KD, int EPI>
__global__ __launch_bounds__(256) void mfma_gemm(
    const ushort* __restrict__ Ab, size_t astr,
    const ushort* __restrict__ Btb, size_t btstr,
    const float* __restrict__ biasb, size_t bstr,
    const float* __restrict__ cvecb, size_t cvstr,
    const float* __restrict__ partialb, size_t pstr,
    void* __restrict__ Coutb, size_t coutstr, int M)
{
    const int m = blockIdx.y;
    const ushort* A = Ab + m * astr;
    const ushort* Bt = Btb + m * btstr;
    const float* bias = biasb + m * bstr;
    const float* cvec = (EPI == 2) ? cvecb + m * cvstr : nullptr;
    const float* partial = (EPI == 2) ? partialb + m * pstr : nullptr;
    char* Cout = (char*)Coutb + m * coutstr * (EPI == 1 ? 4 : 2);

    constexpr int PA = 40;
    constexpr int WAVES_M = (NW == 128) ? 2 : 4;
    constexpr int WM = 128 / WAVES_M;
    constexpr int TM = WM / 16;
    constexpr int TN = 4;
    __shared__ ushort As[128 * PA];
    __shared__ ushort Bs[NW * PA];

    const int tid  = threadIdx.x;
    const int row0 = blockIdx.x * 128;
    const int wave = tid >> 6, lane = tid & 63;
    const int l15 = lane & 15, l4 = lane >> 4;
    int wm0, wn0;
    if (NW == 128) { wm0 = (wave >> 1) * 64; wn0 = (wave & 1) * 64; }
    else           { wm0 = wave * WM;        wn0 = 0; }

    f4v acc[TM][TN];
    #pragma unroll
    for (int i = 0; i < TM; ++i)
        #pragma unroll
        for (int j = 0; j < TN; ++j)
            acc[i][j] = (f4v)(0.0f);

    for (int kc = 0; kc < KD; kc += 32) {
        __syncthreads();
        #pragma unroll
        for (int it = 0; it < 2; ++it) {
            int f = tid + it * 256;
            int r = f >> 2, g = (f & 3) * 8;
            int gr = row0 + r;
            float4 v = make_float4(0.f, 0.f, 0.f, 0.f);
            if (gr < M) v = *(const float4*)(A + (size_t)gr * KD + kc + g);
            *(float4*)(&As[r * PA + g]) = v;
        }
        #pragma unroll
        for (int it = 0; it < NW * 32 / (256 * 8); ++it) {
            int f = tid + it * 256;
            int r = f >> 2, g = (f & 3) * 8;
            *(float4*)(&Bs[r * PA + g]) = *(const float4*)(Bt + (size_t)r * KD + kc + g);
        }
        __syncthreads();

        s8v af[TM], bfr[TN];
        #pragma unroll
        for (int i = 0; i < TM; ++i)
            af[i] = *(const s8v*)(&As[(wm0 + i * 16 + l15) * PA + l4 * 8]);
        #pragma unroll
        for (int j = 0; j < TN; ++j)
            bfr[j] = *(const s8v*)(&Bs[(wn0 + j * 16 + l15) * PA + l4 * 8]);
        #pragma unroll
        for (int i = 0; i < TM; ++i)
            #pragma unroll
            for (int j = 0; j < TN; ++j)
                acc[i][j] = __builtin_amdgcn_mfma_f32_16x16x32_bf16(
                    af[i], bfr[j], acc[i][j], 0, 0, 0);
    }

    #pragma unroll
    for (int i = 0; i < TM; ++i) {
        #pragma unroll
        for (int ii = 0; ii < 4; ++ii) {
            int row = row0 + wm0 + i * 16 + l4 * 4 + ii;
            if (row < M) {
                #pragma unroll
                for (int j = 0; j < TN; ++j) {
                    int col = wn0 + j * 16 + l15;
                    float a = acc[i][j][ii];
                    if (EPI == 1) {
                        ((float*)Cout)[(size_t)row * NW + col] = a + bias[col];
                    } else {
                        float val = a + cvec[row] * bias[col];
                        float o = partial[(size_t)row * NW + col] + 0.5f * fmaxf(val, 0.f);
                        ((ushort*)Cout)[(size_t)row * NW + col] = f2bf(o);
                    }
                }
            }
        }
    }
}

// ---------------------------------------------------------------------------
// CSR histogram (4 edge lists batched) + weight transpose merged in one grid.
// ---------------------------------------------------------------------------
__global__ void histo4_prep(CPtr4 ed, MPtr4 cnt,
    const float* __restrict__ Win, const float* __restrict__ W1,
    const float* __restrict__ W2,  const float* __restrict__ Wout,
    ushort* __restrict__ Wtin, ushort* __restrict__ Wt1,
    ushort* __restrict__ Wt2,  ushort* __restrict__ Wtout)
{
    int b = blockIdx.x, t = threadIdx.x;
    if (b >= NB_CSR) {
        int i = (b - NB_CSR) * 256 + t;
        if (i < 65536) {
            int m = i >> 15, r = i & 32767, k = r >> 7, n = r & 127;
            Wtin[m * 32768 + n * 256 + k] = f2bf(Win[m * 32768 + k * 128 + n]);
        } else if (i < 98304) {
            int i2 = i - 65536;
            int m = i2 >> 14, r = i2 & 16383, k = r >> 7, n = r & 127;
            Wt1[m * 16384 + n * 128 + k] = f2bf(W1[m * 16384 + k * 128 + n]);
        } else if (i < 131072) {
            int i2 = i - 98304;
            int m = i2 >> 14, r = i2 & 16383, k = r >> 7, n = r & 127;
            Wt2[m * 16384 + n * 128 + k] = f2bf(W2[m * 16384 + k * 128 + n]);
        } else if (i < 147456) {
            int i2 = i - 131072;
            int m = i2 >> 13, r = i2 & 8191, k = r >> 6, n = r & 63;
            Wtout[m * 8192 + n * 128 + k] = f2bf(Wout[m * 8192 + k * 64 + n]);
        }
        return;
    }
    const int* edp; int* cp; int e, E;
    if (b < NBE0)          { edp = ed.p0; cp = cnt.p0; e = b * 256 + t;              E = E0_N; }
    else if (b < 2 * NBE0) { edp = ed.p1; cp = cnt.p1; e = (b - NBE0) * 256 + t;     E = E0_N; }
    else if (b < 2 * NBE0 + NBE1)
                           { edp = ed.p2; cp = cnt.p2; e = (b - 2 * NBE0) * 256 + t; E = E1_N; }
    else                   { edp = ed.p3; cp = cnt.p3; e = (b - 2 * NBE0 - NBE1) * 256 + t; E = E1_N; }
    if (e < E) atomicAdd(&cp[edp[e]], 1);
}

__global__ __launch_bounds__(1024) void exscan4(MPtr4 cnt, MPtr4 row, MPtr4 head)
{
    __shared__ int part[1024];
    const int b = blockIdx.x, t = threadIdx.x;
    int* cp; int* rp; int* hp; int n;
    if (b == 0)      { cp = cnt.p0; rp = row.p0; hp = head.p0; n = ND0; }
    else if (b == 1) { cp = cnt.p1; rp = row.p1; hp = head.p1; n = ND0; }
    else if (b == 2) { cp = cnt.p2; rp = row.p2; hp = head.p2; n = ND1; }
    else             { cp = cnt.p3; rp = row.p3; hp = head.p3; n = ND1; }

    const int chunk = (n + 1023) >> 10;
    const int start = t * chunk;
    int s = 0;
    for (int i = 0; i < chunk; ++i) {
        int idx = start + i;
        if (idx < n) s += cp[idx];
    }
    part[t] = s;
    __syncthreads();
    for (int off = 1; off < 1024; off <<= 1) {
        int v = (t >= off) ? part[t - off] : 0;
        __syncthreads();
        part[t] += v;
        __syncthreads();
    }
    int run = (t == 0) ? 0 : part[t - 1];
    for (int i = 0; i < chunk; ++i) {
        int idx = start + i;
        if (idx < n) { rp[idx] = run; hp[idx] = run; run += cp[idx]; }
    }
    if (t == 1023) rp[n] = part[1023];
}

__global__ void build4(CPtr4 es, CPtr4 ed, MPtr4 head, MPtr4 src)
{
    int b = blockIdx.x, t = threadIdx.x;
    const int *esp, *edp; int *hp, *sp; int e, E;
    if (b < NBE0)          { esp = es.p0; edp = ed.p0; hp = head.p0; sp = src.p0; e = b * 256 + t;              E = E0_N; }
    else if (b < 2 * NBE0) { esp = es.p1; edp = ed.p1; hp = head.p1; sp = src.p1; e = (b - NBE0) * 256 + t;     E = E0_N; }
    else if (b < 2 * NBE0 + NBE1)
                           { esp = es.p2; edp = ed.p2; hp = head.p2; sp = src.p2; e = (b - 2 * NBE0) * 256 + t; E = E1_N; }
    else                   { esp = es.p3; edp = ed.p3; hp = head.p3; sp = src.p3; e = (b - 2 * NBE0 - NBE1) * 256 + t; E = E1_N; }
    if (e >= E) return;
    int p = atomicAdd(&hp[edp[e]], 1);
    sp[p] = esp[e];
}

// ---------------------------------------------------------------------------
// Per-node projections, mode-fused. 8 lanes/node, weight slices in regs.
// ---------------------------------------------------------------------------
#define NP_NPB 128
__global__ __launch_bounds__(256) void node_proj(
    const ushort* __restrict__ zb, size_t zstr,
    const float* __restrict__ Web, const float* __restrict__ Wib,
    float* __restrict__ psb, float* __restrict__ qsb,
    float* __restrict__ pdb, float* __restrict__ qdb,
    int n_src, int n_dst)
{
    const int m = blockIdx.y;
    const ushort* z = zb + m * zstr;
    const float* We = Web + m * 512;
    const float* Wi = Wib + m * 256;
    float* ps = psb + (size_t)m * NS0 * 2;
    float* qs = qsb + (size_t)m * NS0;
    float* pd = pdb + (size_t)m * ND0 * 2;
    float* qd = qdb + (size_t)m * ND0;

    __shared__ float w[6][D_DIM];
    for (int k = threadIdx.x; k < D_DIM; k += 256) {
        w[0][k] = We[k * 2 + 0];
        w[1][k] = We[k * 2 + 1];
        w[2][k] = Wi[k];
        w[3][k] = We[(D_DIM + k) * 2 + 0];
        w[4][k] = We[(D_DIM + k) * 2 + 1];
        w[5][k] = Wi[D_DIM + k];
    }
    __syncthreads();

    const int sub = threadIdx.x & 7;
    const int g   = threadIdx.x >> 3;

    float wr[6][16];
    #pragma unroll
    for (int c = 0; c < 6; ++c)
        #pragma unroll
        for (int q = 0; q < 4; ++q) {
            float4 f = *(const float4*)(&w[c][sub * 16 + q * 4]);
            wr[c][q * 4 + 0] = f.x; wr[c][q * 4 + 1] = f.y;
            wr[c][q * 4 + 2] = f.z; wr[c][q * 4 + 3] = f.w;
        }

    #pragma unroll
    for (int it = 0; it < 4; ++it) {
        int node = blockIdx.x * NP_NPB + it * 32 + g;
        if (node >= n_src) continue;
        const ushort* zp = z + (size_t)node * D_DIM + sub * 16;
        uint4 ra = *(const uint4*)zp;
        uint4 rb = *(const uint4*)(zp + 8);
        uint rr[8] = {ra.x, ra.y, ra.z, ra.w, rb.x, rb.y, rb.z, rb.w};
        float p[6] = {0.f, 0.f, 0.f, 0.f, 0.f, 0.f};
        #pragma unroll
        for (int e = 0; e < 8; ++e) {
            float2 f2 = unpack2(rr[e]);
            #pragma unroll
            for (int c = 0; c < 6; ++c)
                p[c] += f2.x * wr[c][2 * e] + f2.y * wr[c][2 * e + 1];
        }
        #pragma unroll
        for (int off = 4; off > 0; off >>= 1)
            #pragma unroll
            for (int c = 0; c < 6; ++c)
                p[c] += __shfl_down(p[c], off);

        if (sub == 0) {
            *(float2*)(ps + (size_t)node * 2) = make_float2(p[0], p[1]);
            qs[node] = p[2];
            if (node < n_dst) {
                *(float2*)(pd + (size_t)node * 2) = make_float2(p[3], p[4]);
                qd[node] = p[5];
            }
        }
    }
}

// ---------------------------------------------------------------------------
// Edge attention, mode-fused: one wave per dst, one LANE per CSR slot.
// Writes PACKED (weight, src) uint2 per edge; wave-reduces Σe0 -> cvec.
// ---------------------------------------------------------------------------
__global__ __launch_bounds__(256) void edge_att(
    const float* __restrict__ psb, const float* __restrict__ pdb,
    const float* __restrict__ qsb, const float* __restrict__ qdb,
    const int* __restrict__ row_c, const int* __restrict__ src_c,
    const int* __restrict__ row_s, const int* __restrict__ src_s,
    uint2* __restrict__ epkb, uint2* __restrict__ ipkb,
    float* __restrict__ cvecb, int n_dst)
{
    const int m = blockIdx.y;
    const int d = blockIdx.x * 4 + (threadIdx.x >> 6);
    const int lane = threadIdx.x & 63;
    if (d >= n_dst) return;

    const float* ps = psb + (size_t)m * NS0 * 2;
    const float* qs = qsb + (size_t)m * NS0;
    const float* pdv = pdb + (size_t)m * ND0 * 2;
    const float* qdv = qdb + (size_t)m * ND0;
    const int* erow = m ? row_s : row_c;
    const int* esrc = m ? src_s : src_c;
    const int* irow = m ? row_c : row_s;
    const int* isrc = m ? src_c : src_s;
    uint2* epk = epkb + (size_t)m * E0_N;
    uint2* ipk = ipkb + (size_t)m * E0_N;
    float* cvec = cvecb + (size_t)m * ND0;

    const float pd0 = pdv[2 * d], pd1 = pdv[2 * d + 1];
    const float qdd = qdv[d];

    const int b0 = erow[d], b1 = erow[d + 1];
    float se0 = 0.f;
    for (int j = b0 + lane; j < b1; j += 64) {
        int s = esrc[j];
        float2 pp = *(const float2*)(ps + 2 * (size_t)s);
        float l0 = pp.x + pd0, l1 = pp.y + pd1;
        float mx = fmaxf(l0, l1);
        float x0 = __expf(l0 - mx), x1 = __expf(l1 - mx);
        float e0 = x0 / (x0 + x1);
        epk[j] = make_uint2(f2u(e0), (uint)s);
        se0 += e0;
    }
    #pragma unroll
    for (int off = 32; off > 0; off >>= 1)
        se0 += __shfl_down(se0, off);
    if (lane == 0) cvec[d] = se0 / fmaxf((float)(b1 - b0), 1.0f);

    const int c0 = irow[d], c1 = irow[d + 1];
    for (int j = c0 + lane; j < c1; j += 64) {
        int s = isrc[j];
        float q = qs[s] + qdd;
        float sg = 1.0f / (1.0f + __expf(-q));
        ipk[j] = make_uint2(f2u(sg), (uint)s);
    }
}

// ---------------------------------------------------------------------------
// Gather-accumulate, mode-fused: one wave per dst node, unroll-8 with a
// PREDICATED tail batch (8 loads stay in flight through the remainder).
//   e-loop: sz += v, h0 += e0*v; eh = sz - h0 (e1 = 1-e0).
//   h0 -> bf16 (normalized by deg), partial = 0.5*(relu(eh*ih) + z_d)
// ---------------------------------------------------------------------------
__global__ __launch_bounds__(256) void gather_acc(
    const ushort* __restrict__ zb, size_t zstr,
    const uint2* __restrict__ epkb, const uint2* __restrict__ ipkb,
    const int* __restrict__ row_c, const int* __restrict__ row_s,
    ushort* __restrict__ h0base, float* __restrict__ partialb, int n_dst)
{
    const int m = blockIdx.y;
    const int d = blockIdx.x * 4 + (threadIdx.x >> 6);
    const int lane = threadIdx.x & 63;
    if (d >= n_dst) return;

    const ushort* z = zb + m * zstr;
    const uint2* epk = epkb + (size_t)m * E0_N;
    const uint2* ipk = ipkb + (size_t)m * E0_N;
    const int* erow = m ? row_s : row_c;
    const int* irow = m ? row_c : row_s;
    ushort* h0b = h0base + (size_t)m * ND0 * D_DIM;
    float* partial = partialb + (size_t)m * ND0 * D_DIM;

    float h0x = 0.f, h0y = 0.f, szx = 0.f, szy = 0.f;
    float ihx = 0.f, ihy = 0.f;

    const int b0 = erow[d], b1 = erow[d + 1];
    int j = b0;
    const int jfull = b0 + ((b1 - b0) & ~7);
    for (; j < jfull; j += 8) {
        uint2 ew[8]; uint rr[8];
        #pragma unroll
        for (int k = 0; k < 8; ++k) ew[k] = epk[j + k];
        #pragma unroll
        for (int k = 0; k < 8; ++k) rr[k] = *(const uint*)(z + (size_t)ew[k].y * D_DIM + lane * 2);
        #pragma unroll
        for (int k = 0; k < 8; ++k) {
            float w0 = u2f(ew[k].x);
            float2 v = unpack2(rr[k]);
            szx += v.x; szy += v.y;
            h0x += w0 * v.x; h0y += w0 * v.y;
        }
    }
    if (j < b1) {   // predicated batch of 8 (epk has +8 slack)
        uint2 ew[8]; uint rr[8];
        #pragma unroll
        for (int k = 0; k < 8; ++k) ew[k] = epk[j + k];
        #pragma unroll
        for (int k = 0; k < 8; ++k) {
            uint s = (j + k < b1) ? ew[k].y : 0u;
            rr[k] = *(const uint*)(z + (size_t)s * D_DIM + lane * 2);
        }
        #pragma unroll
        for (int k = 0; k < 8; ++k) {
            float sel = (j + k < b1) ? 1.0f : 0.0f;
            float w0 = u2f(ew[k].x) * sel;
            float2 v = unpack2(rr[k]);
            szx += v.x * sel; szy += v.y * sel;
            h0x += w0 * v.x; h0y += w0 * v.y;
        }
    }

    const int c0 = irow[d], c1 = irow[d + 1];
    j = c0;
    const int cfull = c0 + ((c1 - c0) & ~7);
    for (; j < cfull; j += 8) {
        uint2 ew[8]; uint rr[8];
        #pragma unroll
        for (int k = 0; k < 8; ++k) ew[k] = ipk[j + k];
        #pragma unroll
        for (int k = 0; k < 8; ++k) rr[k] = *(const uint*)(z + (size_t)ew[k].y * D_DIM + lane * 2);
        #pragma unroll
        for (int k = 0; k < 8; ++k) {
            float g = u2f(ew[k].x);
            float2 v = unpack2(rr[k]);
            ihx += g * v.x; ihy += g * v.y;
        }
    }
    if (j < c1) {
        uint2 ew[8]; uint rr[8];
        #pragma unroll
        for (int k = 0; k < 8; ++k) ew[k] = ipk[j + k];
        #pragma unroll
        for (int k = 0; k < 8; ++k) {
            uint s = (j + k < c1) ? ew[k].y : 0u;
            rr[k] = *(const uint*)(z + (size_t)s * D_DIM + lane * 2);
        }
        #pragma unroll
        for (int k = 0; k < 8; ++k) {
            float sel = (j + k < c1) ? 1.0f : 0.0f;
            float g = u2f(ew[k].x) * sel;
            float2 v = unpack2(rr[k]);
            ihx += g * v.x; ihy += g * v.y;
        }
    }

    float ehx = szx - h0x, ehy = szy - h0y;   // e1 = 1 - e0
    float inv = 1.0f / fmaxf((float)(b1 - b0), 1.0f);
    uint hp = (uint)f2bf(h0x * inv) | ((uint)f2bf(h0y * inv) << 16);
    *(uint*)(h0b + (size_t)d * D_DIM + lane * 2) = hp;

    float2 zd = unpack2(*(const uint*)(z + (size_t)d * D_DIM + lane * 2));
    float px = 0.5f * (fmaxf(ehx * ihx, 0.f) + zd.x);
    float py = 0.5f * (fmaxf(ehy * ihy, 0.f) + zd.y);
    *(float2*)(partial + (size_t)d * D_DIM + lane * 2) = make_float2(px, py);
}

// ---------------------------------------------------------------------------
extern "C" void kernel_launch(void* const* d_in, const int* in_sizes, int n_in,
                              void* d_out, int out_size, void* d_ws, size_t ws_size,
                              hipStream_t stream)
{
    const float* feat = (const float*)d_in[0];
    const int* src0_cor = (const int*)d_in[1];
    const int* dst0_cor = (const int*)d_in[2];
    const int* src0_sim = (const int*)d_in[3];
    const int* dst0_sim = (const int*)d_in[4];
    const int* src1_cor = (const int*)d_in[5];
    const int* dst1_cor = (const int*)d_in[6];
    const int* src1_sim = (const int*)d_in[7];
    const int* dst1_sim = (const int*)d_in[8];
    const float* Win  = (const float*)d_in[11];
    const float* b_in = (const float*)d_in[12];
    const float* ea1  = (const float*)d_in[14];
    const float* ia1  = (const float*)d_in[15];
    const float* W1   = (const float*)d_in[16];
    const float* b1   = (const float*)d_in[17];
    const float* ea2  = (const float*)d_in[19];
    const float* ia2  = (const float*)d_in[20];
    const float* W2   = (const float*)d_in[21];
    const float* b2   = (const float*)d_in[22];
    const float* Wout = (const float*)d_in[23];
    const float* bout = (const float*)d_in[24];
    (void)in_sizes; (void)n_in; (void)out_size; (void)ws_size;

    // ---- workspace layout ----
    char* wsb = (char*)d_ws;
    size_t off = 0;
    auto alloc_f = [&](size_t n) { float*  p = (float*) (wsb + off); off += n * 4; return p; };
    auto alloc_i = [&](size_t n) { int*    p = (int*)   (wsb + off); off += n * 4; return p; };
    auto alloc_h = [&](size_t n) { ushort* p = (ushort*)(wsb + off); off += ((n * 2 + 15) & ~15ull); return p; };
    auto alloc_u2 = [&](size_t n) { uint2* p = (uint2*)(wsb + off); off += n * 8; return p; };

    ushort* z0b   = alloc_h((size_t)2 * NS0 * D_DIM);
    ushort* z1b   = alloc_h((size_t)2 * NS1 * D_DIM);
    ushort* z2b   = alloc_h((size_t)2 * ND1 * D_DIM);
    ushort* h0b   = alloc_h((size_t)2 * ND0 * D_DIM);
    ushort* Wtin  = alloc_h((size_t)2 * D_DIM * F_DIM);
    ushort* Wt1   = alloc_h((size_t)2 * D_DIM * D_DIM);
    ushort* Wt2   = alloc_h((size_t)2 * D_DIM * D_DIM);
    ushort* Wtout = alloc_h((size_t)2 * O_DIM * D_DIM);

    float* ps      = alloc_f((size_t)2 * NS0 * 2);
    float* qs      = alloc_f((size_t)2 * NS0);
    float* pd      = alloc_f((size_t)2 * ND0 * 2);
    float* qd      = alloc_f((size_t)2 * ND0);
    float* cvec    = alloc_f((size_t)2 * ND0);
    float* partial = alloc_f((size_t)2 * ND0 * D_DIM);
    uint2* epk     = alloc_u2((size_t)2 * E0_N + 8);   // +8 slack for predicated tail
    uint2* ipk     = alloc_u2((size_t)2 * E0_N + 8);

    int* src_c0 = alloc_i(E0_N); int* row_c0 = alloc_i(ND0 + 1);
    int* src_s0 = alloc_i(E0_N); int* row_s0 = alloc_i(ND0 + 1);
    int* src_c1 = alloc_i(E1_N); int* row_c1 = alloc_i(ND1 + 1);
    int* src_s1 = alloc_i(E1_N); int* row_s1 = alloc_i(ND1 + 1);
    int* cnt_all  = alloc_i(2 * ND0 + 2 * ND1);
    int* head_all = alloc_i(2 * ND0 + 2 * ND1);

    int* cnt_c0 = cnt_all;            int* head_c0 = head_all;
    int* cnt_s0 = cnt_all + ND0;      int* head_s0 = head_all + ND0;
    int* cnt_c1 = cnt_all + 2 * ND0;  int* head_c1 = head_all + 2 * ND0;
    int* cnt_s1 = cnt_c1 + ND1;       int* head_s1 = head_c1 + ND1;

    // ---- batched CSR build + weight prep ----
    hipMemsetAsync(cnt_all, 0, (size_t)(2 * ND0 + 2 * ND1) * 4, stream);
    {
        CPtr4 edp  = {dst0_cor, dst0_sim, dst1_cor, dst1_sim};
        CPtr4 esp  = {src0_cor, src0_sim, src1_cor, src1_sim};
        MPtr4 cntp = {cnt_c0, cnt_s0, cnt_c1, cnt_s1};
        MPtr4 rowp = {row_c0, row_s0, row_c1, row_s1};
        MPtr4 hdp  = {head_c0, head_s0, head_c1, head_s1};
        MPtr4 srcp = {src_c0, src_s0, src_c1, src_s1};
        histo4_prep<<<NB_CSR + NB_WPREP, 256, 0, stream>>>(
            edp, cntp, Win, W1, W2, Wout, Wtin, Wt1, Wt2, Wtout);
        exscan4<<<4, 1024, 0, stream>>>(cntp, rowp, hdp);
        build4<<<NB_CSR, 256, 0, stream>>>(esp, edp, hdp, srcp);
    }

    // ======== both modes fused ========
    const size_t Z0S = (size_t)NS0 * D_DIM, Z1S = (size_t)NS1 * D_DIM;
    const size_t Z2S = (size_t)ND1 * D_DIM, H0S = (size_t)ND0 * D_DIM;

    // --- Layer 0: z0[m] = feat @ Win[m] + b_in[m]  (A staged once for both modes)
    gemm_l0<<<(NS0 + 63) / 64, 256, 0, stream>>>(
        feat, Wtin, b_in, z0b, Z0S, NS0);

    // --- Layer 1
    node_proj<<<dim3((NS0 + NP_NPB - 1) / NP_NPB, 2), 256, 0, stream>>>(
        z0b, Z0S, ea1, ia1, ps, qs, pd, qd, NS0, ND0);
    edge_att<<<dim3((ND0 + 3) / 4, 2), 256, 0, stream>>>(
        ps, pd, qs, qd, row_c0, src_c0, row_s0, src_s0, epk, ipk, cvec, ND0);
    gather_acc<<<dim3((ND0 + 3) / 4, 2), 256, 0, stream>>>(
        z0b, Z0S, epk, ipk, row_c0, row_s0, h0b, partial, ND0);
    mfma_gemm<128, 128, 2><<<dim3((ND0 + 127) / 128, 2), 256, 0, stream>>>(
        h0b, H0S, Wt1, (size_t)D_DIM * D_DIM, b1, D_DIM,
        cvec, ND0, partial, H0S, z1b, Z1S, ND0);

    // --- Layer 2
    node_proj<<<dim3((NS1 + NP_NPB - 1) / NP_NPB, 2), 256, 0, stream>>>(
        z1b, Z1S, ea2, ia2, ps, qs, pd, qd, NS1, ND1);
    edge_att<<<dim3((ND1 + 3) / 4, 2), 256, 0, stream>>>(
        ps, pd, qs, qd, row_c1, src_c1, row_s1, src_s1, epk, ipk, cvec, ND1);
    gather_acc<<<dim3((ND1 + 3) / 4, 2), 256, 0, stream>>>(
        z1b, Z1S, epk, ipk, row_c1, row_s1, h0b, partial, ND1);
    mfma_gemm<128, 128, 2><<<dim3((ND1 + 127) / 128, 2), 256, 0, stream>>>(
        h0b, H0S, Wt2, (size_t)D_DIM * D_DIM, b2, D_DIM,
        cvec, ND0, partial, H0S, z2b, Z2S, ND1);

    // --- Output: out[m] = z2 @ Wout[m] + bout[m]  (fp32 out)
    mfma_gemm<64, 128, 1><<<dim3((ND1 + 127) / 128, 2), 256, 0, stream>>>(
        z2b, Z2S, Wtout, (size_t)O_DIM * D_DIM, bout, O_DIM,
        nullptr, 0, nullptr, 0, (float*)d_out, (size_t)ND1 * O_DIM, ND1);
}